// Round 1
// 1224.394 us; speedup vs baseline: 6.6136x; 6.6136x over previous
//
#include <hip/hip_runtime.h>

typedef unsigned short u16;
typedef unsigned int u32;
typedef __attribute__((ext_vector_type(8))) unsigned short ushort8v;
typedef __attribute__((ext_vector_type(8))) __bf16 bf16x8;
typedef __attribute__((ext_vector_type(4))) float f32x4;

__device__ __forceinline__ float bf2f(u16 u) { return __uint_as_float(((u32)u) << 16); }
__device__ __forceinline__ u16 f2bf(float f) {
    u32 u = __float_as_uint(f);
    u32 r = u + 0x7fffu + ((u >> 16) & 1u);
    return (u16)(r >> 16);
}
__device__ __forceinline__ float wave_sum(float v) {
    #pragma unroll
    for (int m = 1; m < 64; m <<= 1) v += __shfl_xor(v, m, 64);
    return v;
}
// dtype-flexible load/store: f32=true -> float32 buffer, else bf16 (u16) buffer
__device__ __forceinline__ float gld(const void* p, size_t i, bool f32) {
    return f32 ? ((const float*)p)[i] : bf2f(((const u16*)p)[i]);
}
__device__ __forceinline__ void gst(void* p, size_t i, bool f32, float v) {
    if (f32) ((float*)p)[i] = v;
    else     ((u16*)p)[i] = f2bf(v);
}
// load 16 consecutive elements (dtype per flag), emit 16 bf16 words
__device__ __forceinline__ void stg16(const void* p, size_t i, bool f32, u16* o) {
    if (f32) {
        const float4* q = (const float4*)((const float*)p + i);
        float4 a = q[0], b = q[1], c = q[2], d = q[3];
        o[0] = f2bf(a.x); o[1] = f2bf(a.y); o[2] = f2bf(a.z); o[3] = f2bf(a.w);
        o[4] = f2bf(b.x); o[5] = f2bf(b.y); o[6] = f2bf(b.z); o[7] = f2bf(b.w);
        o[8] = f2bf(c.x); o[9] = f2bf(c.y); o[10] = f2bf(c.z); o[11] = f2bf(c.w);
        o[12] = f2bf(d.x); o[13] = f2bf(d.y); o[14] = f2bf(d.z); o[15] = f2bf(d.w);
    } else {
        const ushort8v* q = (const ushort8v*)((const u16*)p + i);
        ushort8v v0 = q[0], v1 = q[1];
        #pragma unroll
        for (int j = 0; j < 8; j++) { o[j] = v0[j]; o[8 + j] = v1[j]; }
    }
}

// ---- dtype probe: bf16 N(0,1) decodes |v|<~5 always; f32 viewed as u16 halves
// has ~48% of low-half words decoding to |v|>64 or NaN -> flags within 1024 floats.
__global__ void __launch_bounds__(256) k_probe(const u16* __restrict__ x, u32* __restrict__ flag) {
    __shared__ int cnt;
    if (threadIdx.x == 0) cnt = 0;
    __syncthreads();
    int bad = 0;
    for (int i = threadIdx.x; i < 2048; i += 256) {
        float v = bf2f(x[i]);
        if (!(v > -64.f && v < 64.f)) bad = 1;
    }
    if (bad) atomicAdd(&cnt, 1);
    __syncthreads();
    if (threadIdx.x == 0) flag[0] = (cnt > 0) ? 1u : 0u;
}

__global__ void __launch_bounds__(256) k_zero(u32* __restrict__ p, int n) {
    int i = blockIdx.x * 256 + threadIdx.x;
    if (i < n) p[i] = 0u;
}

// ---- MFMA bf16 GEMM: C[m, col0+n] = sum_k A[arow0+m, k]*B[brow0+n, k], n < Nn
// Tile 128 x BN, 256 threads (4 waves), v_mfma_f32_16x16x32_bf16, BK=32.
// BN=128: waves 2x2 of 64x64 (4x4 frags). BN=64: waves 4x1 of 32x64 (2x4 frags).
// A/B staged to LDS as bf16 (runtime dtype per probe flag), padded stride 40 u16
// (80 B) -> ~2-way bank pattern on ds_read_b128 (free).
// Row clamp handles M tails (reads valid rows, stores guarded).
// EPI: 0 = bf16 store; 1 = bf16 gelu(acc+bias[col]); 2 = f32 store
template <int EPI, int BN>
__global__ void __launch_bounds__(256) mgemm(const u32* __restrict__ dflag, int amode, int bmode,
                                             const void* __restrict__ A, const void* __restrict__ B,
                                             void* __restrict__ Cout, const void* __restrict__ bias,
                                             int M, int Nn, int K, int ldC, int col0, int brow0,
                                             int arow0) {
    const bool ibf32 = dflag[0] != 0u;
    const bool af32 = amode && ibf32;
    const bool bf32 = bmode && ibf32;
    constexpr int LDT = 40;  // u16 stride (80 B)
    __shared__ u16 sA[128 * LDT];
    __shared__ u16 sB[BN * LDT];

    const int tid = threadIdx.x;
    const int m0 = blockIdx.y * 128;
    const int n0 = blockIdx.x * BN;
    const int wid = tid >> 6;
    const int lane = tid & 63;

    constexpr int WAVES_N = (BN == 128) ? 2 : 1;
    constexpr int WM = 128 / (4 / WAVES_N);  // 64 or 32
    constexpr int WN = BN / WAVES_N;         // 64
    constexpr int FM = WM / 16;              // 4 or 2
    constexpr int FN = WN / 16;              // 4
    const int wm = (wid / WAVES_N) * WM;
    const int wn = (wid % WAVES_N) * WN;
    const int lr = lane & 15;         // frag row (A) / col (B,C)
    const int lk = (lane >> 4) * 8;   // k offset within 32

    f32x4 acc[FM][FN] = {};

    // staging coords: thread covers 16 elems of one row
    const int sr = tid >> 1;              // A row 0..127 (B row for tid<2*BN)
    const int skk = (tid & 1) << 4;       // 0 or 16
    int ar = m0 + sr; if (ar >= M) ar = M - 1;
    const size_t abase = (size_t)(arow0 + ar) * K;
    int br = n0 + sr; if (br >= Nn) br = Nn - 1;
    const size_t bbase = (size_t)(brow0 + br) * K;

    for (int k0 = 0; k0 < K; k0 += 32) {
        __syncthreads();
        {
            u16 t16[16];
            stg16(A, abase + k0 + skk, af32, t16);
            *(ushort8v*)&sA[sr * LDT + skk] = *(const ushort8v*)&t16[0];
            *(ushort8v*)&sA[sr * LDT + skk + 8] = *(const ushort8v*)&t16[8];
        }
        if (BN == 128 || tid < 2 * BN) {
            u16 t16[16];
            stg16(B, bbase + k0 + skk, bf32, t16);
            *(ushort8v*)&sB[sr * LDT + skk] = *(const ushort8v*)&t16[0];
            *(ushort8v*)&sB[sr * LDT + skk + 8] = *(const ushort8v*)&t16[8];
        }
        __syncthreads();
        bf16x8 afr[FM], bfr[FN];
        #pragma unroll
        for (int m = 0; m < FM; m++)
            afr[m] = __builtin_bit_cast(bf16x8, *(const ushort8v*)&sA[(wm + m * 16 + lr) * LDT + lk]);
        #pragma unroll
        for (int n = 0; n < FN; n++)
            bfr[n] = __builtin_bit_cast(bf16x8, *(const ushort8v*)&sB[(wn + n * 16 + lr) * LDT + lk]);
        #pragma unroll
        for (int m = 0; m < FM; m++)
            #pragma unroll
            for (int n = 0; n < FN; n++)
                acc[m][n] = __builtin_amdgcn_mfma_f32_16x16x32_bf16(afr[m], bfr[n], acc[m][n], 0, 0, 0);
    }

    // C/D: col = lane&15, row = (lane>>4)*4 + reg  [m89-verified]
    const int or0 = (lane >> 4) << 2;
    #pragma unroll
    for (int m = 0; m < FM; m++) {
        #pragma unroll
        for (int r = 0; r < 4; r++) {
            int gr = m0 + wm + m * 16 + or0 + r;
            if (gr >= M) continue;
            #pragma unroll
            for (int n = 0; n < FN; n++) {
                int cn = n0 + wn + n * 16 + lr;
                if (cn >= Nn) continue;
                int col = col0 + cn;
                float v = acc[m][n][r];
                if (EPI == 1) {
                    v += gld(bias, col, ibf32);
                    v = 0.5f * v * (1.0f + erff(v * 0.70710678f));
                    ((u16*)Cout)[(size_t)gr * ldC + col] = f2bf(v);
                } else if (EPI == 0) {
                    ((u16*)Cout)[(size_t)gr * ldC + col] = f2bf(v);
                } else {
                    ((float*)Cout)[(size_t)gr * ldC + col] = v;
                }
            }
        }
    }
}

// ---- fold attention vectors through W: Mmat[th][k] (bf16, [32,256])
// th<16:  sum_c Wsrc[h*32+c][k] * attS[t,h,c]   (th = t*8+h)
// th>=16: sum_c Wdst[h*32+c][k] * attD[t,h,c]
// Then dots[n, :] = x[n, :] @ Mmat^T  == per-(t,h) att dot products, exactly.
__global__ void __launch_bounds__(256) k_mkatt(const u32* __restrict__ dflag,
                                               const void* __restrict__ Wsrc, const void* __restrict__ Wdst,
                                               const void* __restrict__ attS, const void* __restrict__ attD,
                                               u16* __restrict__ Mmat, int K) {
    bool f32 = dflag[0] != 0u;
    int th = blockIdx.x;   // 0..31
    int k = threadIdx.x;   // 0..K-1 (K=256)
    int tt = th & 15;
    const void* W = (th < 16) ? Wsrc : Wdst;
    const void* att = (th < 16) ? attS : attD;
    int h = tt & 7;
    float s = 0.f;
    #pragma unroll 8
    for (int c = 0; c < 32; c++)
        s += gld(W, (size_t)(h * 32 + c) * K + k, f32) * gld(att, tt * 32 + c, f32);
    Mmat[th * K + k] = f2bf(s);
}

// ---- CSR build (dst-major) ----
__global__ void __launch_bounds__(256) k_count(const int* __restrict__ ei, u32* __restrict__ cnt, int E) {
    int e = blockIdx.x * 256 + threadIdx.x;
    if (e < E) atomicAdd(cnt + ei[E + e], 1u);
}
__global__ void __launch_bounds__(256) k_scanA(u32* __restrict__ buf, u32* __restrict__ bsum, int N) {
    int t = threadIdx.x, idx = blockIdx.x * 256 + t;
    u32 v = (idx < N) ? buf[idx] : 0u;
    __shared__ u32 sc[256];
    sc[t] = v; __syncthreads();
    for (int d = 1; d < 256; d <<= 1) {
        u32 add = (t >= d) ? sc[t - d] : 0u; __syncthreads();
        sc[t] += add; __syncthreads();
    }
    if (idx < N) buf[idx] = sc[t] - v;
    if (t == 255) bsum[blockIdx.x] = sc[255];
}
__global__ void __launch_bounds__(256) k_scanB(u32* __restrict__ bsum, int nb) {
    int t = threadIdx.x;
    u32 v = (t < nb) ? bsum[t] : 0u;
    __shared__ u32 sc[256];
    sc[t] = v; __syncthreads();
    for (int d = 1; d < 256; d <<= 1) {
        u32 add = (t >= d) ? sc[t - d] : 0u; __syncthreads();
        sc[t] += add; __syncthreads();
    }
    if (t < nb) bsum[t] = sc[t] - v;
}
__global__ void __launch_bounds__(256) k_scanC(u32* __restrict__ obuf, u32* __restrict__ cursor,
                                               const u32* __restrict__ bsum, int N, int E) {
    int idx = blockIdx.x * 256 + threadIdx.x;
    if (idx < N) {
        u32 o = obuf[idx] + bsum[blockIdx.x];
        obuf[idx] = o;
        cursor[idx] = o;
    }
    if (blockIdx.x == 0 && threadIdx.x == 0) obuf[N] = (u32)E;
}
__global__ void __launch_bounds__(256) k_scatter(const int* __restrict__ ei, u32* __restrict__ cursor,
                                                 u32* __restrict__ elist, int E) {
    int e = blockIdx.x * 256 + threadIdx.x;
    if (e >= E) return;
    u32 slot = atomicAdd(cursor + ei[E + e], 1u);
    elist[slot] = (u32)e;
}

// ---- fused per-node softmax aggregation over 64-channel window [ch0, ch0+64)
// one wave per node, lane owns 1 channel; writes v = agg + bias + x (pre-LN)
__global__ void __launch_bounds__(256) k_node(const u32* __restrict__ dflag,
                                              const int* __restrict__ ei, const int* __restrict__ et,
                                              const void* __restrict__ ew, const void* __restrict__ x,
                                              const u16* __restrict__ xq, const u16* __restrict__ dots,
                                              const u32* __restrict__ obuf, const u32* __restrict__ elist,
                                              const void* __restrict__ bias, void* __restrict__ vout,
                                              int N, int ch0) {
    bool f32 = dflag[0] != 0u;
    int node = blockIdx.x * 4 + (threadIdx.x >> 6);
    if (node >= N) return;
    int lane = threadIdx.x & 63;
    int ch = ch0 + lane;
    int hh = ch >> 5;
    float ad0 = bf2f(dots[(size_t)node * 32 + 16 + hh]);
    float ad1 = bf2f(dots[(size_t)node * 32 + 24 + hh]);
    // self-loop: type 0, weight 1
    float a = bf2f(dots[(size_t)node * 32 + hh]) + ad0;
    float p = __expf(a >= 0.f ? a : 0.2f * a);
    float den = p;
    float num = p * bf2f(xq[(size_t)node * 64 + lane]);
    u32 kbeg = obuf[node], kend = obuf[node + 1];
    for (u32 k = kbeg; k < kend; k++) {
        int e = (int)elist[k];
        int src = ei[e];
        int t = et[e];
        float w = gld(ew, e, f32);
        float aa = bf2f(dots[(size_t)src * 32 + t * 8 + hh]) + (t ? ad1 : ad0);
        float pp = __expf(aa >= 0.f ? aa : 0.2f * aa);
        den += pp;
        num += pp * w * bf2f(xq[(size_t)src * 64 + lane]);
    }
    float v = num / den + gld(bias, ch, f32) + gld(x, (size_t)node * 256 + ch, f32);
    gst(vout, (size_t)node * 256 + ch, f32, v);
}

// ---- LN1 in place on v ([N,256], dtype follows flag) -> h
__global__ void __launch_bounds__(256) k_ln1(const u32* __restrict__ dflag, void* __restrict__ v,
                                             const void* __restrict__ g, const void* __restrict__ b, int N) {
    bool f32 = dflag[0] != 0u;
    int node = blockIdx.x * 4 + (threadIdx.x >> 6);
    if (node >= N) return;
    int lane = threadIdx.x & 63;
    size_t base = (size_t)node * 256 + lane * 4;
    float v0 = gld(v, base + 0, f32), v1 = gld(v, base + 1, f32);
    float v2 = gld(v, base + 2, f32), v3 = gld(v, base + 3, f32);
    float mu = wave_sum(v0 + v1 + v2 + v3) * (1.f / 256.f);
    float d0 = v0 - mu, d1 = v1 - mu, d2 = v2 - mu, d3 = v3 - mu;
    float var = wave_sum(d0 * d0 + d1 * d1 + d2 * d2 + d3 * d3) * (1.f / 256.f);
    float rs = rsqrtf(var + 1e-5f);
    gst(v, base + 0, f32, d0 * rs * gld(g, lane * 4 + 0, f32) + gld(b, lane * 4 + 0, f32));
    gst(v, base + 1, f32, d1 * rs * gld(g, lane * 4 + 1, f32) + gld(b, lane * 4 + 1, f32));
    gst(v, base + 2, f32, d2 * rs * gld(g, lane * 4 + 2, f32) + gld(b, lane * 4 + 2, f32));
    gst(v, base + 3, f32, d3 * rs * gld(g, lane * 4 + 3, f32) + gld(b, lane * 4 + 3, f32));
}

// ---- residual + LN2 (chunked, in place on h rows [row0, row0+rows)): out = LN(h + ffn + fb2)
__global__ void __launch_bounds__(256) k_ln2(const u32* __restrict__ dflag,
                                             void* __restrict__ h, int row0, const float* __restrict__ ffn,
                                             const void* __restrict__ fb2, const void* __restrict__ g,
                                             const void* __restrict__ b, int rows) {
    bool f32 = dflag[0] != 0u;
    int row = blockIdx.x * 4 + (threadIdx.x >> 6);
    if (row >= rows) return;
    int lane = threadIdx.x & 63;
    size_t hbase = (size_t)(row0 + row) * 256 + lane * 4;
    size_t fbase = (size_t)row * 256 + lane * 4;
    float4 tv = *(const float4*)(ffn + fbase);
    float v0 = tv.x + gld(h, hbase + 0, f32) + gld(fb2, lane * 4 + 0, f32);
    float v1 = tv.y + gld(h, hbase + 1, f32) + gld(fb2, lane * 4 + 1, f32);
    float v2 = tv.z + gld(h, hbase + 2, f32) + gld(fb2, lane * 4 + 2, f32);
    float v3 = tv.w + gld(h, hbase + 3, f32) + gld(fb2, lane * 4 + 3, f32);
    float mu = wave_sum(v0 + v1 + v2 + v3) * (1.f / 256.f);
    float d0 = v0 - mu, d1 = v1 - mu, d2 = v2 - mu, d3 = v3 - mu;
    float var = wave_sum(d0 * d0 + d1 * d1 + d2 * d2 + d3 * d3) * (1.f / 256.f);
    float rs = rsqrtf(var + 1e-5f);
    gst(h, hbase + 0, f32, d0 * rs * gld(g, lane * 4 + 0, f32) + gld(b, lane * 4 + 0, f32));
    gst(h, hbase + 1, f32, d1 * rs * gld(g, lane * 4 + 1, f32) + gld(b, lane * 4 + 1, f32));
    gst(h, hbase + 2, f32, d2 * rs * gld(g, lane * 4 + 2, f32) + gld(b, lane * 4 + 2, f32));
    gst(h, hbase + 3, f32, d3 * rs * gld(g, lane * 4 + 3, f32) + gld(b, lane * 4 + 3, f32));
}

extern "C" void kernel_launch(void* const* d_in, const int* in_sizes, int n_in,
                              void* d_out, int out_size, void* d_ws, size_t ws_size,
                              hipStream_t stream) {
    const int N = in_sizes[0] / 256;     // 50000
    const int E = in_sizes[1] / 2;       // 800000
    const int NB = (N + 255) / 256;      // 196

    const void* x    = d_in[0];
    const int*  ei   = (const int*)d_in[1];
    const int*  et   = (const int*)d_in[2];
    const void* ew   = d_in[3];
    const void* Wsrc = d_in[4];
    const void* Wdst = d_in[5];
    const void* attS = d_in[6];
    const void* attD = d_in[7];
    const void* bias = d_in[8];
    const void* g1   = d_in[9];
    const void* b1   = d_in[10];
    const void* g2   = d_in[11];
    const void* b2   = d_in[12];
    const void* W1   = d_in[13];
    const void* fb1  = d_in[14];
    const void* W2   = d_in[15];
    const void* fb2  = d_in[16];

    // Graph/attention phase layout (~14.5 MB, same as verified baseline)
    char* ws = (char*)d_ws;
    u32* flag   = (u32*)(ws + 0);            // 256 B
    u32* bsum   = (u32*)(ws + 256);          // 1 KB
    u32* obuf   = (u32*)(ws + 1536);         // (N+1)*4 ~ 200 KB
    u32* cursor = (u32*)(ws + 201984);       // N*4 = 200 KB
    u16* dots   = (u16*)(ws + 402176);       // N*32*2 = 3.2 MB
    u32* elist  = (u32*)(ws + 3602176);      // E*4 = 3.2 MB
    char* region = ws + 6802176;             // 7.68 MB shared region
    u16*   xq     = (u16*)region;            // [N,64] bf16 = 6.4 MB (phase B)
    u16*   Mmat   = (u16*)region;            // [32,256] bf16 = 16 KB (dots GEMM only; dead before xq)
    void*  hbuf   = d_out;                   // v -> h -> out staged in d_out (dtype = flag)

    k_probe<<<1, 256, 0, stream>>>((const u16*)x, flag);

    const int gyN = (N + 127) / 128;         // 391

    // Phase A: fold att vectors through W (tiny), then one skinny MFMA GEMM for all 32 dots
    k_mkatt<<<32, 256, 0, stream>>>(flag, Wsrc, Wdst, attS, attD, Mmat, 256);
    mgemm<0, 64><<<dim3(1, gyN), 256, 0, stream>>>(
        flag, 1, 0, x, Mmat, dots, nullptr, N, 32, 256, 32, 0, 0, 0);

    // CSR build
    k_zero<<<NB, 256, 0, stream>>>(obuf, N);
    k_count<<<(E + 255) / 256, 256, 0, stream>>>(ei, obuf, E);
    k_scanA<<<NB, 256, 0, stream>>>(obuf, bsum, N);
    k_scanB<<<1, 256, 0, stream>>>(bsum, NB);
    k_scanC<<<NB, 256, 0, stream>>>(obuf, cursor, bsum, N, E);
    k_scatter<<<(E + 255) / 256, 256, 0, stream>>>(ei, cursor, elist, E);

    // Phase B: aggregation per 64-channel quarter (xq = x@Wsrc^T quarter)
    for (int q = 0; q < 4; q++) {
        mgemm<0, 64><<<dim3(1, gyN), 256, 0, stream>>>(
            flag, 1, 1, x, Wsrc, xq, nullptr, N, 64, 256, 64, 0, q * 64, 0);
        k_node<<<(N + 3) / 4, 256, 0, stream>>>(flag, ei, et, ew, x, xq, dots,
                                                obuf, elist, bias, hbuf, N, q * 64);
    }
    k_ln1<<<(N + 3) / 4, 256, 0, stream>>>(flag, hbuf, g1, b1, N);

    // FFN + LN2. After ln1 the CSR/dots/elist/xq space is dead: reuse the whole
    // workspace (minus flag) for act (bf16 [rc,1024]) + ffnout (f32 [rc,256]).
    // rc sized from ws_size: 3072 B per row.
    int rc = (int)((ws_size - 512) / 3072);
    rc &= ~127;
    if (rc > 50048) rc = 50048;
    if (rc < 128) rc = 128;
    u16*   act    = (u16*)(ws + 512);
    float* ffnout = (float*)(ws + 512 + (size_t)rc * 2048);

    for (int r0 = 0; r0 < N; r0 += rc) {
        int rows = N - r0; if (rows > rc) rows = rc;
        int gy = (rows + 127) / 128;
        mgemm<1, 128><<<dim3(8, gy), 256, 0, stream>>>(flag, 1, 1,
            hbuf, W1, act, fb1, rows, 1024, 256, 1024, 0, 0, r0);
        mgemm<2, 64><<<dim3(4, gy), 256, 0, stream>>>(flag, 0, 1,
            act, W2, ffnout, nullptr, rows, 256, 1024, 256, 0, 0, 0);
        k_ln2<<<(rows + 3) / 4, 256, 0, stream>>>(flag, hbuf, r0, ffnout,
                                                  fb2, g2, b2, rows);
    }
}

// Round 2
// 1036.306 us; speedup vs baseline: 7.8140x; 1.1815x over previous
//
#include <hip/hip_runtime.h>

typedef unsigned short u16;
typedef unsigned int u32;
typedef __attribute__((ext_vector_type(8))) unsigned short ushort8v;
typedef __attribute__((ext_vector_type(8))) __bf16 bf16x8;
typedef __attribute__((ext_vector_type(4))) float f32x4;

__device__ __forceinline__ float bf2f(u16 u) { return __uint_as_float(((u32)u) << 16); }
__device__ __forceinline__ u16 f2bf(float f) {
    u32 u = __float_as_uint(f);
    u32 r = u + 0x7fffu + ((u >> 16) & 1u);
    return (u16)(r >> 16);
}
__device__ __forceinline__ float wave_sum(float v) {
    #pragma unroll
    for (int m = 1; m < 64; m <<= 1) v += __shfl_xor(v, m, 64);
    return v;
}
// dtype-flexible load/store: f32=true -> float32 buffer, else bf16 (u16) buffer
__device__ __forceinline__ float gld(const void* p, size_t i, bool f32) {
    return f32 ? ((const float*)p)[i] : bf2f(((const u16*)p)[i]);
}
__device__ __forceinline__ void gst(void* p, size_t i, bool f32, float v) {
    if (f32) ((float*)p)[i] = v;
    else     ((u16*)p)[i] = f2bf(v);
}
__device__ __forceinline__ void ldf8(const void* p, size_t i, bool f32, float* o) {
    if (f32) {
        const float4* q = (const float4*)((const float*)p + i);
        float4 a = q[0], b = q[1];
        o[0] = a.x; o[1] = a.y; o[2] = a.z; o[3] = a.w;
        o[4] = b.x; o[5] = b.y; o[6] = b.z; o[7] = b.w;
    } else {
        ushort8v v = *(const ushort8v*)((const u16*)p + i);
        #pragma unroll
        for (int j = 0; j < 8; j++) o[j] = bf2f(v[j]);
    }
}
// async global(bf16)->LDS, 16 bytes per lane; LDS dst is wave-uniform base + lane*16
__device__ __forceinline__ void gl2lds16(const u16* g, u16* l) {
    __builtin_amdgcn_global_load_lds((const __attribute__((address_space(1))) void*)g,
                                     (__attribute__((address_space(3))) void*)l, 16, 0, 0);
}

// ---- dtype probe: bf16 N(0,1) decodes |v|<~5 always; f32 viewed as u16 halves
// has ~48% of low-half words decoding to |v|>64 or NaN -> flags within 1024 floats.
__global__ void __launch_bounds__(256) k_probe(const u16* __restrict__ x, u32* __restrict__ flag) {
    __shared__ int cnt;
    if (threadIdx.x == 0) cnt = 0;
    __syncthreads();
    int bad = 0;
    for (int i = threadIdx.x; i < 2048; i += 256) {
        float v = bf2f(x[i]);
        if (!(v > -64.f && v < 64.f)) bad = 1;
    }
    if (bad) atomicAdd(&cnt, 1);
    __syncthreads();
    if (threadIdx.x == 0) flag[0] = (cnt > 0) ? 1u : 0u;
}

__global__ void __launch_bounds__(256) k_zero(u32* __restrict__ p, int n) {
    int i = blockIdx.x * 256 + threadIdx.x;
    if (i < n) p[i] = 0u;
}

// ---- convert a tensor (dtype per flag) to bf16, 8 elems/thread
__global__ void __launch_bounds__(256) k_cvt(const u32* __restrict__ dflag,
                                             const void* __restrict__ src, u16* __restrict__ dst, int n8) {
    bool f32 = dflag[0] != 0u;
    int i = blockIdx.x * 256 + threadIdx.x;
    if (i >= n8) return;
    float t[8];
    ldf8(src, (size_t)i * 8, f32, t);
    ushort8v o;
    #pragma unroll
    for (int j = 0; j < 8; j++) o[j] = f2bf(t[j]);
    *(ushort8v*)&dst[(size_t)i * 8] = o;
}

// ---- MFMA bf16 GEMM (m97 template): C[m,n] = sum_k A[arow0+m,k]*B[n,k]
// A,B pre-converted bf16, row stride = K elems. Tile 128 x BN, BK=64, 4 waves,
// linear LDS [rows][64] u16, staging via global_load_lds dwordx4 (no VGPR trip).
// BN=128: waves 2x2 of 64x64 (4x4 frags). BN=64: waves 4x1 of 32x64 (2x4 frags).
// Row clamp handles M/Nn tails (reads valid rows, stores guarded). K % 64 == 0.
// EPI: 0 = bf16 store; 1 = bf16 gelu(acc+bias[col]); 2 = f32 store
template <int EPI, int BN>
__global__ void __launch_bounds__(256) mgemm2(const u32* __restrict__ dflag,
                                              const u16* __restrict__ A, const u16* __restrict__ B,
                                              void* __restrict__ Cout, const void* __restrict__ bias,
                                              int M, int Nn, int K, int ldC, int arow0) {
    const bool ibf32 = dflag[0] != 0u;
    __shared__ __attribute__((aligned(16))) u16 sA[128 * 64];
    __shared__ __attribute__((aligned(16))) u16 sB[BN * 64];

    const int tid = threadIdx.x;
    const int m0 = blockIdx.y * 128;
    const int n0 = blockIdx.x * BN;
    const int wid = tid >> 6;
    const int lane = tid & 63;

    constexpr int WAVES_N = BN / 64;           // 2 (BN=128) or 1 (BN=64)
    constexpr int WM = (BN == 128) ? 64 : 32;
    constexpr int FM = WM / 16;                // 4 or 2
    constexpr int FN = 4;
    const int wm = (wid / WAVES_N) * WM;
    const int wn = (wid % WAVES_N) * 64;
    const int lr = lane & 15;
    const int lk = (lane >> 4) * 8;

    // staging lane coords: 1024B unit = 8 rows x 128B; lane covers row u*8+(lane>>3),
    // bytes (lane&7)*16 (= 8 bf16 elems)
    const int srow = lane >> 3;
    const int scol = (lane & 7) * 8;
    constexpr int NBU = BN / 32;               // B units per wave (4 or 2)

    f32x4 acc[FM][FN] = {};

    for (int k0 = 0; k0 < K; k0 += 64) {
        __syncthreads();   // previous tile fully consumed
        #pragma unroll
        for (int j = 0; j < 4; j++) {
            int u = wid * 4 + j;
            int gr = m0 + u * 8 + srow; if (gr >= M) gr = M - 1;
            gl2lds16(A + (size_t)(arow0 + gr) * K + k0 + scol, &sA[u * 512]);
        }
        #pragma unroll
        for (int j = 0; j < NBU; j++) {
            int u = wid * NBU + j;
            int gr = n0 + u * 8 + srow; if (gr >= Nn) gr = Nn - 1;
            gl2lds16(B + (size_t)gr * K + k0 + scol, &sB[u * 512]);
        }
        __syncthreads();   // compiler drains vmcnt(0) before s_barrier -> LDS ready
        #pragma unroll
        for (int h = 0; h < 2; h++) {
            bf16x8 afr[FM], bfr[FN];
            #pragma unroll
            for (int m = 0; m < FM; m++)
                afr[m] = __builtin_bit_cast(bf16x8, *(const ushort8v*)&sA[(wm + m * 16 + lr) * 64 + h * 32 + lk]);
            #pragma unroll
            for (int n = 0; n < FN; n++)
                bfr[n] = __builtin_bit_cast(bf16x8, *(const ushort8v*)&sB[(wn + n * 16 + lr) * 64 + h * 32 + lk]);
            #pragma unroll
            for (int m = 0; m < FM; m++)
                #pragma unroll
                for (int n = 0; n < FN; n++)
                    acc[m][n] = __builtin_amdgcn_mfma_f32_16x16x32_bf16(afr[m], bfr[n], acc[m][n], 0, 0, 0);
        }
    }

    // C/D: col = lane&15, row = (lane>>4)*4 + reg  [verified in passing round-1 kernel]
    const int or0 = (lane >> 4) << 2;
    #pragma unroll
    for (int m = 0; m < FM; m++) {
        #pragma unroll
        for (int r = 0; r < 4; r++) {
            int gr = m0 + wm + m * 16 + or0 + r;
            if (gr >= M) continue;
            #pragma unroll
            for (int n = 0; n < FN; n++) {
                int cn = n0 + wn + n * 16 + lr;
                if (cn >= Nn) continue;
                float v = acc[m][n][r];
                if (EPI == 1) {
                    v += gld(bias, cn, ibf32);
                    v = 0.5f * v * (1.0f + erff(v * 0.70710678f));
                    ((u16*)Cout)[(size_t)gr * ldC + cn] = f2bf(v);
                } else if (EPI == 0) {
                    ((u16*)Cout)[(size_t)gr * ldC + cn] = f2bf(v);
                } else {
                    ((float*)Cout)[(size_t)gr * ldC + cn] = v;
                }
            }
        }
    }
}

// ---- fold attention vectors through W: Mmat[th][k] (bf16, [32,256])
// th<16:  sum_c Wsrc[h*32+c][k] * attS[t,h,c]   (th = t*8+h)
// th>=16: sum_c Wdst[h*32+c][k] * attD[t,h,c]
__global__ void __launch_bounds__(256) k_mkatt(const u32* __restrict__ dflag,
                                               const void* __restrict__ Wsrc, const void* __restrict__ Wdst,
                                               const void* __restrict__ attS, const void* __restrict__ attD,
                                               u16* __restrict__ Mmat, int K) {
    bool f32 = dflag[0] != 0u;
    int th = blockIdx.x;   // 0..31
    int k = threadIdx.x;   // 0..K-1 (K=256)
    int tt = th & 15;
    const void* W = (th < 16) ? Wsrc : Wdst;
    const void* att = (th < 16) ? attS : attD;
    int h = tt & 7;
    float s = 0.f;
    #pragma unroll 8
    for (int c = 0; c < 32; c++)
        s += gld(W, (size_t)(h * 32 + c) * K + k, f32) * gld(att, tt * 32 + c, f32);
    Mmat[th * K + k] = f2bf(s);
}

// ---- CSR build (dst-major) ----
__global__ void __launch_bounds__(256) k_count(const int* __restrict__ ei, u32* __restrict__ cnt, int E) {
    int e = blockIdx.x * 256 + threadIdx.x;
    if (e < E) atomicAdd(cnt + ei[E + e], 1u);
}
__global__ void __launch_bounds__(256) k_scanA(u32* __restrict__ buf, u32* __restrict__ bsum, int N) {
    int t = threadIdx.x, idx = blockIdx.x * 256 + t;
    u32 v = (idx < N) ? buf[idx] : 0u;
    __shared__ u32 sc[256];
    sc[t] = v; __syncthreads();
    for (int d = 1; d < 256; d <<= 1) {
        u32 add = (t >= d) ? sc[t - d] : 0u; __syncthreads();
        sc[t] += add; __syncthreads();
    }
    if (idx < N) buf[idx] = sc[t] - v;
    if (t == 255) bsum[blockIdx.x] = sc[255];
}
__global__ void __launch_bounds__(256) k_scanB(u32* __restrict__ bsum, int nb) {
    int t = threadIdx.x;
    u32 v = (t < nb) ? bsum[t] : 0u;
    __shared__ u32 sc[256];
    sc[t] = v; __syncthreads();
    for (int d = 1; d < 256; d <<= 1) {
        u32 add = (t >= d) ? sc[t - d] : 0u; __syncthreads();
        sc[t] += add; __syncthreads();
    }
    if (t < nb) bsum[t] = sc[t] - v;
}
__global__ void __launch_bounds__(256) k_scanC(u32* __restrict__ obuf, u32* __restrict__ cursor,
                                               const u32* __restrict__ bsum, int N, int E) {
    int idx = blockIdx.x * 256 + threadIdx.x;
    if (idx < N) {
        u32 o = obuf[idx] + bsum[blockIdx.x];
        obuf[idx] = o;
        cursor[idx] = o;
    }
    if (blockIdx.x == 0 && threadIdx.x == 0) obuf[N] = (u32)E;
}
__global__ void __launch_bounds__(256) k_scatter(const int* __restrict__ ei, u32* __restrict__ cursor,
                                                 u32* __restrict__ elist, int E) {
    int e = blockIdx.x * 256 + threadIdx.x;
    if (e >= E) return;
    u32 slot = atomicAdd(cursor + ei[E + e], 1u);
    elist[slot] = (u32)e;
}

// ---- fused per-node softmax aggregation, all 256 channels, one block per node
// (4 waves; wave w owns channels [w*64, w*64+64), edge scalars shared via L1)
// writes v = agg + bias + x (pre-LN) into vout (dtype follows probe flag)
__global__ void __launch_bounds__(256) k_node(const u32* __restrict__ dflag,
                                              const int* __restrict__ ei, const int* __restrict__ et,
                                              const void* __restrict__ ew, const void* __restrict__ x,
                                              const u16* __restrict__ xs, const u16* __restrict__ dots,
                                              const u32* __restrict__ obuf, const u32* __restrict__ elist,
                                              const void* __restrict__ bias, void* __restrict__ vout, int N) {
    bool f32 = dflag[0] != 0u;
    int node = blockIdx.x;
    if (node >= N) return;
    int ch = threadIdx.x;
    int hh = ch >> 5;
    float ad0 = bf2f(dots[(size_t)node * 32 + 16 + hh]);
    float ad1 = bf2f(dots[(size_t)node * 32 + 24 + hh]);
    // self-loop: type 0, weight 1
    float a = bf2f(dots[(size_t)node * 32 + hh]) + ad0;
    float p = __expf(a >= 0.f ? a : 0.2f * a);
    float den = p;
    float num = p * bf2f(xs[(size_t)node * 256 + ch]);
    u32 kbeg = obuf[node], kend = obuf[node + 1];
    for (u32 k = kbeg; k < kend; k++) {
        int e = (int)elist[k];
        int src = ei[e];
        int t = et[e];
        float w = gld(ew, e, f32);
        float aa = bf2f(dots[(size_t)src * 32 + t * 8 + hh]) + (t ? ad1 : ad0);
        float pp = __expf(aa >= 0.f ? aa : 0.2f * aa);
        den += pp;
        num += pp * w * bf2f(xs[(size_t)src * 256 + ch]);
    }
    float v = num / den + gld(bias, ch, f32) + gld(x, (size_t)node * 256 + ch, f32);
    gst(vout, (size_t)node * 256 + ch, f32, v);
}

// ---- LN1 in place on v ([N,256], dtype follows flag) -> h; also emit bf16 copy hb
__global__ void __launch_bounds__(256) k_ln1(const u32* __restrict__ dflag, void* __restrict__ v,
                                             u16* __restrict__ hb,
                                             const void* __restrict__ g, const void* __restrict__ b, int N) {
    bool f32 = dflag[0] != 0u;
    int node = blockIdx.x * 4 + (threadIdx.x >> 6);
    if (node >= N) return;
    int lane = threadIdx.x & 63;
    size_t base = (size_t)node * 256 + lane * 4;
    float v0 = gld(v, base + 0, f32), v1 = gld(v, base + 1, f32);
    float v2 = gld(v, base + 2, f32), v3 = gld(v, base + 3, f32);
    float mu = wave_sum(v0 + v1 + v2 + v3) * (1.f / 256.f);
    float d0 = v0 - mu, d1 = v1 - mu, d2 = v2 - mu, d3 = v3 - mu;
    float var = wave_sum(d0 * d0 + d1 * d1 + d2 * d2 + d3 * d3) * (1.f / 256.f);
    float rs = rsqrtf(var + 1e-5f);
    float o0 = d0 * rs * gld(g, lane * 4 + 0, f32) + gld(b, lane * 4 + 0, f32);
    float o1 = d1 * rs * gld(g, lane * 4 + 1, f32) + gld(b, lane * 4 + 1, f32);
    float o2 = d2 * rs * gld(g, lane * 4 + 2, f32) + gld(b, lane * 4 + 2, f32);
    float o3 = d3 * rs * gld(g, lane * 4 + 3, f32) + gld(b, lane * 4 + 3, f32);
    gst(v, base + 0, f32, o0); gst(v, base + 1, f32, o1);
    gst(v, base + 2, f32, o2); gst(v, base + 3, f32, o3);
    ushort4 hv; hv.x = f2bf(o0); hv.y = f2bf(o1); hv.z = f2bf(o2); hv.w = f2bf(o3);
    *(ushort4*)&hb[base] = hv;
}

// ---- residual + LN2 (chunked, in place on h rows [row0, row0+rows)): out = LN(h + ffn + fb2)
__global__ void __launch_bounds__(256) k_ln2(const u32* __restrict__ dflag,
                                             void* __restrict__ h, int row0, const float* __restrict__ ffn,
                                             const void* __restrict__ fb2, const void* __restrict__ g,
                                             const void* __restrict__ b, int rows) {
    bool f32 = dflag[0] != 0u;
    int row = blockIdx.x * 4 + (threadIdx.x >> 6);
    if (row >= rows) return;
    int lane = threadIdx.x & 63;
    size_t hbase = (size_t)(row0 + row) * 256 + lane * 4;
    size_t fbase = (size_t)row * 256 + lane * 4;
    float4 tv = *(const float4*)(ffn + fbase);
    float v0 = tv.x + gld(h, hbase + 0, f32) + gld(fb2, lane * 4 + 0, f32);
    float v1 = tv.y + gld(h, hbase + 1, f32) + gld(fb2, lane * 4 + 1, f32);
    float v2 = tv.z + gld(h, hbase + 2, f32) + gld(fb2, lane * 4 + 2, f32);
    float v3 = tv.w + gld(h, hbase + 3, f32) + gld(fb2, lane * 4 + 3, f32);
    float mu = wave_sum(v0 + v1 + v2 + v3) * (1.f / 256.f);
    float d0 = v0 - mu, d1 = v1 - mu, d2 = v2 - mu, d3 = v3 - mu;
    float var = wave_sum(d0 * d0 + d1 * d1 + d2 * d2 + d3 * d3) * (1.f / 256.f);
    float rs = rsqrtf(var + 1e-5f);
    gst(h, hbase + 0, f32, d0 * rs * gld(g, lane * 4 + 0, f32) + gld(b, lane * 4 + 0, f32));
    gst(h, hbase + 1, f32, d1 * rs * gld(g, lane * 4 + 1, f32) + gld(b, lane * 4 + 1, f32));
    gst(h, hbase + 2, f32, d2 * rs * gld(g, lane * 4 + 2, f32) + gld(b, lane * 4 + 2, f32));
    gst(h, hbase + 3, f32, d3 * rs * gld(g, lane * 4 + 3, f32) + gld(b, lane * 4 + 3, f32));
}

extern "C" void kernel_launch(void* const* d_in, const int* in_sizes, int n_in,
                              void* d_out, int out_size, void* d_ws, size_t ws_size,
                              hipStream_t stream) {
    const int N = in_sizes[0] / 256;     // 50000
    const int E = in_sizes[1] / 2;       // 800000
    const int NB = (N + 255) / 256;      // 196

    const void* x    = d_in[0];
    const int*  ei   = (const int*)d_in[1];
    const int*  et   = (const int*)d_in[2];
    const void* ew   = d_in[3];
    const void* Wsrc = d_in[4];
    const void* Wdst = d_in[5];
    const void* attS = d_in[6];
    const void* attD = d_in[7];
    const void* bias = d_in[8];
    const void* g1   = d_in[9];
    const void* b1   = d_in[10];
    const void* g2   = d_in[11];
    const void* b2   = d_in[12];
    const void* W1   = d_in[13];
    const void* fb1  = d_in[14];
    const void* W2   = d_in[15];
    const void* fb2  = d_in[16];

    // Workspace layout (bench round 1 proved ws_size >= ~154 MB: one-chunk FFN
    // wrote the full 102.4 MB act). All offsets 16B-aligned.
    char* ws = (char*)d_ws;
    u32* flag   = (u32*)(ws + 0);             // 256 B
    u32* bsum   = (u32*)(ws + 256);           // 1 KB
    u32* obuf   = (u32*)(ws + 1536);          // (N+1)*4 ~ 200 KB
    u32* cursor = (u32*)(ws + 201984);        // N*4 = 200 KB
    u16* dots   = (u16*)(ws + 402176);        // [N,32] bf16 = 3.2 MB
    u32* elist  = (u32*)(ws + 3602176);       // E*4 = 3.2 MB
    u16* xb     = (u16*)(ws + 6802176);       // [N,256] bf16 = 25.6 MB (x pre-cvt)
    u16* hb     = (u16*)(ws + 6802176);       // [N,256] bf16 post-LN1 (xb dead by then)
    u16* xs     = (u16*)(ws + 32402176);      // [N,256] bf16 = x@Wsrc^T, 25.6 MB
    u16* Mmat   = (u16*)(ws + 58002176);      // [32,256] bf16 = 16 KB
    u16* Wsb    = (u16*)(ws + 58018560);      // [256,256] bf16 = 128 KB
    u16* W1b    = (u16*)(ws + 58149632);      // [1024,256] bf16 = 512 KB
    u16* W2b    = (u16*)(ws + 58673920);      // [256,1024] bf16 = 512 KB
    char* ffnbuf = ws + 59198208;             // FFN chunk buffers (runtime sized)
    void* hbuf  = d_out;                      // v -> h -> out staged in d_out (dtype = flag)

    k_probe<<<1, 256, 0, stream>>>((const u16*)x, flag);

    // bf16 pre-conversion of all GEMM operands (identity if inputs already bf16)
    k_cvt<<<(N * 32 + 255) / 256, 256, 0, stream>>>(flag, x, xb, N * 32);       // N*256/8
    k_cvt<<<32, 256, 0, stream>>>(flag, Wsrc, Wsb, 8192);                       // 256*256/8
    k_cvt<<<128, 256, 0, stream>>>(flag, W1, W1b, 32768);                       // 1024*256/8
    k_cvt<<<128, 256, 0, stream>>>(flag, W2, W2b, 32768);                       // 256*1024/8
    k_mkatt<<<32, 256, 0, stream>>>(flag, Wsrc, Wdst, attS, attD, Mmat, 256);

    const int gyN = (N + 127) / 128;          // 391

    // attention logits: dots[N,32] = xb @ Mmat^T ; x_src: xs[N,256] = xb @ Wsb^T
    mgemm2<0, 64><<<dim3(1, gyN), 256, 0, stream>>>(flag, xb, Mmat, dots, nullptr, N, 32, 256, 32, 0);
    mgemm2<0, 128><<<dim3(2, gyN), 256, 0, stream>>>(flag, xb, Wsb, xs, nullptr, N, 256, 256, 256, 0);

    // CSR build
    k_zero<<<NB, 256, 0, stream>>>(obuf, N);
    k_count<<<(E + 255) / 256, 256, 0, stream>>>(ei, obuf, E);
    k_scanA<<<NB, 256, 0, stream>>>(obuf, bsum, N);
    k_scanB<<<1, 256, 0, stream>>>(bsum, NB);
    k_scanC<<<NB, 256, 0, stream>>>(obuf, cursor, bsum, N, E);
    k_scatter<<<(E + 255) / 256, 256, 0, stream>>>(ei, cursor, elist, E);

    // aggregation (one block per node, all 256 channels) + LN1
    k_node<<<N, 256, 0, stream>>>(flag, ei, et, ew, x, xs, dots, obuf, elist, bias, hbuf, N);
    k_ln1<<<(N + 3) / 4, 256, 0, stream>>>(flag, hbuf, hb, g1, b1, N);

    // FFN + LN2, chunked to fit remaining ws: 3072 B/row (act bf16 1024 + ffnout f32 256)
    long long avail = (long long)ws_size - 59198208 - 256;
    int rc = (int)(avail / 3072);
    rc &= ~127;
    if (rc > 50048) rc = 50048;
    if (rc < 128) rc = 128;
    u16*   act    = (u16*)ffnbuf;
    float* ffnout = (float*)(ffnbuf + (size_t)rc * 2048);

    for (int r0 = 0; r0 < N; r0 += rc) {
        int rows = N - r0; if (rows > rc) rows = rc;
        int gy = (rows + 127) / 128;
        mgemm2<1, 128><<<dim3(8, gy), 256, 0, stream>>>(flag, hb, W1b, act, fb1, rows, 1024, 256, 1024, r0);
        mgemm2<2, 128><<<dim3(2, gy), 256, 0, stream>>>(flag, act, W2b, ffnout, nullptr, rows, 256, 1024, 256, 0);
        k_ln2<<<(rows + 3) / 4, 256, 0, stream>>>(flag, hbuf, r0, ffnout, fb2, g2, b2, rows);
    }
}

// Round 3
// 754.462 us; speedup vs baseline: 10.7330x; 1.3736x over previous
//
#include <hip/hip_runtime.h>

typedef unsigned short u16;
typedef unsigned int u32;
typedef __attribute__((ext_vector_type(8))) unsigned short ushort8v;
typedef __attribute__((ext_vector_type(8))) __bf16 bf16x8;
typedef __attribute__((ext_vector_type(4))) float f32x4;

__device__ __forceinline__ float bf2f(u16 u) { return __uint_as_float(((u32)u) << 16); }
__device__ __forceinline__ u16 f2bf(float f) {
    u32 u = __float_as_uint(f);
    u32 r = u + 0x7fffu + ((u >> 16) & 1u);
    return (u16)(r >> 16);
}
__device__ __forceinline__ float wave_sum(float v) {
    #pragma unroll
    for (int m = 1; m < 64; m <<= 1) v += __shfl_xor(v, m, 64);
    return v;
}
// dtype-flexible load/store: f32=true -> float32 buffer, else bf16 (u16) buffer
__device__ __forceinline__ float gld(const void* p, size_t i, bool f32) {
    return f32 ? ((const float*)p)[i] : bf2f(((const u16*)p)[i]);
}
__device__ __forceinline__ void gst(void* p, size_t i, bool f32, float v) {
    if (f32) ((float*)p)[i] = v;
    else     ((u16*)p)[i] = f2bf(v);
}
__device__ __forceinline__ void ldf8(const void* p, size_t i, bool f32, float* o) {
    if (f32) {
        const float4* q = (const float4*)((const float*)p + i);
        float4 a = q[0], b = q[1];
        o[0] = a.x; o[1] = a.y; o[2] = a.z; o[3] = a.w;
        o[4] = b.x; o[5] = b.y; o[6] = b.z; o[7] = b.w;
    } else {
        ushort8v v = *(const ushort8v*)((const u16*)p + i);
        #pragma unroll
        for (int j = 0; j < 8; j++) o[j] = bf2f(v[j]);
    }
}
// async global(bf16)->LDS, 16 bytes per lane; LDS dst is wave-uniform base + lane*16
__device__ __forceinline__ void gl2lds16(const u16* g, u16* l) {
    __builtin_amdgcn_global_load_lds((const __attribute__((address_space(1))) void*)g,
                                     (__attribute__((address_space(3))) void*)l, 16, 0, 0);
}

// ---- dtype probe: bf16 N(0,1) decodes |v|<~5 always; f32 viewed as u16 halves
// has ~48% of low-half words decoding to |v|>64 or NaN -> flags within 1024 floats.
__global__ void __launch_bounds__(256) k_probe(const u16* __restrict__ x, u32* __restrict__ flag) {
    __shared__ int cnt;
    if (threadIdx.x == 0) cnt = 0;
    __syncthreads();
    int bad = 0;
    for (int i = threadIdx.x; i < 2048; i += 256) {
        float v = bf2f(x[i]);
        if (!(v > -64.f && v < 64.f)) bad = 1;
    }
    if (bad) atomicAdd(&cnt, 1);
    __syncthreads();
    if (threadIdx.x == 0) flag[0] = (cnt > 0) ? 1u : 0u;
}

__global__ void __launch_bounds__(256) k_zero(u32* __restrict__ p, int n) {
    int i = blockIdx.x * 256 + threadIdx.x;
    if (i < n) p[i] = 0u;
}

// ---- convert a tensor (dtype per flag) to bf16, 8 elems/thread
__global__ void __launch_bounds__(256) k_cvt(const u32* __restrict__ dflag,
                                             const void* __restrict__ src, u16* __restrict__ dst, int n8) {
    bool f32 = dflag[0] != 0u;
    int i = blockIdx.x * 256 + threadIdx.x;
    if (i >= n8) return;
    float t[8];
    ldf8(src, (size_t)i * 8, f32, t);
    ushort8v o;
    #pragma unroll
    for (int j = 0; j < 8; j++) o[j] = f2bf(t[j]);
    *(ushort8v*)&dst[(size_t)i * 8] = o;
}

// ---- MFMA bf16 GEMM (m97 template): C[m,n] = sum_k A[arow0+m,k]*B[n,k]
// A,B pre-converted bf16, row stride = K elems. Tile 128 x BN, BK=64, 4 waves,
// linear LDS [rows][64] u16, staging via global_load_lds dwordx4 (no VGPR trip).
// XCD-aware bijective block swizzle (m204) for A-panel L2 reuse across grid.x.
// EPI: 0 = bf16 store; 1 = bf16 gelu(acc+bias[col]); 2 = f32 store
template <int EPI, int BN>
__global__ void __launch_bounds__(256) mgemm2(const u32* __restrict__ dflag,
                                              const u16* __restrict__ A, const u16* __restrict__ B,
                                              void* __restrict__ Cout, const void* __restrict__ bias,
                                              int M, int Nn, int K, int ldC, int arow0) {
    const bool ibf32 = dflag[0] != 0u;
    __shared__ __attribute__((aligned(16))) u16 sA[128 * 64];
    __shared__ __attribute__((aligned(16))) u16 sB[BN * 64];

    // XCD swizzle: contiguous chunk of remapped ids per XCD (bijective for any nwg)
    int nwg = gridDim.x * gridDim.y;
    int wgid = blockIdx.y * gridDim.x + blockIdx.x;
    if (nwg >= 16) {
        int q = nwg >> 3, r = nwg & 7;
        int xcd = wgid & 7, i = wgid >> 3;
        wgid = (xcd < r ? xcd * (q + 1) : r * (q + 1) + (xcd - r) * q) + i;
    }
    const int m0 = (wgid / gridDim.x) * 128;
    const int n0 = (wgid % gridDim.x) * BN;

    const int tid = threadIdx.x;
    const int wid = tid >> 6;
    const int lane = tid & 63;

    constexpr int WAVES_N = BN / 64;           // 2 (BN=128) or 1 (BN=64)
    constexpr int WM = (BN == 128) ? 64 : 32;
    constexpr int FM = WM / 16;                // 4 or 2
    constexpr int FN = 4;
    const int wm = (wid / WAVES_N) * WM;
    const int wn = (wid % WAVES_N) * 64;
    const int lr = lane & 15;
    const int lk = (lane >> 4) * 8;

    // staging lane coords: 1024B unit = 8 rows x 128B
    const int srow = lane >> 3;
    const int scol = (lane & 7) * 8;
    constexpr int NBU = BN / 32;               // B units per wave (4 or 2)

    f32x4 acc[FM][FN] = {};

    for (int k0 = 0; k0 < K; k0 += 64) {
        __syncthreads();   // previous tile fully consumed
        #pragma unroll
        for (int j = 0; j < 4; j++) {
            int u = wid * 4 + j;
            int gr = m0 + u * 8 + srow; if (gr >= M) gr = M - 1;
            gl2lds16(A + (size_t)(arow0 + gr) * K + k0 + scol, &sA[u * 512]);
        }
        #pragma unroll
        for (int j = 0; j < NBU; j++) {
            int u = wid * NBU + j;
            int gr = n0 + u * 8 + srow; if (gr >= Nn) gr = Nn - 1;
            gl2lds16(B + (size_t)gr * K + k0 + scol, &sB[u * 512]);
        }
        __syncthreads();   // compiler drains vmcnt(0) before s_barrier -> LDS ready
        #pragma unroll
        for (int h = 0; h < 2; h++) {
            bf16x8 afr[FM], bfr[FN];
            #pragma unroll
            for (int m = 0; m < FM; m++)
                afr[m] = __builtin_bit_cast(bf16x8, *(const ushort8v*)&sA[(wm + m * 16 + lr) * 64 + h * 32 + lk]);
            #pragma unroll
            for (int n = 0; n < FN; n++)
                bfr[n] = __builtin_bit_cast(bf16x8, *(const ushort8v*)&sB[(wn + n * 16 + lr) * 64 + h * 32 + lk]);
            #pragma unroll
            for (int m = 0; m < FM; m++)
                #pragma unroll
                for (int n = 0; n < FN; n++)
                    acc[m][n] = __builtin_amdgcn_mfma_f32_16x16x32_bf16(afr[m], bfr[n], acc[m][n], 0, 0, 0);
        }
    }

    // C/D: col = lane&15, row = (lane>>4)*4 + reg  [verified in passing round-1 kernel]
    const int or0 = (lane >> 4) << 2;
    #pragma unroll
    for (int m = 0; m < FM; m++) {
        #pragma unroll
        for (int r = 0; r < 4; r++) {
            int gr = m0 + wm + m * 16 + or0 + r;
            if (gr >= M) continue;
            #pragma unroll
            for (int n = 0; n < FN; n++) {
                int cn = n0 + wn + n * 16 + lr;
                if (cn >= Nn) continue;
                float v = acc[m][n][r];
                if (EPI == 1) {
                    v += gld(bias, cn, ibf32);
                    v = 0.5f * v * (1.0f + erff(v * 0.70710678f));
                    ((u16*)Cout)[(size_t)gr * ldC + cn] = f2bf(v);
                } else if (EPI == 0) {
                    ((u16*)Cout)[(size_t)gr * ldC + cn] = f2bf(v);
                } else {
                    ((float*)Cout)[(size_t)gr * ldC + cn] = v;
                }
            }
        }
    }
}

// ---- fold attention vectors through W: Mmat[th][k] (bf16, [32,256])
// th<16:  sum_c Wsrc[h*32+c][k] * attS[t,h,c]   (th = t*8+h)
// th>=16: sum_c Wdst[h*32+c][k] * attD[t,h,c]
__global__ void __launch_bounds__(256) k_mkatt(const u32* __restrict__ dflag,
                                               const void* __restrict__ Wsrc, const void* __restrict__ Wdst,
                                               const void* __restrict__ attS, const void* __restrict__ attD,
                                               u16* __restrict__ Mmat, int K) {
    bool f32 = dflag[0] != 0u;
    int th = blockIdx.x;   // 0..31
    int k = threadIdx.x;   // 0..K-1 (K=256)
    int tt = th & 15;
    const void* W = (th < 16) ? Wsrc : Wdst;
    const void* att = (th < 16) ? attS : attD;
    int h = tt & 7;
    float s = 0.f;
    #pragma unroll 8
    for (int c = 0; c < 32; c++)
        s += gld(W, (size_t)(h * 32 + c) * K + k, f32) * gld(att, tt * 32 + c, f32);
    Mmat[th * K + k] = f2bf(s);
}

// ---- CSR build (dst-major) ----
__global__ void __launch_bounds__(256) k_count(const int* __restrict__ ei, u32* __restrict__ cnt, int E) {
    int e = blockIdx.x * 256 + threadIdx.x;
    if (e < E) atomicAdd(cnt + ei[E + e], 1u);
}
__global__ void __launch_bounds__(256) k_scanA(u32* __restrict__ buf, u32* __restrict__ bsum, int N) {
    int t = threadIdx.x, idx = blockIdx.x * 256 + t;
    u32 v = (idx < N) ? buf[idx] : 0u;
    __shared__ u32 sc[256];
    sc[t] = v; __syncthreads();
    for (int d = 1; d < 256; d <<= 1) {
        u32 add = (t >= d) ? sc[t - d] : 0u; __syncthreads();
        sc[t] += add; __syncthreads();
    }
    if (idx < N) buf[idx] = sc[t] - v;
    if (t == 255) bsum[blockIdx.x] = sc[255];
}
__global__ void __launch_bounds__(256) k_scanB(u32* __restrict__ bsum, int nb) {
    int t = threadIdx.x;
    u32 v = (t < nb) ? bsum[t] : 0u;
    __shared__ u32 sc[256];
    sc[t] = v; __syncthreads();
    for (int d = 1; d < 256; d <<= 1) {
        u32 add = (t >= d) ? sc[t - d] : 0u; __syncthreads();
        sc[t] += add; __syncthreads();
    }
    if (t < nb) bsum[t] = sc[t] - v;
}
__global__ void __launch_bounds__(256) k_scanC(u32* __restrict__ obuf, u32* __restrict__ cursor,
                                               const u32* __restrict__ bsum, int N, int E) {
    int idx = blockIdx.x * 256 + threadIdx.x;
    if (idx < N) {
        u32 o = obuf[idx] + bsum[blockIdx.x];
        obuf[idx] = o;
        cursor[idx] = o;
    }
    if (blockIdx.x == 0 && threadIdx.x == 0) obuf[N] = (u32)E;
}
__global__ void __launch_bounds__(256) k_scatter(const int* __restrict__ ei, u32* __restrict__ cursor,
                                                 u32* __restrict__ elist, int E) {
    int e = blockIdx.x * 256 + threadIdx.x;
    if (e >= E) return;
    u32 slot = atomicAdd(cursor + ei[E + e], 1u);
    elist[slot] = (u32)e;
}

// ---- fused per-node softmax aggregation, two-phase chunked:
// phase 1: stage up to 64 edges' {src, w, p[8]} into LDS (1 thread/edge computes
//          the 8 head exps ONCE -- kills 32x redundant exp + dependent meta chain)
// phase 2: 256 channel-threads accumulate; only remaining memory op is the xs row
//          gather, 4-way unrolled (4 independent gathers in flight per wave).
// writes v = agg + bias + x (pre-LN) into vout (dtype follows probe flag)
__global__ void __launch_bounds__(256) k_node(const u32* __restrict__ dflag,
                                              const int* __restrict__ ei, const int* __restrict__ et,
                                              const void* __restrict__ ew, const void* __restrict__ x,
                                              const u16* __restrict__ xs, const u16* __restrict__ dots,
                                              const u32* __restrict__ obuf, const u32* __restrict__ elist,
                                              const void* __restrict__ bias, void* __restrict__ vout, int N) {
    bool f32 = dflag[0] != 0u;
    int node = blockIdx.x;
    if (node >= N) return;
    int tid = threadIdx.x;
    int ch = tid;
    int hh = ch >> 5;
    __shared__ u32 s_src[64];
    __shared__ float s_w[64];
    __shared__ float s_pe[64][8];

    // self-loop: type 0, weight 1
    float a = bf2f(dots[(size_t)node * 32 + hh]) + bf2f(dots[(size_t)node * 32 + 16 + hh]);
    float p = __expf(a >= 0.f ? a : 0.2f * a);
    float den = p;
    float num = p * bf2f(xs[(size_t)node * 256 + ch]);

    u32 kbeg = obuf[node], kend = obuf[node + 1];
    for (u32 c0 = kbeg; c0 < kend; c0 += 64) {
        int cnt = (int)(kend - c0) < 64 ? (int)(kend - c0) : 64;
        __syncthreads();   // previous chunk's LDS fully consumed
        if (tid < cnt) {
            int e = (int)elist[c0 + tid];
            int src = ei[e];
            int t = et[e];
            s_src[tid] = (u32)src;
            s_w[tid] = gld(ew, e, f32);
            const u16* ds = &dots[(size_t)src * 32 + t * 8];
            const u16* dd = &dots[(size_t)node * 32 + 16 + t * 8];
            #pragma unroll
            for (int h = 0; h < 8; h++) {
                float aa = bf2f(ds[h]) + bf2f(dd[h]);
                s_pe[tid][h] = __expf(aa >= 0.f ? aa : 0.2f * aa);
            }
        }
        __syncthreads();
        float n0 = 0.f, n1 = 0.f, n2 = 0.f, n3 = 0.f;
        float d0 = 0.f, d1 = 0.f, d2 = 0.f, d3 = 0.f;
        int k = 0;
        for (; k + 4 <= cnt; k += 4) {
            u32 sa = s_src[k], sb = s_src[k + 1], sc = s_src[k + 2], sd = s_src[k + 3];
            float pa = s_pe[k][hh], pb = s_pe[k + 1][hh], pc = s_pe[k + 2][hh], pd = s_pe[k + 3][hh];
            float wa = s_w[k], wb = s_w[k + 1], wc = s_w[k + 2], wd = s_w[k + 3];
            float xa = bf2f(xs[(size_t)sa * 256 + ch]);
            float xb = bf2f(xs[(size_t)sb * 256 + ch]);
            float xc = bf2f(xs[(size_t)sc * 256 + ch]);
            float xd = bf2f(xs[(size_t)sd * 256 + ch]);
            n0 += pa * wa * xa; n1 += pb * wb * xb;
            n2 += pc * wc * xc; n3 += pd * wd * xd;
            d0 += pa; d1 += pb; d2 += pc; d3 += pd;
        }
        for (; k < cnt; k++) {
            float pp = s_pe[k][hh];
            num += pp * s_w[k] * bf2f(xs[(size_t)s_src[k] * 256 + ch]);
            den += pp;
        }
        num += (n0 + n1) + (n2 + n3);
        den += (d0 + d1) + (d2 + d3);
    }
    float v = num / den + gld(bias, ch, f32) + gld(x, (size_t)node * 256 + ch, f32);
    gst(vout, (size_t)node * 256 + ch, f32, v);
}

// ---- LN1 in place on v ([N,256], dtype follows flag) -> h; also emit bf16 copy hb
__global__ void __launch_bounds__(256) k_ln1(const u32* __restrict__ dflag, void* __restrict__ v,
                                             u16* __restrict__ hb,
                                             const void* __restrict__ g, const void* __restrict__ b, int N) {
    bool f32 = dflag[0] != 0u;
    int node = blockIdx.x * 4 + (threadIdx.x >> 6);
    if (node >= N) return;
    int lane = threadIdx.x & 63;
    size_t base = (size_t)node * 256 + lane * 4;
    float v0 = gld(v, base + 0, f32), v1 = gld(v, base + 1, f32);
    float v2 = gld(v, base + 2, f32), v3 = gld(v, base + 3, f32);
    float mu = wave_sum(v0 + v1 + v2 + v3) * (1.f / 256.f);
    float d0 = v0 - mu, d1 = v1 - mu, d2 = v2 - mu, d3 = v3 - mu;
    float var = wave_sum(d0 * d0 + d1 * d1 + d2 * d2 + d3 * d3) * (1.f / 256.f);
    float rs = rsqrtf(var + 1e-5f);
    float o0 = d0 * rs * gld(g, lane * 4 + 0, f32) + gld(b, lane * 4 + 0, f32);
    float o1 = d1 * rs * gld(g, lane * 4 + 1, f32) + gld(b, lane * 4 + 1, f32);
    float o2 = d2 * rs * gld(g, lane * 4 + 2, f32) + gld(b, lane * 4 + 2, f32);
    float o3 = d3 * rs * gld(g, lane * 4 + 3, f32) + gld(b, lane * 4 + 3, f32);
    gst(v, base + 0, f32, o0); gst(v, base + 1, f32, o1);
    gst(v, base + 2, f32, o2); gst(v, base + 3, f32, o3);
    ushort4 hv; hv.x = f2bf(o0); hv.y = f2bf(o1); hv.z = f2bf(o2); hv.w = f2bf(o3);
    *(ushort4*)&hb[base] = hv;
}

// ---- residual + LN2 (chunked, in place on h rows [row0, row0+rows)): out = LN(h + ffn + fb2)
__global__ void __launch_bounds__(256) k_ln2(const u32* __restrict__ dflag,
                                             void* __restrict__ h, int row0, const float* __restrict__ ffn,
                                             const void* __restrict__ fb2, const void* __restrict__ g,
                                             const void* __restrict__ b, int rows) {
    bool f32 = dflag[0] != 0u;
    int row = blockIdx.x * 4 + (threadIdx.x >> 6);
    if (row >= rows) return;
    int lane = threadIdx.x & 63;
    size_t hbase = (size_t)(row0 + row) * 256 + lane * 4;
    size_t fbase = (size_t)row * 256 + lane * 4;
    float4 tv = *(const float4*)(ffn + fbase);
    float v0 = tv.x + gld(h, hbase + 0, f32) + gld(fb2, lane * 4 + 0, f32);
    float v1 = tv.y + gld(h, hbase + 1, f32) + gld(fb2, lane * 4 + 1, f32);
    float v2 = tv.z + gld(h, hbase + 2, f32) + gld(fb2, lane * 4 + 2, f32);
    float v3 = tv.w + gld(h, hbase + 3, f32) + gld(fb2, lane * 4 + 3, f32);
    float mu = wave_sum(v0 + v1 + v2 + v3) * (1.f / 256.f);
    float d0 = v0 - mu, d1 = v1 - mu, d2 = v2 - mu, d3 = v3 - mu;
    float var = wave_sum(d0 * d0 + d1 * d1 + d2 * d2 + d3 * d3) * (1.f / 256.f);
    float rs = rsqrtf(var + 1e-5f);
    gst(h, hbase + 0, f32, d0 * rs * gld(g, lane * 4 + 0, f32) + gld(b, lane * 4 + 0, f32));
    gst(h, hbase + 1, f32, d1 * rs * gld(g, lane * 4 + 1, f32) + gld(b, lane * 4 + 1, f32));
    gst(h, hbase + 2, f32, d2 * rs * gld(g, lane * 4 + 2, f32) + gld(b, lane * 4 + 2, f32));
    gst(h, hbase + 3, f32, d3 * rs * gld(g, lane * 4 + 3, f32) + gld(b, lane * 4 + 3, f32));
}

extern "C" void kernel_launch(void* const* d_in, const int* in_sizes, int n_in,
                              void* d_out, int out_size, void* d_ws, size_t ws_size,
                              hipStream_t stream) {
    const int N = in_sizes[0] / 256;     // 50000
    const int E = in_sizes[1] / 2;       // 800000
    const int NB = (N + 255) / 256;      // 196

    const void* x    = d_in[0];
    const int*  ei   = (const int*)d_in[1];
    const int*  et   = (const int*)d_in[2];
    const void* ew   = d_in[3];
    const void* Wsrc = d_in[4];
    const void* Wdst = d_in[5];
    const void* attS = d_in[6];
    const void* attD = d_in[7];
    const void* bias = d_in[8];
    const void* g1   = d_in[9];
    const void* b1   = d_in[10];
    const void* g2   = d_in[11];
    const void* b2   = d_in[12];
    const void* W1   = d_in[13];
    const void* fb1  = d_in[14];
    const void* W2   = d_in[15];
    const void* fb2  = d_in[16];

    // Workspace layout (round 1 proved ws_size >= ~154 MB). All offsets 16B-aligned.
    char* ws = (char*)d_ws;
    u32* flag   = (u32*)(ws + 0);             // 256 B
    u32* bsum   = (u32*)(ws + 256);           // 1 KB
    u32* obuf   = (u32*)(ws + 1536);          // (N+1)*4 ~ 200 KB
    u32* cursor = (u32*)(ws + 201984);        // N*4 = 200 KB
    u16* dots   = (u16*)(ws + 402176);        // [N,32] bf16 = 3.2 MB
    u32* elist  = (u32*)(ws + 3602176);       // E*4 = 3.2 MB
    u16* xb     = (u16*)(ws + 6802176);       // [N,256] bf16 = 25.6 MB (x pre-cvt)
    u16* hb     = (u16*)(ws + 6802176);       // [N,256] bf16 post-LN1 (xb dead by then)
    u16* xs     = (u16*)(ws + 32402176);      // [N,256] bf16 = x@Wsrc^T, 25.6 MB
    u16* Mmat   = (u16*)(ws + 58002176);      // [32,256] bf16 = 16 KB
    u16* Wsb    = (u16*)(ws + 58018560);      // [256,256] bf16 = 128 KB
    u16* W1b    = (u16*)(ws + 58149632);      // [1024,256] bf16 = 512 KB
    u16* W2b    = (u16*)(ws + 58673920);      // [256,1024] bf16 = 512 KB
    char* ffnbuf = ws + 59198208;             // FFN chunk buffers (runtime sized)
    void* hbuf  = d_out;                      // v -> h -> out staged in d_out (dtype = flag)

    k_probe<<<1, 256, 0, stream>>>((const u16*)x, flag);

    // bf16 pre-conversion of all GEMM operands (identity if inputs already bf16)
    k_cvt<<<(N * 32 + 255) / 256, 256, 0, stream>>>(flag, x, xb, N * 32);       // N*256/8
    k_cvt<<<32, 256, 0, stream>>>(flag, Wsrc, Wsb, 8192);                       // 256*256/8
    k_cvt<<<128, 256, 0, stream>>>(flag, W1, W1b, 32768);                       // 1024*256/8
    k_cvt<<<128, 256, 0, stream>>>(flag, W2, W2b, 32768);                       // 256*1024/8
    k_mkatt<<<32, 256, 0, stream>>>(flag, Wsrc, Wdst, attS, attD, Mmat, 256);

    const int gyN = (N + 127) / 128;          // 391

    // attention logits: dots[N,32] = xb @ Mmat^T ; x_src: xs[N,256] = xb @ Wsb^T
    mgemm2<0, 64><<<dim3(1, gyN), 256, 0, stream>>>(flag, xb, Mmat, dots, nullptr, N, 32, 256, 32, 0);
    mgemm2<0, 128><<<dim3(2, gyN), 256, 0, stream>>>(flag, xb, Wsb, xs, nullptr, N, 256, 256, 256, 0);

    // CSR build
    k_zero<<<NB, 256, 0, stream>>>(obuf, N);
    k_count<<<(E + 255) / 256, 256, 0, stream>>>(ei, obuf, E);
    k_scanA<<<NB, 256, 0, stream>>>(obuf, bsum, N);
    k_scanB<<<1, 256, 0, stream>>>(bsum, NB);
    k_scanC<<<NB, 256, 0, stream>>>(obuf, cursor, bsum, N, E);
    k_scatter<<<(E + 255) / 256, 256, 0, stream>>>(ei, cursor, elist, E);

    // aggregation (one block per node, all 256 channels) + LN1
    k_node<<<N, 256, 0, stream>>>(flag, ei, et, ew, x, xs, dots, obuf, elist, bias, hbuf, N);
    k_ln1<<<(N + 3) / 4, 256, 0, stream>>>(flag, hbuf, hb, g1, b1, N);

    // FFN + LN2, chunked to fit remaining ws: 3072 B/row (act bf16 1024 + ffnout f32 256)
    long long avail = (long long)ws_size - 59198208 - 256;
    int rc = (int)(avail / 3072);
    rc &= ~127;
    if (rc > 50048) rc = 50048;
    if (rc < 128) rc = 128;
    u16*   act    = (u16*)ffnbuf;
    float* ffnout = (float*)(ffnbuf + (size_t)rc * 2048);

    for (int r0 = 0; r0 < N; r0 += rc) {
        int rows = N - r0; if (rows > rc) rows = rc;
        int gy = (rows + 127) / 128;
        mgemm2<1, 128><<<dim3(8, gy), 256, 0, stream>>>(flag, hb, W1b, act, fb1, rows, 1024, 256, 1024, r0);
        mgemm2<2, 128><<<dim3(2, gy), 256, 0, stream>>>(flag, act, W2b, ffnout, nullptr, rows, 256, 1024, 256, 0);
        k_ln2<<<(rows + 3) / 4, 256, 0, stream>>>(flag, hbuf, r0, ffnout, fb2, g2, b2, rows);
    }
}

// Round 4
// 692.373 us; speedup vs baseline: 11.6955x; 1.0897x over previous
//
#include <hip/hip_runtime.h>

typedef unsigned short u16;
typedef unsigned int u32;
typedef __attribute__((ext_vector_type(8))) unsigned short ushort8v;
typedef __attribute__((ext_vector_type(8))) __bf16 bf16x8;
typedef __attribute__((ext_vector_type(4))) float f32x4;

__device__ __forceinline__ float bf2f(u16 u) { return __uint_as_float(((u32)u) << 16); }
__device__ __forceinline__ u16 f2bf(float f) {
    u32 u = __float_as_uint(f);
    u32 r = u + 0x7fffu + ((u >> 16) & 1u);
    return (u16)(r >> 16);
}
__device__ __forceinline__ float wave_sum(float v) {
    #pragma unroll
    for (int m = 1; m < 64; m <<= 1) v += __shfl_xor(v, m, 64);
    return v;
}
// dtype-flexible load/store: f32=true -> float32 buffer, else bf16 (u16) buffer
__device__ __forceinline__ float gld(const void* p, size_t i, bool f32) {
    return f32 ? ((const float*)p)[i] : bf2f(((const u16*)p)[i]);
}
__device__ __forceinline__ void gst(void* p, size_t i, bool f32, float v) {
    if (f32) ((float*)p)[i] = v;
    else     ((u16*)p)[i] = f2bf(v);
}
__device__ __forceinline__ void ldf8(const void* p, size_t i, bool f32, float* o) {
    if (f32) {
        const float4* q = (const float4*)((const float*)p + i);
        float4 a = q[0], b = q[1];
        o[0] = a.x; o[1] = a.y; o[2] = a.z; o[3] = a.w;
        o[4] = b.x; o[5] = b.y; o[6] = b.z; o[7] = b.w;
    } else {
        ushort8v v = *(const ushort8v*)((const u16*)p + i);
        #pragma unroll
        for (int j = 0; j < 8; j++) o[j] = bf2f(v[j]);
    }
}
// async global(bf16)->LDS, 16 bytes per lane; LDS dst is wave-uniform base + lane*16
__device__ __forceinline__ void gl2lds16(const u16* g, u16* l) {
    __builtin_amdgcn_global_load_lds((const __attribute__((address_space(1))) void*)g,
                                     (__attribute__((address_space(3))) void*)l, 16, 0, 0);
}
// fast gelu: A&S 3-term erf, |err(erf)| <= 2.5e-5 (invisible under bf16 rounding)
__device__ __forceinline__ float gelu_f(float v) {
    float ay = fabsf(v) * 0.70710678f;
    float t = __builtin_amdgcn_rcpf(1.0f + 0.47047f * ay);
    float poly = t * (0.3480242f + t * (-0.0958798f + t * 0.7478556f));
    float erfa = 1.0f - poly * __expf(-ay * ay);
    float er = (v >= 0.f) ? erfa : -erfa;
    return 0.5f * v * (1.0f + er);
}

// ---- dtype probe: bf16 N(0,1) decodes |v|<~5 always; f32 viewed as u16 halves
// has ~48% of low-half words decoding to |v|>64 or NaN -> flags within 1024 floats.
__global__ void __launch_bounds__(256) k_probe(const u16* __restrict__ x, u32* __restrict__ flag) {
    __shared__ int cnt;
    if (threadIdx.x == 0) cnt = 0;
    __syncthreads();
    int bad = 0;
    for (int i = threadIdx.x; i < 2048; i += 256) {
        float v = bf2f(x[i]);
        if (!(v > -64.f && v < 64.f)) bad = 1;
    }
    if (bad) atomicAdd(&cnt, 1);
    __syncthreads();
    if (threadIdx.x == 0) flag[0] = (cnt > 0) ? 1u : 0u;
}

__global__ void __launch_bounds__(256) k_zero(u32* __restrict__ p, int n) {
    int i = blockIdx.x * 256 + threadIdx.x;
    if (i < n) p[i] = 0u;
}

// ---- convert a tensor (dtype per flag) to bf16, 8 elems/thread
__global__ void __launch_bounds__(256) k_cvt(const u32* __restrict__ dflag,
                                             const void* __restrict__ src, u16* __restrict__ dst, int n8) {
    bool f32 = dflag[0] != 0u;
    int i = blockIdx.x * 256 + threadIdx.x;
    if (i >= n8) return;
    float t[8];
    ldf8(src, (size_t)i * 8, f32, t);
    ushort8v o;
    #pragma unroll
    for (int j = 0; j < 8; j++) o[j] = f2bf(t[j]);
    *(ushort8v*)&dst[(size_t)i * 8] = o;
}

// ---- MFMA bf16 GEMM, double-buffered + swizzled: C[m,n] = sum_k A[arow0+m,k]*B[n,k]
// Tile 128x128, BK=64, 4 waves (2x2 of 64x64), v_mfma_f32_16x16x32_bf16.
// LDS: 2 buffers x (A,B) x [128 rows][8 granules of 16B]; granule XOR-swizzled by
// (row&7) on BOTH sides (pre-swizzled per-lane GLOBAL source for global_load_lds,
// same involution on ds_read) -> balanced banks, conflict-free (was 16-lane/group).
// One barrier per K-step; next tile's loads issued BEFORE current compute so HBM
// latency overlaps ds_read+MFMA (this shape is latency-bound: K=256/1024 only).
// EPI: 0 = bf16 store; 1 = bf16 gelu(acc+bias[col]); 2 = f32 store
template <int EPI>
__global__ void __launch_bounds__(256) mgemm3(const u32* __restrict__ dflag,
                                              const u16* __restrict__ A, const u16* __restrict__ B,
                                              void* __restrict__ Cout, const void* __restrict__ bias,
                                              int M, int Nn, int K, int ldC, int arow0) {
    const bool ibf32 = dflag[0] != 0u;
    __shared__ __attribute__((aligned(16))) u16 sA[2][128 * 64];
    __shared__ __attribute__((aligned(16))) u16 sB[2][128 * 64];

    // XCD swizzle: contiguous chunk of remapped ids per XCD (bijective for any nwg)
    int nwg = gridDim.x * gridDim.y;
    int wgid = blockIdx.y * gridDim.x + blockIdx.x;
    if (nwg >= 16) {
        int q = nwg >> 3, r = nwg & 7;
        int xcd = wgid & 7, i = wgid >> 3;
        wgid = (xcd < r ? xcd * (q + 1) : r * (q + 1) + (xcd - r) * q) + i;
    }
    const int m0 = (wgid / gridDim.x) * 128;
    const int n0 = (wgid % gridDim.x) * 128;

    const int tid = threadIdx.x;
    const int wid = tid >> 6;
    const int lane = tid & 63;

    const int wm = (wid >> 1) * 64;
    const int wn = (wid & 1) * 64;
    const int lr = lane & 15;

    // staging lane coords: unit = 8 rows x 128B; lane covers row u*8+(lane>>3),
    // source granule pre-swizzled: (lane&7) ^ (lane>>3)  [involution with read side]
    const int srow = lane >> 3;
    const int scol = ((lane & 7) ^ (lane >> 3)) * 8;

    f32x4 acc[4][4] = {};

    const size_t abase = (size_t)arow0 * K;

    // prologue: stage tile 0 into buf 0
    {
        #pragma unroll
        for (int j = 0; j < 4; j++) {
            int u = wid * 4 + j;
            int gr = m0 + u * 8 + srow; if (gr >= M) gr = M - 1;
            gl2lds16(A + abase + (size_t)gr * K + scol, &sA[0][u * 512]);
        }
        #pragma unroll
        for (int j = 0; j < 4; j++) {
            int u = wid * 4 + j;
            int gr = n0 + u * 8 + srow; if (gr >= Nn) gr = Nn - 1;
            gl2lds16(B + (size_t)gr * K + scol, &sB[0][u * 512]);
        }
    }
    __syncthreads();   // compiler drains vmcnt(0) before s_barrier -> buf0 ready

    int cur = 0;
    for (int k0 = 0; k0 < K; k0 += 64) {
        // issue next tile's loads FIRST (latency hides under compute below)
        if (k0 + 64 < K) {
            int nb = cur ^ 1, k1 = k0 + 64;
            #pragma unroll
            for (int j = 0; j < 4; j++) {
                int u = wid * 4 + j;
                int gr = m0 + u * 8 + srow; if (gr >= M) gr = M - 1;
                gl2lds16(A + abase + (size_t)gr * K + k1 + scol, &sA[nb][u * 512]);
            }
            #pragma unroll
            for (int j = 0; j < 4; j++) {
                int u = wid * 4 + j;
                int gr = n0 + u * 8 + srow; if (gr >= Nn) gr = Nn - 1;
                gl2lds16(B + (size_t)gr * K + k1 + scol, &sB[nb][u * 512]);
            }
        }
        // compute current buffer
        #pragma unroll
        for (int h = 0; h < 2; h++) {
            const int g = ((h * 4 + (lane >> 4)) ^ (lr & 7)) * 8;  // swizzled granule
            bf16x8 afr[4], bfr[4];
            #pragma unroll
            for (int m = 0; m < 4; m++)
                afr[m] = __builtin_bit_cast(bf16x8, *(const ushort8v*)&sA[cur][(wm + m * 16 + lr) * 64 + g]);
            #pragma unroll
            for (int n = 0; n < 4; n++)
                bfr[n] = __builtin_bit_cast(bf16x8, *(const ushort8v*)&sB[cur][(wn + n * 16 + lr) * 64 + g]);
            #pragma unroll
            for (int m = 0; m < 4; m++)
                #pragma unroll
                for (int n = 0; n < 4; n++)
                    acc[m][n] = __builtin_amdgcn_mfma_f32_16x16x32_bf16(afr[m], bfr[n], acc[m][n], 0, 0, 0);
        }
        __syncthreads();   // drains this wave's prefetch (vmcnt(0)) + syncs buffer flip
        cur ^= 1;
    }

    // C/D: col = lane&15, row = (lane>>4)*4 + reg  [harness-verified rounds 1-3]
    const int or0 = (lane >> 4) << 2;
    #pragma unroll
    for (int m = 0; m < 4; m++) {
        #pragma unroll
        for (int r = 0; r < 4; r++) {
            int gr = m0 + wm + m * 16 + or0 + r;
            if (gr >= M) continue;
            #pragma unroll
            for (int n = 0; n < 4; n++) {
                int cn = n0 + wn + n * 16 + lr;
                if (cn >= Nn) continue;
                float v = acc[m][n][r];
                if (EPI == 1) {
                    v += gld(bias, cn, ibf32);
                    ((u16*)Cout)[(size_t)gr * ldC + cn] = f2bf(gelu_f(v));
                } else if (EPI == 0) {
                    ((u16*)Cout)[(size_t)gr * ldC + cn] = f2bf(v);
                } else {
                    ((float*)Cout)[(size_t)gr * ldC + cn] = v;
                }
            }
        }
    }
}

// ---- fold attention vectors through W: Mmat[th][k] (bf16, [32,256])
// th<16:  sum_c Wsrc[h*32+c][k] * attS[t,h,c]   (th = t*8+h)
// th>=16: sum_c Wdst[h*32+c][k] * attD[t,h,c]
__global__ void __launch_bounds__(256) k_mkatt(const u32* __restrict__ dflag,
                                               const void* __restrict__ Wsrc, const void* __restrict__ Wdst,
                                               const void* __restrict__ attS, const void* __restrict__ attD,
                                               u16* __restrict__ Mmat, int K) {
    bool f32 = dflag[0] != 0u;
    int th = blockIdx.x;   // 0..31
    int k = threadIdx.x;   // 0..K-1 (K=256)
    int tt = th & 15;
    const void* W = (th < 16) ? Wsrc : Wdst;
    const void* att = (th < 16) ? attS : attD;
    int h = tt & 7;
    float s = 0.f;
    #pragma unroll 8
    for (int c = 0; c < 32; c++)
        s += gld(W, (size_t)(h * 32 + c) * K + k, f32) * gld(att, tt * 32 + c, f32);
    Mmat[th * K + k] = f2bf(s);
}

// ---- CSR build (dst-major) ----
__global__ void __launch_bounds__(256) k_count(const int* __restrict__ ei, u32* __restrict__ cnt, int E) {
    int e = blockIdx.x * 256 + threadIdx.x;
    if (e < E) atomicAdd(cnt + ei[E + e], 1u);
}
__global__ void __launch_bounds__(256) k_scanA(u32* __restrict__ buf, u32* __restrict__ bsum, int N) {
    int t = threadIdx.x, idx = blockIdx.x * 256 + t;
    u32 v = (idx < N) ? buf[idx] : 0u;
    __shared__ u32 sc[256];
    sc[t] = v; __syncthreads();
    for (int d = 1; d < 256; d <<= 1) {
        u32 add = (t >= d) ? sc[t - d] : 0u; __syncthreads();
        sc[t] += add; __syncthreads();
    }
    if (idx < N) buf[idx] = sc[t] - v;
    if (t == 255) bsum[blockIdx.x] = sc[255];
}
__global__ void __launch_bounds__(256) k_scanB(u32* __restrict__ bsum, int nb) {
    int t = threadIdx.x;
    u32 v = (t < nb) ? bsum[t] : 0u;
    __shared__ u32 sc[256];
    sc[t] = v; __syncthreads();
    for (int d = 1; d < 256; d <<= 1) {
        u32 add = (t >= d) ? sc[t - d] : 0u; __syncthreads();
        sc[t] += add; __syncthreads();
    }
    if (t < nb) bsum[t] = sc[t] - v;
}
__global__ void __launch_bounds__(256) k_scanC(u32* __restrict__ obuf, u32* __restrict__ cursor,
                                               const u32* __restrict__ bsum, int N, int E) {
    int idx = blockIdx.x * 256 + threadIdx.x;
    if (idx < N) {
        u32 o = obuf[idx] + bsum[blockIdx.x];
        obuf[idx] = o;
        cursor[idx] = o;
    }
    if (blockIdx.x == 0 && threadIdx.x == 0) obuf[N] = (u32)E;
}
__global__ void __launch_bounds__(256) k_scatter(const int* __restrict__ ei, u32* __restrict__ cursor,
                                                 u32* __restrict__ elist, int E) {
    int e = blockIdx.x * 256 + threadIdx.x;
    if (e >= E) return;
    u32 slot = atomicAdd(cursor + ei[E + e], 1u);
    elist[slot] = (u32)e;
}

// ---- fused per-node softmax aggregation, two-phase chunked (round-3 structure).
// xsd = [N,288] bf16: cols 0..255 = x@Wsrc^T, cols 256..287 = the 32 att dots.
__global__ void __launch_bounds__(256) k_node(const u32* __restrict__ dflag,
                                              const int* __restrict__ ei, const int* __restrict__ et,
                                              const void* __restrict__ ew, const void* __restrict__ x,
                                              const u16* __restrict__ xsd,
                                              const u32* __restrict__ obuf, const u32* __restrict__ elist,
                                              const void* __restrict__ bias, void* __restrict__ vout, int N) {
    bool f32 = dflag[0] != 0u;
    int node = blockIdx.x;
    if (node >= N) return;
    int tid = threadIdx.x;
    int ch = tid;
    int hh = ch >> 5;
    __shared__ u32 s_src[64];
    __shared__ float s_w[64];
    __shared__ float s_pe[64][8];

    const size_t nbase = (size_t)node * 288;
    // self-loop: type 0, weight 1
    float a = bf2f(xsd[nbase + 256 + hh]) + bf2f(xsd[nbase + 256 + 16 + hh]);
    float p = __expf(a >= 0.f ? a : 0.2f * a);
    float den = p;
    float num = p * bf2f(xsd[nbase + ch]);

    u32 kbeg = obuf[node], kend = obuf[node + 1];
    for (u32 c0 = kbeg; c0 < kend; c0 += 64) {
        int cnt = (int)(kend - c0) < 64 ? (int)(kend - c0) : 64;
        __syncthreads();   // previous chunk's LDS fully consumed
        if (tid < cnt) {
            int e = (int)elist[c0 + tid];
            int src = ei[e];
            int t = et[e];
            s_src[tid] = (u32)src;
            s_w[tid] = gld(ew, e, f32);
            const u16* ds = &xsd[(size_t)src * 288 + 256 + t * 8];
            const u16* dd = &xsd[nbase + 256 + 16 + t * 8];
            #pragma unroll
            for (int h = 0; h < 8; h++) {
                float aa = bf2f(ds[h]) + bf2f(dd[h]);
                s_pe[tid][h] = __expf(aa >= 0.f ? aa : 0.2f * aa);
            }
        }
        __syncthreads();
        float n0 = 0.f, n1 = 0.f, n2 = 0.f, n3 = 0.f;
        float d0 = 0.f, d1 = 0.f, d2 = 0.f, d3 = 0.f;
        int k = 0;
        for (; k + 4 <= cnt; k += 4) {
            u32 sa = s_src[k], sb = s_src[k + 1], sc = s_src[k + 2], sd = s_src[k + 3];
            float pa = s_pe[k][hh], pb = s_pe[k + 1][hh], pc = s_pe[k + 2][hh], pd = s_pe[k + 3][hh];
            float wa = s_w[k], wb = s_w[k + 1], wc = s_w[k + 2], wd = s_w[k + 3];
            float xa = bf2f(xsd[(size_t)sa * 288 + ch]);
            float xb = bf2f(xsd[(size_t)sb * 288 + ch]);
            float xc = bf2f(xsd[(size_t)sc * 288 + ch]);
            float xd = bf2f(xsd[(size_t)sd * 288 + ch]);
            n0 += pa * wa * xa; n1 += pb * wb * xb;
            n2 += pc * wc * xc; n3 += pd * wd * xd;
            d0 += pa; d1 += pb; d2 += pc; d3 += pd;
        }
        for (; k < cnt; k++) {
            float pp = s_pe[k][hh];
            num += pp * s_w[k] * bf2f(xsd[(size_t)s_src[k] * 288 + ch]);
            den += pp;
        }
        num += (n0 + n1) + (n2 + n3);
        den += (d0 + d1) + (d2 + d3);
    }
    float v = num / den + gld(bias, ch, f32) + gld(x, (size_t)node * 256 + ch, f32);
    gst(vout, (size_t)node * 256 + ch, f32, v);
}

// ---- LN1 in place on v ([N,256], dtype follows flag) -> h; also emit bf16 copy hb
__global__ void __launch_bounds__(256) k_ln1(const u32* __restrict__ dflag, void* __restrict__ v,
                                             u16* __restrict__ hb,
                                             const void* __restrict__ g, const void* __restrict__ b, int N) {
    bool f32 = dflag[0] != 0u;
    int node = blockIdx.x * 4 + (threadIdx.x >> 6);
    if (node >= N) return;
    int lane = threadIdx.x & 63;
    size_t base = (size_t)node * 256 + lane * 4;
    float v0 = gld(v, base + 0, f32), v1 = gld(v, base + 1, f32);
    float v2 = gld(v, base + 2, f32), v3 = gld(v, base + 3, f32);
    float mu = wave_sum(v0 + v1 + v2 + v3) * (1.f / 256.f);
    float d0 = v0 - mu, d1 = v1 - mu, d2 = v2 - mu, d3 = v3 - mu;
    float var = wave_sum(d0 * d0 + d1 * d1 + d2 * d2 + d3 * d3) * (1.f / 256.f);
    float rs = rsqrtf(var + 1e-5f);
    float o0 = d0 * rs * gld(g, lane * 4 + 0, f32) + gld(b, lane * 4 + 0, f32);
    float o1 = d1 * rs * gld(g, lane * 4 + 1, f32) + gld(b, lane * 4 + 1, f32);
    float o2 = d2 * rs * gld(g, lane * 4 + 2, f32) + gld(b, lane * 4 + 2, f32);
    float o3 = d3 * rs * gld(g, lane * 4 + 3, f32) + gld(b, lane * 4 + 3, f32);
    gst(v, base + 0, f32, o0); gst(v, base + 1, f32, o1);
    gst(v, base + 2, f32, o2); gst(v, base + 3, f32, o3);
    ushort4 hv; hv.x = f2bf(o0); hv.y = f2bf(o1); hv.z = f2bf(o2); hv.w = f2bf(o3);
    *(ushort4*)&hb[base] = hv;
}

// ---- residual + LN2 (chunked, in place on h rows [row0, row0+rows)): out = LN(h + ffn + fb2)
__global__ void __launch_bounds__(256) k_ln2(const u32* __restrict__ dflag,
                                             void* __restrict__ h, int row0, const float* __restrict__ ffn,
                                             const void* __restrict__ fb2, const void* __restrict__ g,
                                             const void* __restrict__ b, int rows) {
    bool f32 = dflag[0] != 0u;
    int row = blockIdx.x * 4 + (threadIdx.x >> 6);
    if (row >= rows) return;
    int lane = threadIdx.x & 63;
    size_t hbase = (size_t)(row0 + row) * 256 + lane * 4;
    size_t fbase = (size_t)row * 256 + lane * 4;
    float4 tv = *(const float4*)(ffn + fbase);
    float v0 = tv.x + gld(h, hbase + 0, f32) + gld(fb2, lane * 4 + 0, f32);
    float v1 = tv.y + gld(h, hbase + 1, f32) + gld(fb2, lane * 4 + 1, f32);
    float v2 = tv.z + gld(h, hbase + 2, f32) + gld(fb2, lane * 4 + 2, f32);
    float v3 = tv.w + gld(h, hbase + 3, f32) + gld(fb2, lane * 4 + 3, f32);
    float mu = wave_sum(v0 + v1 + v2 + v3) * (1.f / 256.f);
    float d0 = v0 - mu, d1 = v1 - mu, d2 = v2 - mu, d3 = v3 - mu;
    float var = wave_sum(d0 * d0 + d1 * d1 + d2 * d2 + d3 * d3) * (1.f / 256.f);
    float rs = rsqrtf(var + 1e-5f);
    gst(h, hbase + 0, f32, d0 * rs * gld(g, lane * 4 + 0, f32) + gld(b, lane * 4 + 0, f32));
    gst(h, hbase + 1, f32, d1 * rs * gld(g, lane * 4 + 1, f32) + gld(b, lane * 4 + 1, f32));
    gst(h, hbase + 2, f32, d2 * rs * gld(g, lane * 4 + 2, f32) + gld(b, lane * 4 + 2, f32));
    gst(h, hbase + 3, f32, d3 * rs * gld(g, lane * 4 + 3, f32) + gld(b, lane * 4 + 3, f32));
}

extern "C" void kernel_launch(void* const* d_in, const int* in_sizes, int n_in,
                              void* d_out, int out_size, void* d_ws, size_t ws_size,
                              hipStream_t stream) {
    const int N = in_sizes[0] / 256;     // 50000
    const int E = in_sizes[1] / 2;       // 800000
    const int NB = (N + 255) / 256;      // 196

    const void* x    = d_in[0];
    const int*  ei   = (const int*)d_in[1];
    const int*  et   = (const int*)d_in[2];
    const void* ew   = d_in[3];
    const void* Wsrc = d_in[4];
    const void* Wdst = d_in[5];
    const void* attS = d_in[6];
    const void* attD = d_in[7];
    const void* bias = d_in[8];
    const void* g1   = d_in[9];
    const void* b1   = d_in[10];
    const void* g2   = d_in[11];
    const void* b2   = d_in[12];
    const void* W1   = d_in[13];
    const void* fb1  = d_in[14];
    const void* W2   = d_in[15];
    const void* fb2  = d_in[16];

    // Workspace layout (round 3 proved ws_size >= ~213 MB: full one-chunk FFN ran)
    char* ws = (char*)d_ws;
    u32* flag   = (u32*)(ws + 0);             // 256 B
    u32* bsum   = (u32*)(ws + 256);           // 1 KB
    u32* obuf   = (u32*)(ws + 1536);          // (N+1)*4 ~ 200 KB
    u32* cursor = (u32*)(ws + 201984);        // N*4 = 200 KB
    u32* elist  = (u32*)(ws + 402176);        // E*4 = 3.2 MB -> ends 3602176
    u16* xb     = (u16*)(ws + 3602176);       // [N,256] bf16 = 25.6 MB (x pre-cvt)
    u16* hb     = (u16*)(ws + 3602176);       // [N,256] bf16 post-LN1 (xb dead by then)
    u16* xsd    = (u16*)(ws + 29202176);      // [N,288] bf16 = 28.8 MB (xs | 32 dots)
    u16* Bcat   = (u16*)(ws + 58002176);      // [288,256] bf16: Wsb rows 0-255, Mmat 256-287
    u16* W1b    = (u16*)(ws + 58149632);      // [1024,256] bf16 = 512 KB
    u16* W2b    = (u16*)(ws + 58673920);      // [256,1024] bf16 = 512 KB
    char* ffnbuf = ws + 59198208;             // FFN chunk buffers (runtime sized)
    void* hbuf  = d_out;                      // v -> h -> out staged in d_out (dtype = flag)

    k_probe<<<1, 256, 0, stream>>>((const u16*)x, flag);

    // bf16 pre-conversion of all GEMM operands (identity if inputs already bf16)
    k_cvt<<<(N * 32 + 255) / 256, 256, 0, stream>>>(flag, x, xb, N * 32);       // N*256/8
    k_cvt<<<32, 256, 0, stream>>>(flag, Wsrc, Bcat, 8192);                      // 256*256/8
    k_cvt<<<128, 256, 0, stream>>>(flag, W1, W1b, 32768);                       // 1024*256/8
    k_cvt<<<128, 256, 0, stream>>>(flag, W2, W2b, 32768);                       // 256*1024/8
    k_mkatt<<<32, 256, 0, stream>>>(flag, Wsrc, Wdst, attS, attD, Bcat + 256 * 256, 256);

    const int gyN = (N + 127) / 128;          // 391

    // xsd[N,288] = xb @ [Wsb; Mmat]^T  (x_src features + all 32 att dots, one pass)
    mgemm3<0><<<dim3(3, gyN), 256, 0, stream>>>(flag, xb, Bcat, xsd, nullptr, N, 288, 256, 288, 0);

    // CSR build
    k_zero<<<NB, 256, 0, stream>>>(obuf, N);
    k_count<<<(E + 255) / 256, 256, 0, stream>>>(ei, obuf, E);
    k_scanA<<<NB, 256, 0, stream>>>(obuf, bsum, N);
    k_scanB<<<1, 256, 0, stream>>>(bsum, NB);
    k_scanC<<<NB, 256, 0, stream>>>(obuf, cursor, bsum, N, E);
    k_scatter<<<(E + 255) / 256, 256, 0, stream>>>(ei, cursor, elist, E);

    // aggregation (one block per node, all 256 channels) + LN1
    k_node<<<N, 256, 0, stream>>>(flag, ei, et, ew, x, xsd, obuf, elist, bias, hbuf, N);
    k_ln1<<<(N + 3) / 4, 256, 0, stream>>>(flag, hbuf, hb, g1, b1, N);

    // FFN + LN2, chunked to fit remaining ws: 3072 B/row (act bf16 1024 + ffnout f32 256)
    long long avail = (long long)ws_size - 59198208 - 256;
    int rc = (int)(avail / 3072);
    rc &= ~127;
    if (rc > 50048) rc = 50048;
    if (rc < 128) rc = 128;
    u16*   act    = (u16*)ffnbuf;
    float* ffnout = (float*)(ffnbuf + (size_t)rc * 2048);

    for (int r0 = 0; r0 < N; r0 += rc) {
        int rows = N - r0; if (rows > rc) rows = rc;
        int gy = (rows + 127) / 128;
        mgemm3<1><<<dim3(8, gy), 256, 0, stream>>>(flag, hb, W1b, act, fb1, rows, 1024, 256, 1024, r0);
        mgemm3<2><<<dim3(2, gy), 256, 0, stream>>>(flag, act, W2b, ffnout, nullptr, rows, 256, 1024, 256, 0);
        k_ln2<<<(rows + 3) / 4, 256, 0, stream>>>(flag, hbuf, r0, ffnout, fb2, g2, b2, rows);
    }
}

// Round 6
// 677.395 us; speedup vs baseline: 11.9541x; 1.0221x over previous
//
#include <hip/hip_runtime.h>

typedef unsigned short u16;
typedef unsigned int u32;
typedef __attribute__((ext_vector_type(8))) unsigned short ushort8v;
typedef __attribute__((ext_vector_type(8))) __bf16 bf16x8;
typedef __attribute__((ext_vector_type(4))) float f32x4;

__device__ __forceinline__ float bf2f(u16 u) { return __uint_as_float(((u32)u) << 16); }
__device__ __forceinline__ u16 f2bf(float f) {
    u32 u = __float_as_uint(f);
    u32 r = u + 0x7fffu + ((u >> 16) & 1u);
    return (u16)(r >> 16);
}
__device__ __forceinline__ float wave_sum(float v) {
    #pragma unroll
    for (int m = 1; m < 64; m <<= 1) v += __shfl_xor(v, m, 64);
    return v;
}
// dtype-flexible load/store: f32=true -> float32 buffer, else bf16 (u16) buffer
__device__ __forceinline__ float gld(const void* p, size_t i, bool f32) {
    return f32 ? ((const float*)p)[i] : bf2f(((const u16*)p)[i]);
}
__device__ __forceinline__ void gst(void* p, size_t i, bool f32, float v) {
    if (f32) ((float*)p)[i] = v;
    else     ((u16*)p)[i] = f2bf(v);
}
__device__ __forceinline__ void ldf8(const void* p, size_t i, bool f32, float* o) {
    if (f32) {
        const float4* q = (const float4*)((const float*)p + i);
        float4 a = q[0], b = q[1];
        o[0] = a.x; o[1] = a.y; o[2] = a.z; o[3] = a.w;
        o[4] = b.x; o[5] = b.y; o[6] = b.z; o[7] = b.w;
    } else {
        ushort8v v = *(const ushort8v*)((const u16*)p + i);
        #pragma unroll
        for (int j = 0; j < 8; j++) o[j] = bf2f(v[j]);
    }
}
// async global(bf16)->LDS, 16 bytes per lane; LDS dst is wave-uniform base + lane*16
__device__ __forceinline__ void gl2lds16(const u16* g, u16* l) {
    __builtin_amdgcn_global_load_lds((const __attribute__((address_space(1))) void*)g,
                                     (__attribute__((address_space(3))) void*)l, 16, 0, 0);
}
// fast gelu: A&S 3-term erf, |err(erf)| <= 2.5e-5 (invisible under bf16 rounding)
__device__ __forceinline__ float gelu_f(float v) {
    float ay = fabsf(v) * 0.70710678f;
    float t = __builtin_amdgcn_rcpf(1.0f + 0.47047f * ay);
    float poly = t * (0.3480242f + t * (-0.0958798f + t * 0.7478556f));
    float erfa = 1.0f - poly * __expf(-ay * ay);
    float er = (v >= 0.f) ? erfa : -erfa;
    return 0.5f * v * (1.0f + er);
}

// ---- dtype probe: bf16 N(0,1) decodes |v|<~5 always; f32 viewed as u16 halves
// has ~48% of low-half words decoding to |v|>64 or NaN -> flags within 1024 floats.
__global__ void __launch_bounds__(256) k_probe(const u16* __restrict__ x, u32* __restrict__ flag) {
    __shared__ int cnt;
    if (threadIdx.x == 0) cnt = 0;
    __syncthreads();
    int bad = 0;
    for (int i = threadIdx.x; i < 2048; i += 256) {
        float v = bf2f(x[i]);
        if (!(v > -64.f && v < 64.f)) bad = 1;
    }
    if (bad) atomicAdd(&cnt, 1);
    __syncthreads();
    if (threadIdx.x == 0) flag[0] = (cnt > 0) ? 1u : 0u;
}

__global__ void __launch_bounds__(256) k_zero(u32* __restrict__ p, int n) {
    int i = blockIdx.x * 256 + threadIdx.x;
    if (i < n) p[i] = 0u;
}

// ---- convert a tensor (dtype per flag) to bf16, 8 elems/thread
__global__ void __launch_bounds__(256) k_cvt(const u32* __restrict__ dflag,
                                             const void* __restrict__ src, u16* __restrict__ dst, int n8) {
    bool f32 = dflag[0] != 0u;
    int i = blockIdx.x * 256 + threadIdx.x;
    if (i >= n8) return;
    float t[8];
    ldf8(src, (size_t)i * 8, f32, t);
    ushort8v o;
    #pragma unroll
    for (int j = 0; j < 8; j++) o[j] = f2bf(t[j]);
    *(ushort8v*)&dst[(size_t)i * 8] = o;
}

// ---- MFMA bf16 GEMM, BK=32 double-buffered (32 KB LDS -> 5 blocks/CU):
// C[m,n] = sum_k A[arow0+m,k]*B[n,k]. Tile 128x128, 4 waves (2x2 of 64x64).
// LDS rows are 32 bf16 = 64 B = 4 granules of 16 B. Granule XOR-swizzle by row
// bits 1-2 on BOTH sides (pre-swizzled per-lane GLOBAL source for global_load_lds,
// same involution on ds_read) -> uniform 8 lanes/bank-slot = b128 floor, ~0 conflicts.
// One barrier per K-step; next tile's loads issued BEFORE current compute.
// EPI: 0 = bf16 store; 1 = bf16 gelu(acc+bias[col]); 2 = f32 store
template <int EPI>
__global__ void __launch_bounds__(256, 5) mgemm4(const u32* __restrict__ dflag,
                                                 const u16* __restrict__ A, const u16* __restrict__ B,
                                                 void* __restrict__ Cout, const void* __restrict__ bias,
                                                 int M, int Nn, int K, int ldC, int arow0) {
    const bool ibf32 = dflag[0] != 0u;
    __shared__ __attribute__((aligned(16))) u16 sA[2][128 * 32];
    __shared__ __attribute__((aligned(16))) u16 sB[2][128 * 32];

    // XCD swizzle: contiguous chunk of remapped ids per XCD (bijective for any nwg)
    int nwg = gridDim.x * gridDim.y;
    int wgid = blockIdx.y * gridDim.x + blockIdx.x;
    if (nwg >= 16) {
        int q = nwg >> 3, r = nwg & 7;
        int xcd = wgid & 7, i = wgid >> 3;
        wgid = (xcd < r ? xcd * (q + 1) : r * (q + 1) + (xcd - r) * q) + i;
    }
    const int m0 = (wgid / gridDim.x) * 128;
    const int n0 = (wgid % gridDim.x) * 128;

    const int tid = threadIdx.x;
    const int wid = tid >> 6;
    const int lane = tid & 63;

    const int wm = (wid >> 1) * 64;
    const int wn = (wid & 1) * 64;
    const int lr = lane & 15;
    const int kg = lane >> 4;                       // k-granule 0..3 (8 elems)
    // read-side swizzled granule offset (elems); row bits 1-2 == lr bits 1-2
    const int gsw = (kg ^ ((lr >> 1) & 3)) * 8;

    // staging lane coords: unit = 16 rows x 64 B (1024 B); lane covers
    // row-in-unit lane>>2, LDS granule lane&3; source granule pre-swizzled
    const int srow = lane >> 2;
    const int scol = ((lane & 3) ^ ((lane >> 3) & 3)) * 8;

    f32x4 acc[4][4] = {};

    const size_t abase = (size_t)arow0 * K;

    // prologue: stage tile 0 into buf 0 (2 A-units + 2 B-units per wave)
    {
        #pragma unroll
        for (int j = 0; j < 2; j++) {
            int u = wid * 2 + j;
            int gr = m0 + u * 16 + srow; if (gr >= M) gr = M - 1;
            gl2lds16(A + abase + (size_t)gr * K + scol, &sA[0][u * 512]);
        }
        #pragma unroll
        for (int j = 0; j < 2; j++) {
            int u = wid * 2 + j;
            int gr = n0 + u * 16 + srow; if (gr >= Nn) gr = Nn - 1;
            gl2lds16(B + (size_t)gr * K + scol, &sB[0][u * 512]);
        }
    }
    __syncthreads();   // drains vmcnt(0) before s_barrier -> buf0 ready

    int cur = 0;
    for (int k0 = 0; k0 < K; k0 += 32) {
        // issue next tile's loads FIRST (latency hides under compute below)
        if (k0 + 32 < K) {
            int nb = cur ^ 1, k1 = k0 + 32;
            #pragma unroll
            for (int j = 0; j < 2; j++) {
                int u = wid * 2 + j;
                int gr = m0 + u * 16 + srow; if (gr >= M) gr = M - 1;
                gl2lds16(A + abase + (size_t)gr * K + k1 + scol, &sA[nb][u * 512]);
            }
            #pragma unroll
            for (int j = 0; j < 2; j++) {
                int u = wid * 2 + j;
                int gr = n0 + u * 16 + srow; if (gr >= Nn) gr = Nn - 1;
                gl2lds16(B + (size_t)gr * K + k1 + scol, &sB[nb][u * 512]);
            }
        }
        // compute current buffer: 16 MFMA
        {
            bf16x8 afr[4], bfr[4];
            #pragma unroll
            for (int m = 0; m < 4; m++)
                afr[m] = __builtin_bit_cast(bf16x8, *(const ushort8v*)&sA[cur][(wm + m * 16 + lr) * 32 + gsw]);
            #pragma unroll
            for (int n = 0; n < 4; n++)
                bfr[n] = __builtin_bit_cast(bf16x8, *(const ushort8v*)&sB[cur][(wn + n * 16 + lr) * 32 + gsw]);
            #pragma unroll
            for (int m = 0; m < 4; m++)
                #pragma unroll
                for (int n = 0; n < 4; n++)
                    acc[m][n] = __builtin_amdgcn_mfma_f32_16x16x32_bf16(afr[m], bfr[n], acc[m][n], 0, 0, 0);
        }
        __syncthreads();   // drains this wave's prefetch (vmcnt(0)) + syncs buffer flip
        cur ^= 1;
    }

    // C/D: col = lane&15, row = (lane>>4)*4 + reg  [harness-verified rounds 1-4]
    float bv[4];
    if (EPI == 1) {
        #pragma unroll
        for (int n = 0; n < 4; n++) {
            int cn = n0 + wn + n * 16 + lr; if (cn >= Nn) cn = Nn - 1;
            bv[n] = gld(bias, cn, ibf32);
        }
    }
    const int or0 = (lane >> 4) << 2;
    #pragma unroll
    for (int m = 0; m < 4; m++) {
        #pragma unroll
        for (int r = 0; r < 4; r++) {
            int gr = m0 + wm + m * 16 + or0 + r;
            if (gr >= M) continue;
            #pragma unroll
            for (int n = 0; n < 4; n++) {
                int cn = n0 + wn + n * 16 + lr;
                if (cn >= Nn) continue;
                float v = acc[m][n][r];
                if (EPI == 1) {
                    ((u16*)Cout)[(size_t)gr * ldC + cn] = f2bf(gelu_f(v + bv[n]));
                } else if (EPI == 0) {
                    ((u16*)Cout)[(size_t)gr * ldC + cn] = f2bf(v);
                } else {
                    ((float*)Cout)[(size_t)gr * ldC + cn] = v;
                }
            }
        }
    }
}

// ---- fold attention vectors through W: Mmat[th][k] (bf16, [32,256])
// th<16:  sum_c Wsrc[h*32+c][k] * attS[t,h,c]   (th = t*8+h)
// th>=16: sum_c Wdst[h*32+c][k] * attD[t,h,c]
__global__ void __launch_bounds__(256) k_mkatt(const u32* __restrict__ dflag,
                                               const void* __restrict__ Wsrc, const void* __restrict__ Wdst,
                                               const void* __restrict__ attS, const void* __restrict__ attD,
                                               u16* __restrict__ Mmat, int K) {
    bool f32 = dflag[0] != 0u;
    int th = blockIdx.x;   // 0..31
    int k = threadIdx.x;   // 0..K-1 (K=256)
    int tt = th & 15;
    const void* W = (th < 16) ? Wsrc : Wdst;
    const void* att = (th < 16) ? attS : attD;
    int h = tt & 7;
    float s = 0.f;
    #pragma unroll 8
    for (int c = 0; c < 32; c++)
        s += gld(W, (size_t)(h * 32 + c) * K + k, f32) * gld(att, tt * 32 + c, f32);
    Mmat[th * K + k] = f2bf(s);
}

// ---- CSR build (dst-major) ----
__global__ void __launch_bounds__(256) k_count(const int* __restrict__ ei, u32* __restrict__ cnt, int E) {
    int e = blockIdx.x * 256 + threadIdx.x;
    if (e < E) atomicAdd(cnt + ei[E + e], 1u);
}
__global__ void __launch_bounds__(256) k_scanA(u32* __restrict__ buf, u32* __restrict__ bsum, int N) {
    int t = threadIdx.x, idx = blockIdx.x * 256 + t;
    u32 v = (idx < N) ? buf[idx] : 0u;
    __shared__ u32 sc[256];
    sc[t] = v; __syncthreads();
    for (int d = 1; d < 256; d <<= 1) {
        u32 add = (t >= d) ? sc[t - d] : 0u; __syncthreads();
        sc[t] += add; __syncthreads();
    }
    if (idx < N) buf[idx] = sc[t] - v;
    if (t == 255) bsum[blockIdx.x] = sc[255];
}
__global__ void __launch_bounds__(256) k_scanB(u32* __restrict__ bsum, int nb) {
    int t = threadIdx.x;
    u32 v = (t < nb) ? bsum[t] : 0u;
    __shared__ u32 sc[256];
    sc[t] = v; __syncthreads();
    for (int d = 1; d < 256; d <<= 1) {
        u32 add = (t >= d) ? sc[t - d] : 0u; __syncthreads();
        sc[t] += add; __syncthreads();
    }
    if (t < nb) bsum[t] = sc[t] - v;
}
__global__ void __launch_bounds__(256) k_scanC(u32* __restrict__ obuf, u32* __restrict__ cursor,
                                               const u32* __restrict__ bsum, int N, int E) {
    int idx = blockIdx.x * 256 + threadIdx.x;
    if (idx < N) {
        u32 o = obuf[idx] + bsum[blockIdx.x];
        obuf[idx] = o;
        cursor[idx] = o;
    }
    if (blockIdx.x == 0 && threadIdx.x == 0) obuf[N] = (u32)E;
}
__global__ void __launch_bounds__(256) k_scatter(const int* __restrict__ ei, u32* __restrict__ cursor,
                                                 u32* __restrict__ elist, int E) {
    int e = blockIdx.x * 256 + threadIdx.x;
    if (e >= E) return;
    u32 slot = atomicAdd(cursor + ei[E + e], 1u);
    elist[slot] = (u32)e;
}

// ---- fused per-node softmax aggregation, two-phase chunked (round-3 structure).
// xsd = [N,288] bf16: cols 0..255 = x@Wsrc^T, cols 256..287 = the 32 att dots.
__global__ void __launch_bounds__(256) k_node(const u32* __restrict__ dflag,
                                              const int* __restrict__ ei, const int* __restrict__ et,
                                              const void* __restrict__ ew, const void* __restrict__ x,
                                              const u16* __restrict__ xsd,
                                              const u32* __restrict__ obuf, const u32* __restrict__ elist,
                                              const void* __restrict__ bias, void* __restrict__ vout, int N) {
    bool f32 = dflag[0] != 0u;
    int node = blockIdx.x;
    if (node >= N) return;
    int tid = threadIdx.x;
    int ch = tid;
    int hh = ch >> 5;
    __shared__ u32 s_src[64];
    __shared__ float s_w[64];
    __shared__ float s_pe[64][8];

    const size_t nbase = (size_t)node * 288;
    // self-loop: type 0, weight 1
    float a = bf2f(xsd[nbase + 256 + hh]) + bf2f(xsd[nbase + 256 + 16 + hh]);
    float p = __expf(a >= 0.f ? a : 0.2f * a);
    float den = p;
    float num = p * bf2f(xsd[nbase + ch]);

    u32 kbeg = obuf[node], kend = obuf[node + 1];
    for (u32 c0 = kbeg; c0 < kend; c0 += 64) {
        int cnt = (int)(kend - c0) < 64 ? (int)(kend - c0) : 64;
        __syncthreads();   // previous chunk's LDS fully consumed
        if (tid < cnt) {
            int e = (int)elist[c0 + tid];
            int src = ei[e];
            int t = et[e];
            s_src[tid] = (u32)src;
            s_w[tid] = gld(ew, e, f32);
            const u16* ds = &xsd[(size_t)src * 288 + 256 + t * 8];
            const u16* dd = &xsd[nbase + 256 + 16 + t * 8];
            #pragma unroll
            for (int h = 0; h < 8; h++) {
                float aa = bf2f(ds[h]) + bf2f(dd[h]);
                s_pe[tid][h] = __expf(aa >= 0.f ? aa : 0.2f * aa);
            }
        }
        __syncthreads();
        float n0 = 0.f, n1 = 0.f, n2 = 0.f, n3 = 0.f;
        float d0 = 0.f, d1 = 0.f, d2 = 0.f, d3 = 0.f;
        int k = 0;
        for (; k + 4 <= cnt; k += 4) {
            u32 sa = s_src[k], sb = s_src[k + 1], sc = s_src[k + 2], sd = s_src[k + 3];
            float pa = s_pe[k][hh], pb = s_pe[k + 1][hh], pc = s_pe[k + 2][hh], pd = s_pe[k + 3][hh];
            float wa = s_w[k], wb = s_w[k + 1], wc = s_w[k + 2], wd = s_w[k + 3];
            float xa = bf2f(xsd[(size_t)sa * 288 + ch]);
            float xb = bf2f(xsd[(size_t)sb * 288 + ch]);
            float xc = bf2f(xsd[(size_t)sc * 288 + ch]);
            float xd = bf2f(xsd[(size_t)sd * 288 + ch]);
            n0 += pa * wa * xa; n1 += pb * wb * xb;
            n2 += pc * wc * xc; n3 += pd * wd * xd;
            d0 += pa; d1 += pb; d2 += pc; d3 += pd;
        }
        for (; k < cnt; k++) {
            float pp = s_pe[k][hh];
            num += pp * s_w[k] * bf2f(xsd[(size_t)s_src[k] * 288 + ch]);
            den += pp;
        }
        num += (n0 + n1) + (n2 + n3);
        den += (d0 + d1) + (d2 + d3);
    }
    float v = num / den + gld(bias, ch, f32) + gld(x, (size_t)node * 256 + ch, f32);
    gst(vout, (size_t)node * 256 + ch, f32, v);
}

// ---- LN1 in place on v ([N,256], dtype follows flag) -> h; also emit bf16 copy hb
__global__ void __launch_bounds__(256) k_ln1(const u32* __restrict__ dflag, void* __restrict__ v,
                                             u16* __restrict__ hb,
                                             const void* __restrict__ g, const void* __restrict__ b, int N) {
    bool f32 = dflag[0] != 0u;
    int node = blockIdx.x * 4 + (threadIdx.x >> 6);
    if (node >= N) return;
    int lane = threadIdx.x & 63;
    size_t base = (size_t)node * 256 + lane * 4;
    float v0 = gld(v, base + 0, f32), v1 = gld(v, base + 1, f32);
    float v2 = gld(v, base + 2, f32), v3 = gld(v, base + 3, f32);
    float mu = wave_sum(v0 + v1 + v2 + v3) * (1.f / 256.f);
    float d0 = v0 - mu, d1 = v1 - mu, d2 = v2 - mu, d3 = v3 - mu;
    float var = wave_sum(d0 * d0 + d1 * d1 + d2 * d2 + d3 * d3) * (1.f / 256.f);
    float rs = rsqrtf(var + 1e-5f);
    float o0 = d0 * rs * gld(g, lane * 4 + 0, f32) + gld(b, lane * 4 + 0, f32);
    float o1 = d1 * rs * gld(g, lane * 4 + 1, f32) + gld(b, lane * 4 + 1, f32);
    float o2 = d2 * rs * gld(g, lane * 4 + 2, f32) + gld(b, lane * 4 + 2, f32);
    float o3 = d3 * rs * gld(g, lane * 4 + 3, f32) + gld(b, lane * 4 + 3, f32);
    gst(v, base + 0, f32, o0); gst(v, base + 1, f32, o1);
    gst(v, base + 2, f32, o2); gst(v, base + 3, f32, o3);
    ushort4 hv; hv.x = f2bf(o0); hv.y = f2bf(o1); hv.z = f2bf(o2); hv.w = f2bf(o3);
    *(ushort4*)&hb[base] = hv;
}

// ---- residual + LN2 (chunked, in place on h rows [row0, row0+rows)): out = LN(h + ffn + fb2)
// ffn is bf16 now (W2 epilogue stores bf16 -> halves that buffer's HBM traffic)
__global__ void __launch_bounds__(256) k_ln2(const u32* __restrict__ dflag,
                                             void* __restrict__ h, int row0, const u16* __restrict__ ffn,
                                             const void* __restrict__ fb2, const void* __restrict__ g,
                                             const void* __restrict__ b, int rows) {
    bool f32 = dflag[0] != 0u;
    int row = blockIdx.x * 4 + (threadIdx.x >> 6);
    if (row >= rows) return;
    int lane = threadIdx.x & 63;
    size_t hbase = (size_t)(row0 + row) * 256 + lane * 4;
    size_t fbase = (size_t)row * 256 + lane * 4;
    ushort4 tv = *(const ushort4*)(ffn + fbase);
    float v0 = bf2f(tv.x) + gld(h, hbase + 0, f32) + gld(fb2, lane * 4 + 0, f32);
    float v1 = bf2f(tv.y) + gld(h, hbase + 1, f32) + gld(fb2, lane * 4 + 1, f32);
    float v2 = bf2f(tv.z) + gld(h, hbase + 2, f32) + gld(fb2, lane * 4 + 2, f32);
    float v3 = bf2f(tv.w) + gld(h, hbase + 3, f32) + gld(fb2, lane * 4 + 3, f32);
    float mu = wave_sum(v0 + v1 + v2 + v3) * (1.f / 256.f);
    float d0 = v0 - mu, d1 = v1 - mu, d2 = v2 - mu, d3 = v3 - mu;
    float var = wave_sum(d0 * d0 + d1 * d1 + d2 * d2 + d3 * d3) * (1.f / 256.f);
    float rs = rsqrtf(var + 1e-5f);
    gst(h, hbase + 0, f32, d0 * rs * gld(g, lane * 4 + 0, f32) + gld(b, lane * 4 + 0, f32));
    gst(h, hbase + 1, f32, d1 * rs * gld(g, lane * 4 + 1, f32) + gld(b, lane * 4 + 1, f32));
    gst(h, hbase + 2, f32, d2 * rs * gld(g, lane * 4 + 2, f32) + gld(b, lane * 4 + 2, f32));
    gst(h, hbase + 3, f32, d3 * rs * gld(g, lane * 4 + 3, f32) + gld(b, lane * 4 + 3, f32));
}

extern "C" void kernel_launch(void* const* d_in, const int* in_sizes, int n_in,
                              void* d_out, int out_size, void* d_ws, size_t ws_size,
                              hipStream_t stream) {
    const int N = in_sizes[0] / 256;     // 50000
    const int E = in_sizes[1] / 2;       // 800000
    const int NB = (N + 255) / 256;      // 196

    const void* x    = d_in[0];
    const int*  ei   = (const int*)d_in[1];
    const int*  et   = (const int*)d_in[2];
    const void* ew   = d_in[3];
    const void* Wsrc = d_in[4];
    const void* Wdst = d_in[5];
    const void* attS = d_in[6];
    const void* attD = d_in[7];
    const void* bias = d_in[8];
    const void* g1   = d_in[9];
    const void* b1   = d_in[10];
    const void* g2   = d_in[11];
    const void* b2   = d_in[12];
    const void* W1   = d_in[13];
    const void* fb1  = d_in[14];
    const void* W2   = d_in[15];
    const void* fb2  = d_in[16];

    // Workspace layout (round 4 proved ws_size >= ~187 MB: full one-chunk FFN ran)
    char* ws = (char*)d_ws;
    u32* flag   = (u32*)(ws + 0);             // 256 B
    u32* bsum   = (u32*)(ws + 256);           // 1 KB
    u32* obuf   = (u32*)(ws + 1536);          // (N+1)*4 ~ 200 KB
    u32* cursor = (u32*)(ws + 201984);        // N*4 = 200 KB
    u32* elist  = (u32*)(ws + 402176);        // E*4 = 3.2 MB -> ends 3602176
    u16* xb     = (u16*)(ws + 3602176);       // [N,256] bf16 = 25.6 MB (x pre-cvt)
    u16* hb     = (u16*)(ws + 3602176);       // [N,256] bf16 post-LN1 (xb dead by then)
    u16* xsd    = (u16*)(ws + 29202176);      // [N,288] bf16 = 28.8 MB (xs | 32 dots)
    u16* Bcat   = (u16*)(ws + 58002176);      // [288,256] bf16: Wsb rows 0-255, Mmat 256-287
    u16* W1b    = (u16*)(ws + 58149632);      // [1024,256] bf16 = 512 KB
    u16* W2b    = (u16*)(ws + 58673920);      // [256,1024] bf16 = 512 KB
    char* ffnbuf = ws + 59198208;             // FFN chunk buffers (runtime sized)
    void* hbuf  = d_out;                      // v -> h -> out staged in d_out (dtype = flag)

    k_probe<<<1, 256, 0, stream>>>((const u16*)x, flag);

    // bf16 pre-conversion of all GEMM operands (identity if inputs already bf16)
    k_cvt<<<(N * 32 + 255) / 256, 256, 0, stream>>>(flag, x, xb, N * 32);       // N*256/8
    k_cvt<<<32, 256, 0, stream>>>(flag, Wsrc, Bcat, 8192);                      // 256*256/8
    k_cvt<<<128, 256, 0, stream>>>(flag, W1, W1b, 32768);                       // 1024*256/8
    k_cvt<<<128, 256, 0, stream>>>(flag, W2, W2b, 32768);                       // 256*1024/8
    k_mkatt<<<32, 256, 0, stream>>>(flag, Wsrc, Wdst, attS, attD, Bcat + 256 * 256, 256);

    const int gyN = (N + 127) / 128;          // 391

    // xsd[N,288] = xb @ [Wsb; Mmat]^T  (x_src features + all 32 att dots, one pass)
    mgemm4<0><<<dim3(3, gyN), 256, 0, stream>>>(flag, xb, Bcat, xsd, nullptr, N, 288, 256, 288, 0);

    // CSR build
    k_zero<<<NB, 256, 0, stream>>>(obuf, N);
    k_count<<<(E + 255) / 256, 256, 0, stream>>>(ei, obuf, E);
    k_scanA<<<NB, 256, 0, stream>>>(obuf, bsum, N);
    k_scanB<<<1, 256, 0, stream>>>(bsum, NB);
    k_scanC<<<NB, 256, 0, stream>>>(obuf, cursor, bsum, N, E);
    k_scatter<<<(E + 255) / 256, 256, 0, stream>>>(ei, cursor, elist, E);

    // aggregation (one block per node, all 256 channels) + LN1
    k_node<<<N, 256, 0, stream>>>(flag, ei, et, ew, x, xsd, obuf, elist, bias, hbuf, N);
    k_ln1<<<(N + 3) / 4, 256, 0, stream>>>(flag, hbuf, hb, g1, b1, N);

    // FFN + LN2, chunked to fit remaining ws: 2560 B/row (act bf16 1024 + ffnout bf16 256)
    long long avail = (long long)ws_size - 59198208 - 256;
    int rc = (int)(avail / 2560);
    rc &= ~127;
    if (rc > 50048) rc = 50048;
    if (rc < 128) rc = 128;
    u16* act    = (u16*)ffnbuf;
    u16* ffnout = (u16*)(ffnbuf + (size_t)rc * 2048);

    for (int r0 = 0; r0 < N; r0 += rc) {
        int rows = N - r0; if (rows > rc) rows = rc;
        int gy = (rows + 127) / 128;
        mgemm4<1><<<dim3(8, gy), 256, 0, stream>>>(flag, hb, W1b, act, fb1, rows, 1024, 256, 1024, r0);
        mgemm4<0><<<dim3(2, gy), 256, 0, stream>>>(flag, act, W2b, ffnout, nullptr, rows, 256, 1024, 256, 0);
        k_ln2<<<(rows + 3) / 4, 256, 0, stream>>>(flag, hbuf, r0, ffnout, fb2, g2, b2, rows);
    }
}

// Round 7
// 621.441 us; speedup vs baseline: 13.0305x; 1.0900x over previous
//
#include <hip/hip_runtime.h>

typedef unsigned short u16;
typedef unsigned int u32;
typedef __attribute__((ext_vector_type(8))) unsigned short ushort8v;
typedef __attribute__((ext_vector_type(8))) __bf16 bf16x8;
typedef __attribute__((ext_vector_type(4))) float f32x4;

__device__ __forceinline__ float bf2f(u16 u) { return __uint_as_float(((u32)u) << 16); }
__device__ __forceinline__ u16 f2bf(float f) {
    u32 u = __float_as_uint(f);
    u32 r = u + 0x7fffu + ((u >> 16) & 1u);
    return (u16)(r >> 16);
}
__device__ __forceinline__ float wave_sum(float v) {
    #pragma unroll
    for (int m = 1; m < 64; m <<= 1) v += __shfl_xor(v, m, 64);
    return v;
}
// dtype-flexible load/store: f32=true -> float32 buffer, else bf16 (u16) buffer
__device__ __forceinline__ float gld(const void* p, size_t i, bool f32) {
    return f32 ? ((const float*)p)[i] : bf2f(((const u16*)p)[i]);
}
__device__ __forceinline__ void gst(void* p, size_t i, bool f32, float v) {
    if (f32) ((float*)p)[i] = v;
    else     ((u16*)p)[i] = f2bf(v);
}
__device__ __forceinline__ void ldf8(const void* p, size_t i, bool f32, float* o) {
    if (f32) {
        const float4* q = (const float4*)((const float*)p + i);
        float4 a = q[0], b = q[1];
        o[0] = a.x; o[1] = a.y; o[2] = a.z; o[3] = a.w;
        o[4] = b.x; o[5] = b.y; o[6] = b.z; o[7] = b.w;
    } else {
        ushort8v v = *(const ushort8v*)((const u16*)p + i);
        #pragma unroll
        for (int j = 0; j < 8; j++) o[j] = bf2f(v[j]);
    }
}
// async global(bf16)->LDS, 16 bytes per lane; LDS dst is wave-uniform base + lane*16
__device__ __forceinline__ void gl2lds16(const u16* g, u16* l) {
    __builtin_amdgcn_global_load_lds((const __attribute__((address_space(1))) void*)g,
                                     (__attribute__((address_space(3))) void*)l, 16, 0, 0);
}
// fast gelu: A&S 3-term erf, |err(erf)| <= 2.5e-5 (invisible under bf16 rounding)
__device__ __forceinline__ float gelu_f(float v) {
    float ay = fabsf(v) * 0.70710678f;
    float t = __builtin_amdgcn_rcpf(1.0f + 0.47047f * ay);
    float poly = t * (0.3480242f + t * (-0.0958798f + t * 0.7478556f));
    float erfa = 1.0f - poly * __expf(-ay * ay);
    float er = (v >= 0.f) ? erfa : -erfa;
    return 0.5f * v * (1.0f + er);
}

// ---- dtype probe: bf16 N(0,1) decodes |v|<~5 always; f32 viewed as u16 halves
// has ~48% of low-half words decoding to |v|>64 or NaN -> flags within 1024 floats.
__global__ void __launch_bounds__(256) k_probe(const u16* __restrict__ x, u32* __restrict__ flag) {
    __shared__ int cnt;
    if (threadIdx.x == 0) cnt = 0;
    __syncthreads();
    int bad = 0;
    for (int i = threadIdx.x; i < 2048; i += 256) {
        float v = bf2f(x[i]);
        if (!(v > -64.f && v < 64.f)) bad = 1;
    }
    if (bad) atomicAdd(&cnt, 1);
    __syncthreads();
    if (threadIdx.x == 0) flag[0] = (cnt > 0) ? 1u : 0u;
}

__global__ void __launch_bounds__(256) k_zero(u32* __restrict__ p, int n) {
    int i = blockIdx.x * 256 + threadIdx.x;
    if (i < n) p[i] = 0u;
}

// ---- convert a tensor (dtype per flag) to bf16, 8 elems/thread
__global__ void __launch_bounds__(256) k_cvt(const u32* __restrict__ dflag,
                                             const void* __restrict__ src, u16* __restrict__ dst, int n8) {
    bool f32 = dflag[0] != 0u;
    int i = blockIdx.x * 256 + threadIdx.x;
    if (i >= n8) return;
    float t[8];
    ldf8(src, (size_t)i * 8, f32, t);
    ushort8v o;
    #pragma unroll
    for (int j = 0; j < 8; j++) o[j] = f2bf(t[j]);
    *(ushort8v*)&dst[(size_t)i * 8] = o;
}

// ---- MFMA bf16 GEMM, BK=32 double-buffered (32 KB LDS -> 5 blocks/CU):
// C[m,n] = sum_k A[arow0+m,k]*B[n,k]. Tile 128x128, 4 waves (2x2 of 64x64).
// LDS rows are 32 bf16 = 64 B = 4 granules of 16 B. Granule XOR-swizzle by row
// bits 1-2 on BOTH sides (pre-swizzled per-lane GLOBAL source for global_load_lds,
// same involution on ds_read) -> uniform 8 lanes/bank-slot = b128 floor, ~0 conflicts.
// One barrier per K-step; next tile's loads issued BEFORE current compute.
// EPI: 0 = bf16 store; 1 = bf16 gelu(acc+bias[col]); 2 = f32 store
template <int EPI>
__global__ void __launch_bounds__(256, 5) mgemm4(const u32* __restrict__ dflag,
                                                 const u16* __restrict__ A, const u16* __restrict__ B,
                                                 void* __restrict__ Cout, const void* __restrict__ bias,
                                                 int M, int Nn, int K, int ldC, int arow0) {
    const bool ibf32 = dflag[0] != 0u;
    __shared__ __attribute__((aligned(16))) u16 sA[2][128 * 32];
    __shared__ __attribute__((aligned(16))) u16 sB[2][128 * 32];

    // XCD swizzle: contiguous chunk of remapped ids per XCD (bijective for any nwg)
    int nwg = gridDim.x * gridDim.y;
    int wgid = blockIdx.y * gridDim.x + blockIdx.x;
    if (nwg >= 16) {
        int q = nwg >> 3, r = nwg & 7;
        int xcd = wgid & 7, i = wgid >> 3;
        wgid = (xcd < r ? xcd * (q + 1) : r * (q + 1) + (xcd - r) * q) + i;
    }
    const int m0 = (wgid / gridDim.x) * 128;
    const int n0 = (wgid % gridDim.x) * 128;

    const int tid = threadIdx.x;
    const int wid = tid >> 6;
    const int lane = tid & 63;

    const int wm = (wid >> 1) * 64;
    const int wn = (wid & 1) * 64;
    const int lr = lane & 15;
    const int kg = lane >> 4;                       // k-granule 0..3 (8 elems)
    // read-side swizzled granule offset (elems); row bits 1-2 == lr bits 1-2
    const int gsw = (kg ^ ((lr >> 1) & 3)) * 8;

    // staging lane coords: unit = 16 rows x 64 B (1024 B); lane covers
    // row-in-unit lane>>2, LDS granule lane&3; source granule pre-swizzled
    const int srow = lane >> 2;
    const int scol = ((lane & 3) ^ ((lane >> 3) & 3)) * 8;

    f32x4 acc[4][4] = {};

    const size_t abase = (size_t)arow0 * K;

    // prologue: stage tile 0 into buf 0 (2 A-units + 2 B-units per wave)
    {
        #pragma unroll
        for (int j = 0; j < 2; j++) {
            int u = wid * 2 + j;
            int gr = m0 + u * 16 + srow; if (gr >= M) gr = M - 1;
            gl2lds16(A + abase + (size_t)gr * K + scol, &sA[0][u * 512]);
        }
        #pragma unroll
        for (int j = 0; j < 2; j++) {
            int u = wid * 2 + j;
            int gr = n0 + u * 16 + srow; if (gr >= Nn) gr = Nn - 1;
            gl2lds16(B + (size_t)gr * K + scol, &sB[0][u * 512]);
        }
    }
    __syncthreads();   // drains vmcnt(0) before s_barrier -> buf0 ready

    int cur = 0;
    for (int k0 = 0; k0 < K; k0 += 32) {
        // issue next tile's loads FIRST (latency hides under compute below)
        if (k0 + 32 < K) {
            int nb = cur ^ 1, k1 = k0 + 32;
            #pragma unroll
            for (int j = 0; j < 2; j++) {
                int u = wid * 2 + j;
                int gr = m0 + u * 16 + srow; if (gr >= M) gr = M - 1;
                gl2lds16(A + abase + (size_t)gr * K + k1 + scol, &sA[nb][u * 512]);
            }
            #pragma unroll
            for (int j = 0; j < 2; j++) {
                int u = wid * 2 + j;
                int gr = n0 + u * 16 + srow; if (gr >= Nn) gr = Nn - 1;
                gl2lds16(B + (size_t)gr * K + k1 + scol, &sB[nb][u * 512]);
            }
        }
        // compute current buffer: 16 MFMA
        {
            bf16x8 afr[4], bfr[4];
            #pragma unroll
            for (int m = 0; m < 4; m++)
                afr[m] = __builtin_bit_cast(bf16x8, *(const ushort8v*)&sA[cur][(wm + m * 16 + lr) * 32 + gsw]);
            #pragma unroll
            for (int n = 0; n < 4; n++)
                bfr[n] = __builtin_bit_cast(bf16x8, *(const ushort8v*)&sB[cur][(wn + n * 16 + lr) * 32 + gsw]);
            #pragma unroll
            for (int m = 0; m < 4; m++)
                #pragma unroll
                for (int n = 0; n < 4; n++)
                    acc[m][n] = __builtin_amdgcn_mfma_f32_16x16x32_bf16(afr[m], bfr[n], acc[m][n], 0, 0, 0);
        }
        __syncthreads();   // drains this wave's prefetch (vmcnt(0)) + syncs buffer flip
        cur ^= 1;
    }

    // C/D: col = lane&15, row = (lane>>4)*4 + reg  [harness-verified rounds 1-6]
    float bv[4];
    if (EPI == 1) {
        #pragma unroll
        for (int n = 0; n < 4; n++) {
            int cn = n0 + wn + n * 16 + lr; if (cn >= Nn) cn = Nn - 1;
            bv[n] = gld(bias, cn, ibf32);
        }
    }
    const int or0 = (lane >> 4) << 2;
    #pragma unroll
    for (int m = 0; m < 4; m++) {
        #pragma unroll
        for (int r = 0; r < 4; r++) {
            int gr = m0 + wm + m * 16 + or0 + r;
            if (gr >= M) continue;
            #pragma unroll
            for (int n = 0; n < 4; n++) {
                int cn = n0 + wn + n * 16 + lr;
                if (cn >= Nn) continue;
                float v = acc[m][n][r];
                if (EPI == 1) {
                    ((u16*)Cout)[(size_t)gr * ldC + cn] = f2bf(gelu_f(v + bv[n]));
                } else if (EPI == 0) {
                    ((u16*)Cout)[(size_t)gr * ldC + cn] = f2bf(v);
                } else {
                    ((float*)Cout)[(size_t)gr * ldC + cn] = v;
                }
            }
        }
    }
}

// ---- fold attention vectors through W: Mmat[th][k] (bf16, [32,256])
// th<16:  sum_c Wsrc[h*32+c][k] * attS[t,h,c]   (th = t*8+h)
// th>=16: sum_c Wdst[h*32+c][k] * attD[t,h,c]
__global__ void __launch_bounds__(256) k_mkatt(const u32* __restrict__ dflag,
                                               const void* __restrict__ Wsrc, const void* __restrict__ Wdst,
                                               const void* __restrict__ attS, const void* __restrict__ attD,
                                               u16* __restrict__ Mmat, int K) {
    bool f32 = dflag[0] != 0u;
    int th = blockIdx.x;   // 0..31
    int k = threadIdx.x;   // 0..K-1 (K=256)
    int tt = th & 15;
    const void* W = (th < 16) ? Wsrc : Wdst;
    const void* att = (th < 16) ? attS : attD;
    int h = tt & 7;
    float s = 0.f;
    #pragma unroll 8
    for (int c = 0; c < 32; c++)
        s += gld(W, (size_t)(h * 32 + c) * K + k, f32) * gld(att, tt * 32 + c, f32);
    Mmat[th * K + k] = f2bf(s);
}

// ---- CSR build (dst-major) ----
__global__ void __launch_bounds__(256) k_count(const int* __restrict__ ei, u32* __restrict__ cnt, int E) {
    int e = blockIdx.x * 256 + threadIdx.x;
    if (e < E) atomicAdd(cnt + ei[E + e], 1u);
}
__global__ void __launch_bounds__(256) k_scanA(u32* __restrict__ buf, u32* __restrict__ bsum, int N) {
    int t = threadIdx.x, idx = blockIdx.x * 256 + t;
    u32 v = (idx < N) ? buf[idx] : 0u;
    __shared__ u32 sc[256];
    sc[t] = v; __syncthreads();
    for (int d = 1; d < 256; d <<= 1) {
        u32 add = (t >= d) ? sc[t - d] : 0u; __syncthreads();
        sc[t] += add; __syncthreads();
    }
    if (idx < N) buf[idx] = sc[t] - v;
    if (t == 255) bsum[blockIdx.x] = sc[255];
}
__global__ void __launch_bounds__(256) k_scanB(u32* __restrict__ bsum, int nb) {
    int t = threadIdx.x;
    u32 v = (t < nb) ? bsum[t] : 0u;
    __shared__ u32 sc[256];
    sc[t] = v; __syncthreads();
    for (int d = 1; d < 256; d <<= 1) {
        u32 add = (t >= d) ? sc[t - d] : 0u; __syncthreads();
        sc[t] += add; __syncthreads();
    }
    if (t < nb) bsum[t] = sc[t] - v;
}
__global__ void __launch_bounds__(256) k_scanC(u32* __restrict__ obuf, u32* __restrict__ cursor,
                                               const u32* __restrict__ bsum, int N, int E) {
    int idx = blockIdx.x * 256 + threadIdx.x;
    if (idx < N) {
        u32 o = obuf[idx] + bsum[blockIdx.x];
        obuf[idx] = o;
        cursor[idx] = o;
    }
    if (blockIdx.x == 0 && threadIdx.x == 0) obuf[N] = (u32)E;
}
__global__ void __launch_bounds__(256) k_scatter(const int* __restrict__ ei, u32* __restrict__ cursor,
                                                 u32* __restrict__ elist, int E) {
    int e = blockIdx.x * 256 + threadIdx.x;
    if (e >= E) return;
    u32 slot = atomicAdd(cursor + ei[E + e], 1u);
    elist[slot] = (u32)e;
}

// ---- fused per-node softmax aggregation + LN1, ONE WAVE PER NODE (4 nodes/block,
// no block barriers -- wave-synchronous). Lane owns 4 channels (ch = lane*4..+3):
// gathers are ushort4 (8 B/lane, wave covers full 512 B row/edge), 4-edge unroll
// -> ~2 KB outstanding/wave (4x the old concurrency). Stage uses all 64 lanes
// (1 edge/lane, 16 B vector dot-row loads). LN1 is wave-local (lane holds 4 ch,
// same wave_sum reduction order as the old k_ln1). Writes h (dtype flag) + hb bf16.
// xsd = [N,288] bf16: cols 0..255 = x@Wsrc^T, cols 256..287 = the 32 att dots.
__global__ void __launch_bounds__(256) k_node(const u32* __restrict__ dflag,
                                              const int* __restrict__ ei, const int* __restrict__ et,
                                              const void* __restrict__ ew, const void* __restrict__ x,
                                              const u16* __restrict__ xsd,
                                              const u32* __restrict__ obuf, const u32* __restrict__ elist,
                                              const void* __restrict__ bias,
                                              const void* __restrict__ g1, const void* __restrict__ b1,
                                              void* __restrict__ hout, u16* __restrict__ hb, int N) {
    bool f32 = dflag[0] != 0u;
    const int wid = threadIdx.x >> 6;
    const int lane = threadIdx.x & 63;
    const int node = blockIdx.x * 4 + wid;
    if (node >= N) return;

    __shared__ u32 s_src[4][64];
    __shared__ float s_w[4][64];
    __shared__ float s_pe[4][64][8];

    const int ch0 = lane * 4;
    const int hh = lane >> 3;             // head of this lane's 4 channels
    const size_t nbase = (size_t)node * 288;

    // dst-side dot rows (type 0 at +272, type 1 at +280), kept in registers
    ushort8v dd0v = *(const ushort8v*)&xsd[nbase + 256 + 16];
    ushort8v dd1v = *(const ushort8v*)&xsd[nbase + 256 + 24];

    // self-loop: type 0, weight 1
    float a_self = bf2f(xsd[nbase + 256 + hh]) + bf2f(xsd[nbase + 256 + 16 + hh]);
    float p_self = __expf(a_self >= 0.f ? a_self : 0.2f * a_self);
    float den = p_self;
    ushort4 sv = *(const ushort4*)&xsd[nbase + ch0];
    float num0 = p_self * bf2f(sv.x), num1 = p_self * bf2f(sv.y);
    float num2 = p_self * bf2f(sv.z), num3 = p_self * bf2f(sv.w);

    const u32 kbeg = obuf[node], kend = obuf[node + 1];
    for (u32 c0 = kbeg; c0 < kend; c0 += 64) {
        int cnt = (int)(kend - c0) < 64 ? (int)(kend - c0) : 64;
        __builtin_amdgcn_wave_barrier();   // compiler fence: prior chunk reads done
        if (lane < cnt) {
            int e = (int)elist[c0 + lane];
            int src = ei[e];
            int t = et[e];
            s_src[wid][lane] = (u32)src;
            s_w[wid][lane] = gld(ew, e, f32);
            ushort8v ds8 = *(const ushort8v*)&xsd[(size_t)src * 288 + 256 + t * 8];
            #pragma unroll
            for (int h = 0; h < 8; h++) {
                float aa = bf2f(ds8[h]) + (t ? bf2f(dd1v[h]) : bf2f(dd0v[h]));
                s_pe[wid][lane][h] = __expf(aa >= 0.f ? aa : 0.2f * aa);
            }
        }
        __builtin_amdgcn_wave_barrier();   // compiler fence: stage visible before reads
        int k = 0;
        for (; k + 4 <= cnt; k += 4) {
            u32 sa = s_src[wid][k], sb = s_src[wid][k + 1];
            u32 sc = s_src[wid][k + 2], sd = s_src[wid][k + 3];
            float pa = s_pe[wid][k][hh], pb = s_pe[wid][k + 1][hh];
            float pc = s_pe[wid][k + 2][hh], pd = s_pe[wid][k + 3][hh];
            float wa = s_w[wid][k], wb = s_w[wid][k + 1];
            float wc = s_w[wid][k + 2], wd = s_w[wid][k + 3];
            ushort4 xa = *(const ushort4*)&xsd[(size_t)sa * 288 + ch0];
            ushort4 xb = *(const ushort4*)&xsd[(size_t)sb * 288 + ch0];
            ushort4 xc = *(const ushort4*)&xsd[(size_t)sc * 288 + ch0];
            ushort4 xd = *(const ushort4*)&xsd[(size_t)sd * 288 + ch0];
            float pwa = pa * wa, pwb = pb * wb, pwc = pc * wc, pwd = pd * wd;
            num0 += pwa * bf2f(xa.x) + pwb * bf2f(xb.x) + pwc * bf2f(xc.x) + pwd * bf2f(xd.x);
            num1 += pwa * bf2f(xa.y) + pwb * bf2f(xb.y) + pwc * bf2f(xc.y) + pwd * bf2f(xd.y);
            num2 += pwa * bf2f(xa.z) + pwb * bf2f(xb.z) + pwc * bf2f(xc.z) + pwd * bf2f(xd.z);
            num3 += pwa * bf2f(xa.w) + pwb * bf2f(xb.w) + pwc * bf2f(xc.w) + pwd * bf2f(xd.w);
            den += (pa + pb) + (pc + pd);
        }
        for (; k < cnt; k++) {
            u32 s = s_src[wid][k];
            float p = s_pe[wid][k][hh];
            float pw = p * s_w[wid][k];
            ushort4 xv = *(const ushort4*)&xsd[(size_t)s * 288 + ch0];
            num0 += pw * bf2f(xv.x); num1 += pw * bf2f(xv.y);
            num2 += pw * bf2f(xv.z); num3 += pw * bf2f(xv.w);
            den += p;
        }
    }

    float rden = 1.0f / den;
    // residual x + bias
    float xr0, xr1, xr2, xr3;
    if (f32) {
        float4 t = *(const float4*)((const float*)x + (size_t)node * 256 + ch0);
        xr0 = t.x; xr1 = t.y; xr2 = t.z; xr3 = t.w;
    } else {
        ushort4 t = *(const ushort4*)((const u16*)x + (size_t)node * 256 + ch0);
        xr0 = bf2f(t.x); xr1 = bf2f(t.y); xr2 = bf2f(t.z); xr3 = bf2f(t.w);
    }
    float v0 = num0 * rden + gld(bias, ch0 + 0, f32) + xr0;
    float v1 = num1 * rden + gld(bias, ch0 + 1, f32) + xr1;
    float v2 = num2 * rden + gld(bias, ch0 + 2, f32) + xr2;
    float v3 = num3 * rden + gld(bias, ch0 + 3, f32) + xr3;

    // fused LN1 (wave-local; same reduction order as old k_ln1)
    float mu = wave_sum(v0 + v1 + v2 + v3) * (1.f / 256.f);
    float d0 = v0 - mu, d1 = v1 - mu, d2 = v2 - mu, d3 = v3 - mu;
    float var = wave_sum(d0 * d0 + d1 * d1 + d2 * d2 + d3 * d3) * (1.f / 256.f);
    float rs = rsqrtf(var + 1e-5f);
    float o0 = d0 * rs * gld(g1, ch0 + 0, f32) + gld(b1, ch0 + 0, f32);
    float o1 = d1 * rs * gld(g1, ch0 + 1, f32) + gld(b1, ch0 + 1, f32);
    float o2 = d2 * rs * gld(g1, ch0 + 2, f32) + gld(b1, ch0 + 2, f32);
    float o3 = d3 * rs * gld(g1, ch0 + 3, f32) + gld(b1, ch0 + 3, f32);

    size_t base = (size_t)node * 256 + ch0;
    gst(hout, base + 0, f32, o0); gst(hout, base + 1, f32, o1);
    gst(hout, base + 2, f32, o2); gst(hout, base + 3, f32, o3);
    ushort4 hv; hv.x = f2bf(o0); hv.y = f2bf(o1); hv.z = f2bf(o2); hv.w = f2bf(o3);
    *(ushort4*)&hb[base] = hv;
}

// ---- residual + LN2 (chunked, in place on h rows [row0, row0+rows)): out = LN(h + ffn + fb2)
// ffn is bf16 (W2 epilogue stores bf16)
__global__ void __launch_bounds__(256) k_ln2(const u32* __restrict__ dflag,
                                             void* __restrict__ h, int row0, const u16* __restrict__ ffn,
                                             const void* __restrict__ fb2, const void* __restrict__ g,
                                             const void* __restrict__ b, int rows) {
    bool f32 = dflag[0] != 0u;
    int row = blockIdx.x * 4 + (threadIdx.x >> 6);
    if (row >= rows) return;
    int lane = threadIdx.x & 63;
    size_t hbase = (size_t)(row0 + row) * 256 + lane * 4;
    size_t fbase = (size_t)row * 256 + lane * 4;
    ushort4 tv = *(const ushort4*)(ffn + fbase);
    float v0 = bf2f(tv.x) + gld(h, hbase + 0, f32) + gld(fb2, lane * 4 + 0, f32);
    float v1 = bf2f(tv.y) + gld(h, hbase + 1, f32) + gld(fb2, lane * 4 + 1, f32);
    float v2 = bf2f(tv.z) + gld(h, hbase + 2, f32) + gld(fb2, lane * 4 + 2, f32);
    float v3 = bf2f(tv.w) + gld(h, hbase + 3, f32) + gld(fb2, lane * 4 + 3, f32);
    float mu = wave_sum(v0 + v1 + v2 + v3) * (1.f / 256.f);
    float d0 = v0 - mu, d1 = v1 - mu, d2 = v2 - mu, d3 = v3 - mu;
    float var = wave_sum(d0 * d0 + d1 * d1 + d2 * d2 + d3 * d3) * (1.f / 256.f);
    float rs = rsqrtf(var + 1e-5f);
    gst(h, hbase + 0, f32, d0 * rs * gld(g, lane * 4 + 0, f32) + gld(b, lane * 4 + 0, f32));
    gst(h, hbase + 1, f32, d1 * rs * gld(g, lane * 4 + 1, f32) + gld(b, lane * 4 + 1, f32));
    gst(h, hbase + 2, f32, d2 * rs * gld(g, lane * 4 + 2, f32) + gld(b, lane * 4 + 2, f32));
    gst(h, hbase + 3, f32, d3 * rs * gld(g, lane * 4 + 3, f32) + gld(b, lane * 4 + 3, f32));
}

extern "C" void kernel_launch(void* const* d_in, const int* in_sizes, int n_in,
                              void* d_out, int out_size, void* d_ws, size_t ws_size,
                              hipStream_t stream) {
    const int N = in_sizes[0] / 256;     // 50000
    const int E = in_sizes[1] / 2;       // 800000
    const int NB = (N + 255) / 256;      // 196

    const void* x    = d_in[0];
    const int*  ei   = (const int*)d_in[1];
    const int*  et   = (const int*)d_in[2];
    const void* ew   = d_in[3];
    const void* Wsrc = d_in[4];
    const void* Wdst = d_in[5];
    const void* attS = d_in[6];
    const void* attD = d_in[7];
    const void* bias = d_in[8];
    const void* g1   = d_in[9];
    const void* b1   = d_in[10];
    const void* g2   = d_in[11];
    const void* b2   = d_in[12];
    const void* W1   = d_in[13];
    const void* fb1  = d_in[14];
    const void* W2   = d_in[15];
    const void* fb2  = d_in[16];

    // Workspace layout (round 4 proved ws_size >= ~187 MB: full one-chunk FFN ran)
    char* ws = (char*)d_ws;
    u32* flag   = (u32*)(ws + 0);             // 256 B
    u32* bsum   = (u32*)(ws + 256);           // 1 KB
    u32* obuf   = (u32*)(ws + 1536);          // (N+1)*4 ~ 200 KB
    u32* cursor = (u32*)(ws + 201984);        // N*4 = 200 KB
    u32* elist  = (u32*)(ws + 402176);        // E*4 = 3.2 MB -> ends 3602176
    u16* xb     = (u16*)(ws + 3602176);       // [N,256] bf16 = 25.6 MB (x pre-cvt)
    u16* hb     = (u16*)(ws + 3602176);       // [N,256] bf16 post-LN1 (xb dead by then)
    u16* xsd    = (u16*)(ws + 29202176);      // [N,288] bf16 = 28.8 MB (xs | 32 dots)
    u16* Bcat   = (u16*)(ws + 58002176);      // [288,256] bf16: Wsb rows 0-255, Mmat 256-287
    u16* W1b    = (u16*)(ws + 58149632);      // [1024,256] bf16 = 512 KB
    u16* W2b    = (u16*)(ws + 58673920);      // [256,1024] bf16 = 512 KB
    char* ffnbuf = ws + 59198208;             // FFN chunk buffers (runtime sized)
    void* hbuf  = d_out;                      // h -> out staged in d_out (dtype = flag)

    k_probe<<<1, 256, 0, stream>>>((const u16*)x, flag);

    // bf16 pre-conversion of all GEMM operands (identity if inputs already bf16)
    k_cvt<<<(N * 32 + 255) / 256, 256, 0, stream>>>(flag, x, xb, N * 32);       // N*256/8
    k_cvt<<<32, 256, 0, stream>>>(flag, Wsrc, Bcat, 8192);                      // 256*256/8
    k_cvt<<<128, 256, 0, stream>>>(flag, W1, W1b, 32768);                       // 1024*256/8
    k_cvt<<<128, 256, 0, stream>>>(flag, W2, W2b, 32768);                       // 256*1024/8
    k_mkatt<<<32, 256, 0, stream>>>(flag, Wsrc, Wdst, attS, attD, Bcat + 256 * 256, 256);

    const int gyN = (N + 127) / 128;          // 391

    // xsd[N,288] = xb @ [Wsb; Mmat]^T  (x_src features + all 32 att dots, one pass)
    mgemm4<0><<<dim3(3, gyN), 256, 0, stream>>>(flag, xb, Bcat, xsd, nullptr, N, 288, 256, 288, 0);

    // CSR build
    k_zero<<<NB, 256, 0, stream>>>(obuf, N);
    k_count<<<(E + 255) / 256, 256, 0, stream>>>(ei, obuf, E);
    k_scanA<<<NB, 256, 0, stream>>>(obuf, bsum, N);
    k_scanB<<<1, 256, 0, stream>>>(bsum, NB);
    k_scanC<<<NB, 256, 0, stream>>>(obuf, cursor, bsum, N, E);
    k_scatter<<<(E + 255) / 256, 256, 0, stream>>>(ei, cursor, elist, E);

    // aggregation + fused LN1 (one wave per node) -> h in d_out + hb bf16
    k_node<<<(N + 3) / 4, 256, 0, stream>>>(flag, ei, et, ew, x, xsd, obuf, elist,
                                            bias, g1, b1, hbuf, hb, N);

    // FFN + LN2, chunked to fit remaining ws: 2560 B/row (act bf16 1024 + ffnout bf16 256)
    long long avail = (long long)ws_size - 59198208 - 256;
    int rc = (int)(avail / 2560);
    rc &= ~127;
    if (rc > 50048) rc = 50048;
    if (rc < 128) rc = 128;
    u16* act    = (u16*)ffnbuf;
    u16* ffnout = (u16*)(ffnbuf + (size_t)rc * 2048);

    for (int r0 = 0; r0 < N; r0 += rc) {
        int rows = N - r0; if (rows > rc) rows = rc;
        int gy = (rows + 127) / 128;
        mgemm4<1><<<dim3(8, gy), 256, 0, stream>>>(flag, hb, W1b, act, fb1, rows, 1024, 256, 1024, r0);
        mgemm4<0><<<dim3(2, gy), 256, 0, stream>>>(flag, act, W2b, ffnout, nullptr, rows, 256, 1024, 256, 0);
        k_ln2<<<(rows + 3) / 4, 256, 0, stream>>>(flag, hbuf, r0, ffnout, fb2, g2, b2, rows);
    }
}

// Round 8
// 560.452 us; speedup vs baseline: 14.4484x; 1.1088x over previous
//
#include <hip/hip_runtime.h>

typedef unsigned short u16;
typedef unsigned int u32;
typedef __attribute__((ext_vector_type(8))) unsigned short ushort8v;
typedef __attribute__((ext_vector_type(8))) __bf16 bf16x8;
typedef __attribute__((ext_vector_type(4))) float f32x4;

__device__ __forceinline__ float bf2f(u16 u) { return __uint_as_float(((u32)u) << 16); }
__device__ __forceinline__ u16 f2bf(float f) {
    u32 u = __float_as_uint(f);
    u32 r = u + 0x7fffu + ((u >> 16) & 1u);
    return (u16)(r >> 16);
}
__device__ __forceinline__ float wave_sum(float v) {
    #pragma unroll
    for (int m = 1; m < 64; m <<= 1) v += __shfl_xor(v, m, 64);
    return v;
}
// dtype-flexible load/store: f32=true -> float32 buffer, else bf16 (u16) buffer
__device__ __forceinline__ float gld(const void* p, size_t i, bool f32) {
    return f32 ? ((const float*)p)[i] : bf2f(((const u16*)p)[i]);
}
__device__ __forceinline__ void gst(void* p, size_t i, bool f32, float v) {
    if (f32) ((float*)p)[i] = v;
    else     ((u16*)p)[i] = f2bf(v);
}
__device__ __forceinline__ void ldf8(const void* p, size_t i, bool f32, float* o) {
    if (f32) {
        const float4* q = (const float4*)((const float*)p + i);
        float4 a = q[0], b = q[1];
        o[0] = a.x; o[1] = a.y; o[2] = a.z; o[3] = a.w;
        o[4] = b.x; o[5] = b.y; o[6] = b.z; o[7] = b.w;
    } else {
        ushort8v v = *(const ushort8v*)((const u16*)p + i);
        #pragma unroll
        for (int j = 0; j < 8; j++) o[j] = bf2f(v[j]);
    }
}
// async global(bf16)->LDS, 16 bytes per lane; LDS dst is wave-uniform base + lane*16
__device__ __forceinline__ void gl2lds16(const u16* g, u16* l) {
    __builtin_amdgcn_global_load_lds((const __attribute__((address_space(1))) void*)g,
                                     (__attribute__((address_space(3))) void*)l, 16, 0, 0);
}
// fast gelu: A&S 3-term erf, |err(erf)| <= 2.5e-5 (invisible under bf16 rounding)
__device__ __forceinline__ float gelu_f(float v) {
    float ay = fabsf(v) * 0.70710678f;
    float t = __builtin_amdgcn_rcpf(1.0f + 0.47047f * ay);
    float poly = t * (0.3480242f + t * (-0.0958798f + t * 0.7478556f));
    float erfa = 1.0f - poly * __expf(-ay * ay);
    float er = (v >= 0.f) ? erfa : -erfa;
    return 0.5f * v * (1.0f + er);
}

// ---- dtype probe: bf16 N(0,1) decodes |v|<~5 always; f32 viewed as u16 halves
// has ~48% of low-half words decoding to |v|>64 or NaN -> flags within 1024 floats.
__global__ void __launch_bounds__(256) k_probe(const u16* __restrict__ x, u32* __restrict__ flag) {
    __shared__ int cnt;
    if (threadIdx.x == 0) cnt = 0;
    __syncthreads();
    int bad = 0;
    for (int i = threadIdx.x; i < 2048; i += 256) {
        float v = bf2f(x[i]);
        if (!(v > -64.f && v < 64.f)) bad = 1;
    }
    if (bad) atomicAdd(&cnt, 1);
    __syncthreads();
    if (threadIdx.x == 0) flag[0] = (cnt > 0) ? 1u : 0u;
}

__global__ void __launch_bounds__(256) k_zero(u32* __restrict__ p, int n) {
    int i = blockIdx.x * 256 + threadIdx.x;
    if (i < n) p[i] = 0u;
}

// ---- convert a tensor (dtype per flag) to bf16, 8 elems/thread
__global__ void __launch_bounds__(256) k_cvt(const u32* __restrict__ dflag,
                                             const void* __restrict__ src, u16* __restrict__ dst, int n8) {
    bool f32 = dflag[0] != 0u;
    int i = blockIdx.x * 256 + threadIdx.x;
    if (i >= n8) return;
    float t[8];
    ldf8(src, (size_t)i * 8, f32, t);
    ushort8v o;
    #pragma unroll
    for (int j = 0; j < 8; j++) o[j] = f2bf(t[j]);
    *(ushort8v*)&dst[(size_t)i * 8] = o;
}

// ---- MFMA bf16 GEMM, BK=32 double-buffered (32 KB LDS -> 5 blocks/CU):
// C[m,n] = sum_k A[arow0+m,k]*B[n,k]. Tile 128x128, 4 waves (2x2 of 64x64).
// Granule XOR-swizzle by row bits 1-2 on BOTH sides -> ~0 LDS conflicts
// (harness-verified rounds 6-7). EPI: 0 = bf16 store; 1 = bf16 gelu(acc+bias[col]).
template <int EPI>
__global__ void __launch_bounds__(256, 5) mgemm4(const u32* __restrict__ dflag,
                                                 const u16* __restrict__ A, const u16* __restrict__ B,
                                                 void* __restrict__ Cout, const void* __restrict__ bias,
                                                 int M, int Nn, int K, int ldC, int arow0) {
    const bool ibf32 = dflag[0] != 0u;
    __shared__ __attribute__((aligned(16))) u16 sA[2][128 * 32];
    __shared__ __attribute__((aligned(16))) u16 sB[2][128 * 32];

    // XCD swizzle: contiguous chunk of remapped ids per XCD (bijective for any nwg)
    int nwg = gridDim.x * gridDim.y;
    int wgid = blockIdx.y * gridDim.x + blockIdx.x;
    if (nwg >= 16) {
        int q = nwg >> 3, r = nwg & 7;
        int xcd = wgid & 7, i = wgid >> 3;
        wgid = (xcd < r ? xcd * (q + 1) : r * (q + 1) + (xcd - r) * q) + i;
    }
    const int m0 = (wgid / gridDim.x) * 128;
    const int n0 = (wgid % gridDim.x) * 128;

    const int tid = threadIdx.x;
    const int wid = tid >> 6;
    const int lane = tid & 63;

    const int wm = (wid >> 1) * 64;
    const int wn = (wid & 1) * 64;
    const int lr = lane & 15;
    const int kg = lane >> 4;
    const int gsw = (kg ^ ((lr >> 1) & 3)) * 8;

    const int srow = lane >> 2;
    const int scol = ((lane & 3) ^ ((lane >> 3) & 3)) * 8;

    f32x4 acc[4][4] = {};

    const size_t abase = (size_t)arow0 * K;

    // prologue: stage tile 0 into buf 0 (2 A-units + 2 B-units per wave)
    {
        #pragma unroll
        for (int j = 0; j < 2; j++) {
            int u = wid * 2 + j;
            int gr = m0 + u * 16 + srow; if (gr >= M) gr = M - 1;
            gl2lds16(A + abase + (size_t)gr * K + scol, &sA[0][u * 512]);
        }
        #pragma unroll
        for (int j = 0; j < 2; j++) {
            int u = wid * 2 + j;
            int gr = n0 + u * 16 + srow; if (gr >= Nn) gr = Nn - 1;
            gl2lds16(B + (size_t)gr * K + scol, &sB[0][u * 512]);
        }
    }
    __syncthreads();

    int cur = 0;
    for (int k0 = 0; k0 < K; k0 += 32) {
        if (k0 + 32 < K) {
            int nb = cur ^ 1, k1 = k0 + 32;
            #pragma unroll
            for (int j = 0; j < 2; j++) {
                int u = wid * 2 + j;
                int gr = m0 + u * 16 + srow; if (gr >= M) gr = M - 1;
                gl2lds16(A + abase + (size_t)gr * K + k1 + scol, &sA[nb][u * 512]);
            }
            #pragma unroll
            for (int j = 0; j < 2; j++) {
                int u = wid * 2 + j;
                int gr = n0 + u * 16 + srow; if (gr >= Nn) gr = Nn - 1;
                gl2lds16(B + (size_t)gr * K + k1 + scol, &sB[nb][u * 512]);
            }
        }
        {
            bf16x8 afr[4], bfr[4];
            #pragma unroll
            for (int m = 0; m < 4; m++)
                afr[m] = __builtin_bit_cast(bf16x8, *(const ushort8v*)&sA[cur][(wm + m * 16 + lr) * 32 + gsw]);
            #pragma unroll
            for (int n = 0; n < 4; n++)
                bfr[n] = __builtin_bit_cast(bf16x8, *(const ushort8v*)&sB[cur][(wn + n * 16 + lr) * 32 + gsw]);
            #pragma unroll
            for (int m = 0; m < 4; m++)
                #pragma unroll
                for (int n = 0; n < 4; n++)
                    acc[m][n] = __builtin_amdgcn_mfma_f32_16x16x32_bf16(afr[m], bfr[n], acc[m][n], 0, 0, 0);
        }
        __syncthreads();
        cur ^= 1;
    }

    // C/D: col = lane&15, row = (lane>>4)*4 + reg  [harness-verified rounds 1-7]
    float bv[4];
    if (EPI == 1) {
        #pragma unroll
        for (int n = 0; n < 4; n++) {
            int cn = n0 + wn + n * 16 + lr; if (cn >= Nn) cn = Nn - 1;
            bv[n] = gld(bias, cn, ibf32);
        }
    }
    const int or0 = (lane >> 4) << 2;
    #pragma unroll
    for (int m = 0; m < 4; m++) {
        #pragma unroll
        for (int r = 0; r < 4; r++) {
            int gr = m0 + wm + m * 16 + or0 + r;
            if (gr >= M) continue;
            #pragma unroll
            for (int n = 0; n < 4; n++) {
                int cn = n0 + wn + n * 16 + lr;
                if (cn >= Nn) continue;
                float v = acc[m][n][r];
                if (EPI == 1) {
                    ((u16*)Cout)[(size_t)gr * ldC + cn] = f2bf(gelu_f(v + bv[n]));
                } else {
                    ((u16*)Cout)[(size_t)gr * ldC + cn] = f2bf(v);
                }
            }
        }
    }
}

// ---- W2 GEMM + fused residual LN2. Tile 64 rows x 256 cols (FULL output width),
// K=1024, BK=32 double-buffered. 4 waves 1x4 (wave: 64x64, 4x4 frags).
// LDS: sA 8 KB + sB 32 KB + red 2 KB = 42 KB -> 3 blocks/CU.
// Epilogue: val = acc + h[row,col] + fb2[col]; per-row mean/var via shfl (16 lanes)
// + cross-wave LDS reduce (E[x^2]-mu^2, clamped); writes LN2 output to hout in place.
__global__ void __launch_bounds__(256, 3) mgemm5(const u32* __restrict__ dflag,
                                                 const u16* __restrict__ A, const u16* __restrict__ B,
                                                 void* __restrict__ hout,
                                                 const void* __restrict__ fb2, const void* __restrict__ g2,
                                                 const void* __restrict__ b2, int M, int r0) {
    const bool f32 = dflag[0] != 0u;
    constexpr int K = 1024;
    __shared__ __attribute__((aligned(16))) u16 sA[2][64 * 32];
    __shared__ __attribute__((aligned(16))) u16 sB[2][256 * 32];
    __shared__ float red[4][64][2];

    int nwg = gridDim.x;
    int wgid = blockIdx.x;
    if (nwg >= 16) {
        int q = nwg >> 3, r = nwg & 7;
        int xcd = wgid & 7, i = wgid >> 3;
        wgid = (xcd < r ? xcd * (q + 1) : r * (q + 1) + (xcd - r) * q) + i;
    }
    const int m0 = wgid * 64;

    const int tid = threadIdx.x;
    const int wid = tid >> 6;
    const int lane = tid & 63;
    const int lr = lane & 15;
    const int kg = lane >> 4;
    const int gsw = (kg ^ ((lr >> 1) & 3)) * 8;
    const int srow = lane >> 2;
    const int scol = ((lane & 3) ^ ((lane >> 3) & 3)) * 8;

    f32x4 acc[4][4] = {};

    // prologue: A 4 units (1/wave), B 16 units (4/wave)
    {
        int gr = m0 + wid * 16 + srow; if (gr >= M) gr = M - 1;
        gl2lds16(A + (size_t)gr * K + scol, &sA[0][wid * 512]);
        #pragma unroll
        for (int j = 0; j < 4; j++) {
            int u = wid * 4 + j;
            gl2lds16(B + (size_t)(u * 16 + srow) * K + scol, &sB[0][u * 512]);
        }
    }
    __syncthreads();

    int cur = 0;
    for (int k0 = 0; k0 < K; k0 += 32) {
        if (k0 + 32 < K) {
            int nb = cur ^ 1, k1 = k0 + 32;
            int gr = m0 + wid * 16 + srow; if (gr >= M) gr = M - 1;
            gl2lds16(A + (size_t)gr * K + k1 + scol, &sA[nb][wid * 512]);
            #pragma unroll
            for (int j = 0; j < 4; j++) {
                int u = wid * 4 + j;
                gl2lds16(B + (size_t)(u * 16 + srow) * K + k1 + scol, &sB[nb][u * 512]);
            }
        }
        {
            bf16x8 afr[4], bfr[4];
            #pragma unroll
            for (int m = 0; m < 4; m++)
                afr[m] = __builtin_bit_cast(bf16x8, *(const ushort8v*)&sA[cur][(m * 16 + lr) * 32 + gsw]);
            #pragma unroll
            for (int n = 0; n < 4; n++)
                bfr[n] = __builtin_bit_cast(bf16x8, *(const ushort8v*)&sB[cur][(wid * 64 + n * 16 + lr) * 32 + gsw]);
            #pragma unroll
            for (int m = 0; m < 4; m++)
                #pragma unroll
                for (int n = 0; n < 4; n++)
                    acc[m][n] = __builtin_amdgcn_mfma_f32_16x16x32_bf16(afr[m], bfr[n], acc[m][n], 0, 0, 0);
        }
        __syncthreads();
        cur ^= 1;
    }

    // epilogue: val = acc + h + fb2; per-row LN over 256 cols
    float fb[4], gg[4], bb[4];
    #pragma unroll
    for (int n = 0; n < 4; n++) {
        int cn = wid * 64 + n * 16 + lr;
        fb[n] = gld(fb2, cn, f32); gg[n] = gld(g2, cn, f32); bb[n] = gld(b2, cn, f32);
    }
    const int or0 = (lane >> 4) << 2;
    float s1[4][4], s2[4][4];
    #pragma unroll
    for (int m = 0; m < 4; m++) {
        #pragma unroll
        for (int r = 0; r < 4; r++) {
            int grow = m * 16 + or0 + r;
            float a1 = 0.f, a2 = 0.f;
            if (m0 + grow < M) {
                #pragma unroll
                for (int n = 0; n < 4; n++) {
                    int cn = wid * 64 + n * 16 + lr;
                    float hv = gld(hout, (size_t)(r0 + m0 + grow) * 256 + cn, f32);
                    float v = acc[m][n][r] + hv + fb[n];
                    acc[m][n][r] = v;
                    a1 += v; a2 += v * v;
                }
            }
            s1[m][r] = a1; s2[m][r] = a2;
        }
    }
    // reduce over the 16 lanes (lr) sharing each row
    #pragma unroll
    for (int m = 0; m < 4; m++)
        #pragma unroll
        for (int r = 0; r < 4; r++) {
            #pragma unroll
            for (int d = 1; d < 16; d <<= 1) {
                s1[m][r] += __shfl_xor(s1[m][r], d, 64);
                s2[m][r] += __shfl_xor(s2[m][r], d, 64);
            }
        }
    if (lr == 0) {
        #pragma unroll
        for (int m = 0; m < 4; m++)
            #pragma unroll
            for (int r = 0; r < 4; r++) {
                int grow = m * 16 + or0 + r;
                red[wid][grow][0] = s1[m][r];
                red[wid][grow][1] = s2[m][r];
            }
    }
    __syncthreads();
    #pragma unroll
    for (int m = 0; m < 4; m++) {
        #pragma unroll
        for (int r = 0; r < 4; r++) {
            int grow = m * 16 + or0 + r;
            if (m0 + grow >= M) continue;
            float t1 = red[0][grow][0] + red[1][grow][0] + red[2][grow][0] + red[3][grow][0];
            float t2 = red[0][grow][1] + red[1][grow][1] + red[2][grow][1] + red[3][grow][1];
            float mu = t1 * (1.f / 256.f);
            float var = fmaxf(t2 * (1.f / 256.f) - mu * mu, 0.f);
            float rs = rsqrtf(var + 1e-5f);
            #pragma unroll
            for (int n = 0; n < 4; n++) {
                int cn = wid * 64 + n * 16 + lr;
                float o = (acc[m][n][r] - mu) * rs * gg[n] + bb[n];
                gst(hout, (size_t)(r0 + m0 + grow) * 256 + cn, f32, o);
            }
        }
    }
}

// ---- fold attention vectors through W: Mmat[th][k] (bf16, [32,256])
__global__ void __launch_bounds__(256) k_mkatt(const u32* __restrict__ dflag,
                                               const void* __restrict__ Wsrc, const void* __restrict__ Wdst,
                                               const void* __restrict__ attS, const void* __restrict__ attD,
                                               u16* __restrict__ Mmat, int K) {
    bool f32 = dflag[0] != 0u;
    int th = blockIdx.x;   // 0..31
    int k = threadIdx.x;   // 0..K-1 (K=256)
    int tt = th & 15;
    const void* W = (th < 16) ? Wsrc : Wdst;
    const void* att = (th < 16) ? attS : attD;
    int h = tt & 7;
    float s = 0.f;
    #pragma unroll 8
    for (int c = 0; c < 32; c++)
        s += gld(W, (size_t)(h * 32 + c) * K + k, f32) * gld(att, tt * 32 + c, f32);
    Mmat[th * K + k] = f2bf(s);
}

// ---- CSR build (dst-major) ----
__global__ void __launch_bounds__(256) k_count(const int* __restrict__ ei, u32* __restrict__ cnt, int E) {
    int e = blockIdx.x * 256 + threadIdx.x;
    if (e < E) atomicAdd(cnt + ei[E + e], 1u);
}
__global__ void __launch_bounds__(256) k_scanA(u32* __restrict__ buf, u32* __restrict__ bsum, int N) {
    int t = threadIdx.x, idx = blockIdx.x * 256 + t;
    u32 v = (idx < N) ? buf[idx] : 0u;
    __shared__ u32 sc[256];
    sc[t] = v; __syncthreads();
    for (int d = 1; d < 256; d <<= 1) {
        u32 add = (t >= d) ? sc[t - d] : 0u; __syncthreads();
        sc[t] += add; __syncthreads();
    }
    if (idx < N) buf[idx] = sc[t] - v;
    if (t == 255) bsum[blockIdx.x] = sc[255];
}
__global__ void __launch_bounds__(256) k_scanB(u32* __restrict__ bsum, int nb) {
    int t = threadIdx.x;
    u32 v = (t < nb) ? bsum[t] : 0u;
    __shared__ u32 sc[256];
    sc[t] = v; __syncthreads();
    for (int d = 1; d < 256; d <<= 1) {
        u32 add = (t >= d) ? sc[t - d] : 0u; __syncthreads();
        sc[t] += add; __syncthreads();
    }
    if (t < nb) bsum[t] = sc[t] - v;
}
__global__ void __launch_bounds__(256) k_scanC(u32* __restrict__ obuf, u32* __restrict__ cursor,
                                               const u32* __restrict__ bsum, int N, int E) {
    int idx = blockIdx.x * 256 + threadIdx.x;
    if (idx < N) {
        u32 o = obuf[idx] + bsum[blockIdx.x];
        obuf[idx] = o;
        cursor[idx] = o;
    }
    if (blockIdx.x == 0 && threadIdx.x == 0) obuf[N] = (u32)E;
}
// scatter packed edge payload: pedge[slot] = {src | type<<31, bits(w)}
// -> k_node's stage reads ONE sequential 8 B instead of elist + 3 random gathers
__global__ void __launch_bounds__(256) k_scatter(const u32* __restrict__ dflag,
                                                 const int* __restrict__ ei, const int* __restrict__ et,
                                                 const void* __restrict__ ew, u32* __restrict__ cursor,
                                                 uint2* __restrict__ pedge, int E) {
    bool f32 = dflag[0] != 0u;
    int e = blockIdx.x * 256 + threadIdx.x;
    if (e >= E) return;
    u32 slot = atomicAdd(cursor + ei[E + e], 1u);
    uint2 pk;
    pk.x = (u32)ei[e] | ((u32)et[e] << 31);
    pk.y = __float_as_uint(gld(ew, e, f32));
    pedge[slot] = pk;
}

// ---- fused per-node softmax aggregation + LN1, ONE WAVE PER NODE (round-7 structure
// + packed pedge stage + 8-deep gather unroll).
// xsd = [N,288] bf16: cols 0..255 = x@Wsrc^T, cols 256..287 = the 32 att dots.
__global__ void __launch_bounds__(256) k_node(const u32* __restrict__ dflag,
                                              const uint2* __restrict__ pedge, const void* __restrict__ x,
                                              const u16* __restrict__ xsd,
                                              const u32* __restrict__ obuf,
                                              const void* __restrict__ bias,
                                              const void* __restrict__ g1, const void* __restrict__ b1,
                                              void* __restrict__ hout, u16* __restrict__ hb, int N) {
    bool f32 = dflag[0] != 0u;
    const int wid = threadIdx.x >> 6;
    const int lane = threadIdx.x & 63;
    const int node = blockIdx.x * 4 + wid;
    if (node >= N) return;

    __shared__ u32 s_src[4][64];
    __shared__ float s_w[4][64];
    __shared__ float s_pe[4][64][8];

    const int ch0 = lane * 4;
    const int hh = lane >> 3;
    const size_t nbase = (size_t)node * 288;

    ushort8v dd0v = *(const ushort8v*)&xsd[nbase + 256 + 16];
    ushort8v dd1v = *(const ushort8v*)&xsd[nbase + 256 + 24];

    // self-loop: type 0, weight 1
    float a_self = bf2f(xsd[nbase + 256 + hh]) + bf2f(xsd[nbase + 256 + 16 + hh]);
    float p_self = __expf(a_self >= 0.f ? a_self : 0.2f * a_self);
    float den = p_self;
    ushort4 sv = *(const ushort4*)&xsd[nbase + ch0];
    float num0 = p_self * bf2f(sv.x), num1 = p_self * bf2f(sv.y);
    float num2 = p_self * bf2f(sv.z), num3 = p_self * bf2f(sv.w);

    const u32 kbeg = obuf[node], kend = obuf[node + 1];
    for (u32 c0 = kbeg; c0 < kend; c0 += 64) {
        int cnt = (int)(kend - c0) < 64 ? (int)(kend - c0) : 64;
        __builtin_amdgcn_wave_barrier();   // compiler fence: prior chunk reads done
        if (lane < cnt) {
            uint2 pe = pedge[c0 + lane];
            u32 src = pe.x & 0x7fffffffu;
            int t = (int)(pe.x >> 31);
            s_src[wid][lane] = src;
            s_w[wid][lane] = __uint_as_float(pe.y);
            ushort8v ds8 = *(const ushort8v*)&xsd[(size_t)src * 288 + 256 + t * 8];
            ushort8v ddv = t ? dd1v : dd0v;
            #pragma unroll
            for (int h = 0; h < 8; h++) {
                float aa = bf2f(ds8[h]) + bf2f(ddv[h]);
                s_pe[wid][lane][h] = __expf(aa >= 0.f ? aa : 0.2f * aa);
            }
        }
        __builtin_amdgcn_wave_barrier();   // compiler fence: stage visible before reads
        int k = 0;
        for (; k + 8 <= cnt; k += 8) {
            u32 ss[8]; float pp[8], ww[8]; ushort4 gv[8];
            #pragma unroll
            for (int j = 0; j < 8; j++) {
                ss[j] = s_src[wid][k + j];
                pp[j] = s_pe[wid][k + j][hh];
                ww[j] = s_w[wid][k + j];
            }
            #pragma unroll
            for (int j = 0; j < 8; j++)
                gv[j] = *(const ushort4*)&xsd[(size_t)ss[j] * 288 + ch0];
            #pragma unroll
            for (int j = 0; j < 8; j++) {
                float q = pp[j] * ww[j];
                num0 += q * bf2f(gv[j].x); num1 += q * bf2f(gv[j].y);
                num2 += q * bf2f(gv[j].z); num3 += q * bf2f(gv[j].w);
                den += pp[j];
            }
        }
        for (; k + 4 <= cnt; k += 4) {
            u32 ss[4]; float pp[4], ww[4]; ushort4 gv[4];
            #pragma unroll
            for (int j = 0; j < 4; j++) {
                ss[j] = s_src[wid][k + j];
                pp[j] = s_pe[wid][k + j][hh];
                ww[j] = s_w[wid][k + j];
            }
            #pragma unroll
            for (int j = 0; j < 4; j++)
                gv[j] = *(const ushort4*)&xsd[(size_t)ss[j] * 288 + ch0];
            #pragma unroll
            for (int j = 0; j < 4; j++) {
                float q = pp[j] * ww[j];
                num0 += q * bf2f(gv[j].x); num1 += q * bf2f(gv[j].y);
                num2 += q * bf2f(gv[j].z); num3 += q * bf2f(gv[j].w);
                den += pp[j];
            }
        }
        for (; k < cnt; k++) {
            u32 s = s_src[wid][k];
            float p = s_pe[wid][k][hh];
            float pw = p * s_w[wid][k];
            ushort4 xv = *(const ushort4*)&xsd[(size_t)s * 288 + ch0];
            num0 += pw * bf2f(xv.x); num1 += pw * bf2f(xv.y);
            num2 += pw * bf2f(xv.z); num3 += pw * bf2f(xv.w);
            den += p;
        }
    }

    float rden = 1.0f / den;
    float xr0, xr1, xr2, xr3;
    if (f32) {
        float4 t = *(const float4*)((const float*)x + (size_t)node * 256 + ch0);
        xr0 = t.x; xr1 = t.y; xr2 = t.z; xr3 = t.w;
    } else {
        ushort4 t = *(const ushort4*)((const u16*)x + (size_t)node * 256 + ch0);
        xr0 = bf2f(t.x); xr1 = bf2f(t.y); xr2 = bf2f(t.z); xr3 = bf2f(t.w);
    }
    float v0 = num0 * rden + gld(bias, ch0 + 0, f32) + xr0;
    float v1 = num1 * rden + gld(bias, ch0 + 1, f32) + xr1;
    float v2 = num2 * rden + gld(bias, ch0 + 2, f32) + xr2;
    float v3 = num3 * rden + gld(bias, ch0 + 3, f32) + xr3;

    // fused LN1 (wave-local)
    float mu = wave_sum(v0 + v1 + v2 + v3) * (1.f / 256.f);
    float d0 = v0 - mu, d1 = v1 - mu, d2 = v2 - mu, d3 = v3 - mu;
    float var = wave_sum(d0 * d0 + d1 * d1 + d2 * d2 + d3 * d3) * (1.f / 256.f);
    float rs = rsqrtf(var + 1e-5f);
    float o0 = d0 * rs * gld(g1, ch0 + 0, f32) + gld(b1, ch0 + 0, f32);
    float o1 = d1 * rs * gld(g1, ch0 + 1, f32) + gld(b1, ch0 + 1, f32);
    float o2 = d2 * rs * gld(g1, ch0 + 2, f32) + gld(b1, ch0 + 2, f32);
    float o3 = d3 * rs * gld(g1, ch0 + 3, f32) + gld(b1, ch0 + 3, f32);

    size_t base = (size_t)node * 256 + ch0;
    gst(hout, base + 0, f32, o0); gst(hout, base + 1, f32, o1);
    gst(hout, base + 2, f32, o2); gst(hout, base + 3, f32, o3);
    ushort4 hv; hv.x = f2bf(o0); hv.y = f2bf(o1); hv.z = f2bf(o2); hv.w = f2bf(o3);
    *(ushort4*)&hb[base] = hv;
}

extern "C" void kernel_launch(void* const* d_in, const int* in_sizes, int n_in,
                              void* d_out, int out_size, void* d_ws, size_t ws_size,
                              hipStream_t stream) {
    const int N = in_sizes[0] / 256;     // 50000
    const int E = in_sizes[1] / 2;       // 800000
    const int NB = (N + 255) / 256;      // 196

    const void* x    = d_in[0];
    const int*  ei   = (const int*)d_in[1];
    const int*  et   = (const int*)d_in[2];
    const void* ew   = d_in[3];
    const void* Wsrc = d_in[4];
    const void* Wdst = d_in[5];
    const void* attS = d_in[6];
    const void* attD = d_in[7];
    const void* bias = d_in[8];
    const void* g1   = d_in[9];
    const void* b1   = d_in[10];
    const void* g2   = d_in[11];
    const void* b2   = d_in[12];
    const void* W1   = d_in[13];
    const void* fb1  = d_in[14];
    const void* W2   = d_in[15];
    const void* fb2  = d_in[16];

    // Workspace layout (round 4+ proved ws_size >= ~187 MB: full one-chunk FFN ran)
    char* ws = (char*)d_ws;
    u32* flag   = (u32*)(ws + 0);             // 256 B
    u32* bsum   = (u32*)(ws + 256);           // 1 KB
    u32* obuf   = (u32*)(ws + 1536);          // (N+1)*4 ~ 200 KB
    u32* cursor = (u32*)(ws + 201984);        // N*4 = 200 KB -> ends 402176 (old elist slot free)
    u16* xb     = (u16*)(ws + 3602176);       // [N,256] bf16 = 25.6 MB (x pre-cvt)
    u16* hb     = (u16*)(ws + 3602176);       // [N,256] bf16 post-LN1 (xb dead by then)
    u16* xsd    = (u16*)(ws + 29202176);      // [N,288] bf16 = 28.8 MB (xs | 32 dots)
    u16* Bcat   = (u16*)(ws + 58002176);      // [288,256] bf16: Wsb rows 0-255, Mmat 256-287
    u16* W1b    = (u16*)(ws + 58149632);      // [1024,256] bf16 = 512 KB
    u16* W2b    = (u16*)(ws + 58673920);      // [256,1024] bf16 = 512 KB
    uint2* pedge = (uint2*)(ws + 59198208);   // [E] packed {src|t<<31, w} = 6.4 MB (dead before FFN)
    char* ffnbuf = ws + 59198208;             // FFN act buffer aliases pedge (temporally disjoint)
    void* hbuf  = d_out;                      // h -> out staged in d_out (dtype = flag)

    k_probe<<<1, 256, 0, stream>>>((const u16*)x, flag);

    // bf16 pre-conversion of all GEMM operands (identity if inputs already bf16)
    k_cvt<<<(N * 32 + 255) / 256, 256, 0, stream>>>(flag, x, xb, N * 32);
    k_cvt<<<32, 256, 0, stream>>>(flag, Wsrc, Bcat, 8192);
    k_cvt<<<128, 256, 0, stream>>>(flag, W1, W1b, 32768);
    k_cvt<<<128, 256, 0, stream>>>(flag, W2, W2b, 32768);
    k_mkatt<<<32, 256, 0, stream>>>(flag, Wsrc, Wdst, attS, attD, Bcat + 256 * 256, 256);

    const int gyN = (N + 127) / 128;          // 391

    // xsd[N,288] = xb @ [Wsb; Mmat]^T  (x_src features + all 32 att dots, one pass)
    mgemm4<0><<<dim3(3, gyN), 256, 0, stream>>>(flag, xb, Bcat, xsd, nullptr, N, 288, 256, 288, 0);

    // CSR build (packed payload)
    k_zero<<<NB, 256, 0, stream>>>(obuf, N);
    k_count<<<(E + 255) / 256, 256, 0, stream>>>(ei, obuf, E);
    k_scanA<<<NB, 256, 0, stream>>>(obuf, bsum, N);
    k_scanB<<<1, 256, 0, stream>>>(bsum, NB);
    k_scanC<<<NB, 256, 0, stream>>>(obuf, cursor, bsum, N, E);
    k_scatter<<<(E + 255) / 256, 256, 0, stream>>>(flag, ei, et, ew, cursor, pedge, E);

    // aggregation + fused LN1 (one wave per node) -> h in d_out + hb bf16
    k_node<<<(N + 3) / 4, 256, 0, stream>>>(flag, pedge, x, xsd, obuf,
                                            bias, g1, b1, hbuf, hb, N);

    // FFN: W1 (gelu epilogue) -> act; W2+LN2 fused writes final output in place.
    // 2048 B/row (act bf16 only).
    long long avail = (long long)ws_size - 59198208 - 256;
    int rc = (int)(avail / 2048);
    rc &= ~127;
    if (rc > 50048) rc = 50048;
    if (rc < 128) rc = 128;
    u16* act = (u16*)ffnbuf;

    for (int r0 = 0; r0 < N; r0 += rc) {
        int rows = N - r0; if (rows > rc) rows = rc;
        int gy = (rows + 127) / 128;
        mgemm4<1><<<dim3(8, gy), 256, 0, stream>>>(flag, hb, W1b, act, fb1, rows, 1024, 256, 1024, r0);
        int g5 = (rows + 63) / 64;
        mgemm5<<<g5, 256, 0, stream>>>(flag, act, W2b, hbuf, fb2, g2, b2, rows, r0);
    }
}

// Round 9
// 519.681 us; speedup vs baseline: 15.5820x; 1.0785x over previous
//
#include <hip/hip_runtime.h>

typedef unsigned short u16;
typedef unsigned int u32;
typedef __attribute__((ext_vector_type(8))) unsigned short ushort8v;
typedef __attribute__((ext_vector_type(8))) __bf16 bf16x8;
typedef __attribute__((ext_vector_type(4))) float f32x4;

__device__ __forceinline__ float bf2f(u16 u) { return __uint_as_float(((u32)u) << 16); }
__device__ __forceinline__ u16 f2bf(float f) {
    u32 u = __float_as_uint(f);
    u32 r = u + 0x7fffu + ((u >> 16) & 1u);
    return (u16)(r >> 16);
}
__device__ __forceinline__ float wave_sum(float v) {
    #pragma unroll
    for (int m = 1; m < 64; m <<= 1) v += __shfl_xor(v, m, 64);
    return v;
}
// dtype-flexible load/store: f32=true -> float32 buffer, else bf16 (u16) buffer
__device__ __forceinline__ float gld(const void* p, size_t i, bool f32) {
    return f32 ? ((const float*)p)[i] : bf2f(((const u16*)p)[i]);
}
__device__ __forceinline__ void gst(void* p, size_t i, bool f32, float v) {
    if (f32) ((float*)p)[i] = v;
    else     ((u16*)p)[i] = f2bf(v);
}
__device__ __forceinline__ void ldf8(const void* p, size_t i, bool f32, float* o) {
    if (f32) {
        const float4* q = (const float4*)((const float*)p + i);
        float4 a = q[0], b = q[1];
        o[0] = a.x; o[1] = a.y; o[2] = a.z; o[3] = a.w;
        o[4] = b.x; o[5] = b.y; o[6] = b.z; o[7] = b.w;
    } else {
        ushort8v v = *(const ushort8v*)((const u16*)p + i);
        #pragma unroll
        for (int j = 0; j < 8; j++) o[j] = bf2f(v[j]);
    }
}
// async global(bf16)->LDS, 16 bytes per lane; LDS dst is wave-uniform base + lane*16
__device__ __forceinline__ void gl2lds16(const u16* g, u16* l) {
    __builtin_amdgcn_global_load_lds((const __attribute__((address_space(1))) void*)g,
                                     (__attribute__((address_space(3))) void*)l, 16, 0, 0);
}
// fast gelu: A&S 3-term erf, |err(erf)| <= 2.5e-5 (invisible under bf16 rounding)
__device__ __forceinline__ float gelu_f(float v) {
    float ay = fabsf(v) * 0.70710678f;
    float t = __builtin_amdgcn_rcpf(1.0f + 0.47047f * ay);
    float poly = t * (0.3480242f + t * (-0.0958798f + t * 0.7478556f));
    float erfa = 1.0f - poly * __expf(-ay * ay);
    float er = (v >= 0.f) ? erfa : -erfa;
    return 0.5f * v * (1.0f + er);
}

// ---- dtype probe: bf16 N(0,1) decodes |v|<~5 always; f32 viewed as u16 halves
// has ~48% of low-half words decoding to |v|>64 or NaN -> flags within 1024 floats.
__global__ void __launch_bounds__(256) k_probe(const u16* __restrict__ x, u32* __restrict__ flag) {
    __shared__ int cnt;
    if (threadIdx.x == 0) cnt = 0;
    __syncthreads();
    int bad = 0;
    for (int i = threadIdx.x; i < 2048; i += 256) {
        float v = bf2f(x[i]);
        if (!(v > -64.f && v < 64.f)) bad = 1;
    }
    if (bad) atomicAdd(&cnt, 1);
    __syncthreads();
    if (threadIdx.x == 0) flag[0] = (cnt > 0) ? 1u : 0u;
}

__global__ void __launch_bounds__(256) k_zero(u32* __restrict__ p, int n) {
    int i = blockIdx.x * 256 + threadIdx.x;
    if (i < n) p[i] = 0u;
}

// ---- convert a tensor (dtype per flag) to bf16, 8 elems/thread
__global__ void __launch_bounds__(256) k_cvt(const u32* __restrict__ dflag,
                                             const void* __restrict__ src, u16* __restrict__ dst, int n8) {
    bool f32 = dflag[0] != 0u;
    int i = blockIdx.x * 256 + threadIdx.x;
    if (i >= n8) return;
    float t[8];
    ldf8(src, (size_t)i * 8, f32, t);
    ushort8v o;
    #pragma unroll
    for (int j = 0; j < 8; j++) o[j] = f2bf(t[j]);
    *(ushort8v*)&dst[(size_t)i * 8] = o;
}

// ---- MFMA bf16 GEMM, BK=32 double-buffered (32 KB LDS -> 5 blocks/CU):
// C[m,n] = sum_k A[arow0+m,k]*B[n,k]. Tile 128x128, 4 waves (2x2 of 64x64).
// Granule XOR-swizzle by row bits 1-2 on BOTH sides -> ~0 LDS conflicts
// (harness-verified rounds 6-8).
// NEW: LDS-repack epilogue -- acc written to LDS (fragment layout), then all 256
// threads store contiguous 256 B per row (16 lanes x ushort8). Replaces the
// 32 B-segment scattered u16 stores that caused ~27 MB write amplification.
// EPI: 0 = bf16 store; 1 = bf16 gelu(acc+bias[col]).
template <int EPI>
__global__ void __launch_bounds__(256, 5) mgemm4(const u32* __restrict__ dflag,
                                                 const u16* __restrict__ A, const u16* __restrict__ B,
                                                 void* __restrict__ Cout, const void* __restrict__ bias,
                                                 int M, int Nn, int K, int ldC, int arow0) {
    const bool ibf32 = dflag[0] != 0u;
    __shared__ __attribute__((aligned(16))) u16 smem[16384];  // sA[2][4096] | sB[2][4096]; repack [128][128]
    u16* const sAb = smem;
    u16* const sBb = smem + 8192;

    // XCD swizzle: contiguous chunk of remapped ids per XCD (bijective for any nwg)
    int nwg = gridDim.x * gridDim.y;
    int wgid = blockIdx.y * gridDim.x + blockIdx.x;
    if (nwg >= 16) {
        int q = nwg >> 3, r = nwg & 7;
        int xcd = wgid & 7, i = wgid >> 3;
        wgid = (xcd < r ? xcd * (q + 1) : r * (q + 1) + (xcd - r) * q) + i;
    }
    const int m0 = (wgid / gridDim.x) * 128;
    const int n0 = (wgid % gridDim.x) * 128;

    const int tid = threadIdx.x;
    const int wid = tid >> 6;
    const int lane = tid & 63;

    const int wm = (wid >> 1) * 64;
    const int wn = (wid & 1) * 64;
    const int lr = lane & 15;
    const int kg = lane >> 4;
    const int gsw = (kg ^ ((lr >> 1) & 3)) * 8;

    const int srow = lane >> 2;
    const int scol = ((lane & 3) ^ ((lane >> 3) & 3)) * 8;

    f32x4 acc[4][4] = {};

    const size_t abase = (size_t)arow0 * K;

    // prologue: stage tile 0 into buf 0 (2 A-units + 2 B-units per wave)
    {
        #pragma unroll
        for (int j = 0; j < 2; j++) {
            int u = wid * 2 + j;
            int gr = m0 + u * 16 + srow; if (gr >= M) gr = M - 1;
            gl2lds16(A + abase + (size_t)gr * K + scol, &sAb[u * 512]);
        }
        #pragma unroll
        for (int j = 0; j < 2; j++) {
            int u = wid * 2 + j;
            int gr = n0 + u * 16 + srow; if (gr >= Nn) gr = Nn - 1;
            gl2lds16(B + (size_t)gr * K + scol, &sBb[u * 512]);
        }
    }
    __syncthreads();

    int cur = 0;
    for (int k0 = 0; k0 < K; k0 += 32) {
        if (k0 + 32 < K) {
            int nb = cur ^ 1, k1 = k0 + 32;
            #pragma unroll
            for (int j = 0; j < 2; j++) {
                int u = wid * 2 + j;
                int gr = m0 + u * 16 + srow; if (gr >= M) gr = M - 1;
                gl2lds16(A + abase + (size_t)gr * K + k1 + scol, &sAb[nb * 4096 + u * 512]);
            }
            #pragma unroll
            for (int j = 0; j < 2; j++) {
                int u = wid * 2 + j;
                int gr = n0 + u * 16 + srow; if (gr >= Nn) gr = Nn - 1;
                gl2lds16(B + (size_t)gr * K + k1 + scol, &sBb[nb * 4096 + u * 512]);
            }
        }
        {
            bf16x8 afr[4], bfr[4];
            #pragma unroll
            for (int m = 0; m < 4; m++)
                afr[m] = __builtin_bit_cast(bf16x8, *(const ushort8v*)&sAb[cur * 4096 + (wm + m * 16 + lr) * 32 + gsw]);
            #pragma unroll
            for (int n = 0; n < 4; n++)
                bfr[n] = __builtin_bit_cast(bf16x8, *(const ushort8v*)&sBb[cur * 4096 + (wn + n * 16 + lr) * 32 + gsw]);
            #pragma unroll
            for (int m = 0; m < 4; m++)
                #pragma unroll
                for (int n = 0; n < 4; n++)
                    acc[m][n] = __builtin_amdgcn_mfma_f32_16x16x32_bf16(afr[m], bfr[n], acc[m][n], 0, 0, 0);
        }
        __syncthreads();   // last iteration's barrier also frees smem for the repack
        cur ^= 1;
    }

    // C/D frag: col = lane&15, row = (lane>>4)*4 + reg  [harness-verified rounds 1-8]
    float bv[4];
    if (EPI == 1) {
        #pragma unroll
        for (int n = 0; n < 4; n++) {
            int cn = n0 + wn + n * 16 + lr; if (cn >= Nn) cn = Nn - 1;
            bv[n] = gld(bias, cn, ibf32);
        }
    }
    const int or0 = (lane >> 4) << 2;
    // repack: acc -> smem[128][128] bf16 (same (row,col) mapping as old direct store)
    #pragma unroll
    for (int m = 0; m < 4; m++) {
        #pragma unroll
        for (int r = 0; r < 4; r++) {
            int row = wm + m * 16 + or0 + r;
            #pragma unroll
            for (int n = 0; n < 4; n++) {
                int col = wn + n * 16 + lr;
                float v = acc[m][n][r];
                if (EPI == 1) v = gelu_f(v + bv[n]);
                smem[row * 128 + col] = f2bf(v);
            }
        }
    }
    __syncthreads();
    {
        const int rr = tid >> 4;          // 0..15
        const int cg = (tid & 15) * 8;    // col granule (8 u16 = 16 B)
        #pragma unroll
        for (int p = 0; p < 8; p++) {
            int row = p * 16 + rr;
            int gr = m0 + row;
            if (gr < M && n0 + cg + 8 <= Nn) {
                *(ushort8v*)&((u16*)Cout)[(size_t)gr * ldC + n0 + cg] =
                    *(const ushort8v*)&smem[row * 128 + cg];
            }
        }
    }
}

// ---- W2 GEMM + fused residual LN2. Tile 64 rows x 256 cols (FULL output width),
// K=1024, BK=32 double-buffered. 4 waves 1x4 (wave: 64x64, 4x4 frags).
// LDS: sA 8 KB + sB 32 KB + red 2 KB = 42 KB -> 3 blocks/CU.
// Epilogue: val = acc + h[row,col] + fb2[col]; per-row mean/var via shfl + cross-wave
// LDS reduce (E[x^2]-mu^2, clamped). NEW: normalized outputs repacked through LDS
// (aliasing sB) and stored as contiguous float4/ushort8 rows (was 4-B scatter,
// 58.6 MB written for a 25.6 MB output).
__global__ void __launch_bounds__(256, 3) mgemm5(const u32* __restrict__ dflag,
                                                 const u16* __restrict__ A, const u16* __restrict__ B,
                                                 void* __restrict__ hout,
                                                 const void* __restrict__ fb2, const void* __restrict__ g2,
                                                 const void* __restrict__ b2, int M, int r0) {
    const bool f32 = dflag[0] != 0u;
    constexpr int K = 1024;
    __shared__ __attribute__((aligned(16))) u16 sA[2][64 * 32];
    __shared__ __attribute__((aligned(16))) u16 sB[2][256 * 32];   // repack alias: 32 KB
    __shared__ float red[4][64][2];

    int nwg = gridDim.x;
    int wgid = blockIdx.x;
    if (nwg >= 16) {
        int q = nwg >> 3, r = nwg & 7;
        int xcd = wgid & 7, i = wgid >> 3;
        wgid = (xcd < r ? xcd * (q + 1) : r * (q + 1) + (xcd - r) * q) + i;
    }
    const int m0 = wgid * 64;

    const int tid = threadIdx.x;
    const int wid = tid >> 6;
    const int lane = tid & 63;
    const int lr = lane & 15;
    const int kg = lane >> 4;
    const int gsw = (kg ^ ((lr >> 1) & 3)) * 8;
    const int srow = lane >> 2;
    const int scol = ((lane & 3) ^ ((lane >> 3) & 3)) * 8;

    f32x4 acc[4][4] = {};

    // prologue: A 4 units (1/wave), B 16 units (4/wave)
    {
        int gr = m0 + wid * 16 + srow; if (gr >= M) gr = M - 1;
        gl2lds16(A + (size_t)gr * K + scol, &sA[0][wid * 512]);
        #pragma unroll
        for (int j = 0; j < 4; j++) {
            int u = wid * 4 + j;
            gl2lds16(B + (size_t)(u * 16 + srow) * K + scol, &sB[0][u * 512]);
        }
    }
    __syncthreads();

    int cur = 0;
    for (int k0 = 0; k0 < K; k0 += 32) {
        if (k0 + 32 < K) {
            int nb = cur ^ 1, k1 = k0 + 32;
            int gr = m0 + wid * 16 + srow; if (gr >= M) gr = M - 1;
            gl2lds16(A + (size_t)gr * K + k1 + scol, &sA[nb][wid * 512]);
            #pragma unroll
            for (int j = 0; j < 4; j++) {
                int u = wid * 4 + j;
                gl2lds16(B + (size_t)(u * 16 + srow) * K + k1 + scol, &sB[nb][u * 512]);
            }
        }
        {
            bf16x8 afr[4], bfr[4];
            #pragma unroll
            for (int m = 0; m < 4; m++)
                afr[m] = __builtin_bit_cast(bf16x8, *(const ushort8v*)&sA[cur][(m * 16 + lr) * 32 + gsw]);
            #pragma unroll
            for (int n = 0; n < 4; n++)
                bfr[n] = __builtin_bit_cast(bf16x8, *(const ushort8v*)&sB[cur][(wid * 64 + n * 16 + lr) * 32 + gsw]);
            #pragma unroll
            for (int m = 0; m < 4; m++)
                #pragma unroll
                for (int n = 0; n < 4; n++)
                    acc[m][n] = __builtin_amdgcn_mfma_f32_16x16x32_bf16(afr[m], bfr[n], acc[m][n], 0, 0, 0);
        }
        __syncthreads();   // final barrier frees sB for the repack
        cur ^= 1;
    }

    // epilogue: val = acc + h + fb2; per-row LN over 256 cols
    float fb[4], gg[4], bb[4];
    #pragma unroll
    for (int n = 0; n < 4; n++) {
        int cn = wid * 64 + n * 16 + lr;
        fb[n] = gld(fb2, cn, f32); gg[n] = gld(g2, cn, f32); bb[n] = gld(b2, cn, f32);
    }
    const int or0 = (lane >> 4) << 2;
    float s1[4][4], s2[4][4];
    #pragma unroll
    for (int m = 0; m < 4; m++) {
        #pragma unroll
        for (int r = 0; r < 4; r++) {
            int grow = m * 16 + or0 + r;
            float a1 = 0.f, a2 = 0.f;
            if (m0 + grow < M) {
                #pragma unroll
                for (int n = 0; n < 4; n++) {
                    int cn = wid * 64 + n * 16 + lr;
                    float hv = gld(hout, (size_t)(r0 + m0 + grow) * 256 + cn, f32);
                    float v = acc[m][n][r] + hv + fb[n];
                    acc[m][n][r] = v;
                    a1 += v; a2 += v * v;
                }
            }
            s1[m][r] = a1; s2[m][r] = a2;
        }
    }
    #pragma unroll
    for (int m = 0; m < 4; m++)
        #pragma unroll
        for (int r = 0; r < 4; r++) {
            #pragma unroll
            for (int d = 1; d < 16; d <<= 1) {
                s1[m][r] += __shfl_xor(s1[m][r], d, 64);
                s2[m][r] += __shfl_xor(s2[m][r], d, 64);
            }
        }
    if (lr == 0) {
        #pragma unroll
        for (int m = 0; m < 4; m++)
            #pragma unroll
            for (int r = 0; r < 4; r++) {
                int grow = m * 16 + or0 + r;
                red[wid][grow][0] = s1[m][r];
                red[wid][grow][1] = s2[m][r];
            }
    }
    __syncthreads();
    // normalize in place (acc <- o)
    #pragma unroll
    for (int m = 0; m < 4; m++) {
        #pragma unroll
        for (int r = 0; r < 4; r++) {
            int grow = m * 16 + or0 + r;
            if (m0 + grow >= M) continue;
            float t1 = red[0][grow][0] + red[1][grow][0] + red[2][grow][0] + red[3][grow][0];
            float t2 = red[0][grow][1] + red[1][grow][1] + red[2][grow][1] + red[3][grow][1];
            float mu = t1 * (1.f / 256.f);
            float var = fmaxf(t2 * (1.f / 256.f) - mu * mu, 0.f);
            float rs = rsqrtf(var + 1e-5f);
            #pragma unroll
            for (int n = 0; n < 4; n++)
                acc[m][n][r] = (acc[m][n][r] - mu) * rs * gg[n] + bb[n];
        }
    }
    // coalesced store via LDS repack (aliases sB; K-loop done with it)
    if (f32) {
        float* rep = (float*)sB;          // [64][128] f32 = 32 KB, two half-width passes
        for (int p = 0; p < 2; p++) {
            __syncthreads();
            if ((wid >> 1) == p) {
                #pragma unroll
                for (int m = 0; m < 4; m++)
                    #pragma unroll
                    for (int r = 0; r < 4; r++) {
                        int row = m * 16 + or0 + r;
                        #pragma unroll
                        for (int n = 0; n < 4; n++)
                            rep[row * 128 + (wid & 1) * 64 + n * 16 + lr] = acc[m][n][r];
                    }
            }
            __syncthreads();
            int rr = tid >> 5;            // 0..7
            int co = (tid & 31) * 4;      // f32 col offset within half
            #pragma unroll
            for (int it = 0; it < 8; it++) {
                int row = it * 8 + rr;
                int gr = m0 + row;
                if (gr < M)
                    *(float4*)&((float*)hout)[(size_t)(r0 + gr) * 256 + p * 128 + co] =
                        *(const float4*)&rep[row * 128 + co];
            }
        }
    } else {
        u16* repu = (u16*)sB;             // [64][256] u16 = 32 KB, one pass
        __syncthreads();
        #pragma unroll
        for (int m = 0; m < 4; m++)
            #pragma unroll
            for (int r = 0; r < 4; r++) {
                int row = m * 16 + or0 + r;
                #pragma unroll
                for (int n = 0; n < 4; n++)
                    repu[row * 256 + wid * 64 + n * 16 + lr] = f2bf(acc[m][n][r]);
            }
        __syncthreads();
        int rr = tid >> 5;
        int co = (tid & 31) * 8;
        #pragma unroll
        for (int it = 0; it < 8; it++) {
            int row = it * 8 + rr;
            int gr = m0 + row;
            if (gr < M)
                *(ushort8v*)&((u16*)hout)[(size_t)(r0 + gr) * 256 + co] =
                    *(const ushort8v*)&repu[row * 256 + co];
        }
    }
}

// ---- fold attention vectors through W: Mmat[th][k] (bf16, [32,256])
__global__ void __launch_bounds__(256) k_mkatt(const u32* __restrict__ dflag,
                                               const void* __restrict__ Wsrc, const void* __restrict__ Wdst,
                                               const void* __restrict__ attS, const void* __restrict__ attD,
                                               u16* __restrict__ Mmat, int K) {
    bool f32 = dflag[0] != 0u;
    int th = blockIdx.x;   // 0..31
    int k = threadIdx.x;   // 0..K-1 (K=256)
    int tt = th & 15;
    const void* W = (th < 16) ? Wsrc : Wdst;
    const void* att = (th < 16) ? attS : attD;
    int h = tt & 7;
    float s = 0.f;
    #pragma unroll 8
    for (int c = 0; c < 32; c++)
        s += gld(W, (size_t)(h * 32 + c) * K + k, f32) * gld(att, tt * 32 + c, f32);
    Mmat[th * K + k] = f2bf(s);
}

// ---- CSR build (dst-major) ----
__global__ void __launch_bounds__(256) k_count(const int* __restrict__ ei, u32* __restrict__ cnt, int E) {
    int e = blockIdx.x * 256 + threadIdx.x;
    if (e < E) atomicAdd(cnt + ei[E + e], 1u);
}
__global__ void __launch_bounds__(256) k_scanA(u32* __restrict__ buf, u32* __restrict__ bsum, int N) {
    int t = threadIdx.x, idx = blockIdx.x * 256 + t;
    u32 v = (idx < N) ? buf[idx] : 0u;
    __shared__ u32 sc[256];
    sc[t] = v; __syncthreads();
    for (int d = 1; d < 256; d <<= 1) {
        u32 add = (t >= d) ? sc[t - d] : 0u; __syncthreads();
        sc[t] += add; __syncthreads();
    }
    if (idx < N) buf[idx] = sc[t] - v;
    if (t == 255) bsum[blockIdx.x] = sc[255];
}
__global__ void __launch_bounds__(256) k_scanB(u32* __restrict__ bsum, int nb) {
    int t = threadIdx.x;
    u32 v = (t < nb) ? bsum[t] : 0u;
    __shared__ u32 sc[256];
    sc[t] = v; __syncthreads();
    for (int d = 1; d < 256; d <<= 1) {
        u32 add = (t >= d) ? sc[t - d] : 0u; __syncthreads();
        sc[t] += add; __syncthreads();
    }
    if (t < nb) bsum[t] = sc[t] - v;
}
__global__ void __launch_bounds__(256) k_scanC(u32* __restrict__ obuf, u32* __restrict__ cursor,
                                               const u32* __restrict__ bsum, int N, int E) {
    int idx = blockIdx.x * 256 + threadIdx.x;
    if (idx < N) {
        u32 o = obuf[idx] + bsum[blockIdx.x];
        obuf[idx] = o;
        cursor[idx] = o;
    }
    if (blockIdx.x == 0 && threadIdx.x == 0) obuf[N] = (u32)E;
}
// scatter packed edge payload: pedge[slot] = {src | type<<31, bits(w)}
__global__ void __launch_bounds__(256) k_scatter(const u32* __restrict__ dflag,
                                                 const int* __restrict__ ei, const int* __restrict__ et,
                                                 const void* __restrict__ ew, u32* __restrict__ cursor,
                                                 uint2* __restrict__ pedge, int E) {
    bool f32 = dflag[0] != 0u;
    int e = blockIdx.x * 256 + threadIdx.x;
    if (e >= E) return;
    u32 slot = atomicAdd(cursor + ei[E + e], 1u);
    uint2 pk;
    pk.x = (u32)ei[e] | ((u32)et[e] << 31);
    pk.y = __float_as_uint(gld(ew, e, f32));
    pedge[slot] = pk;
}

// ---- fused per-node softmax aggregation + LN1, ONE WAVE PER NODE (round-8 verified).
// xsd = [N,288] bf16: cols 0..255 = x@Wsrc^T, cols 256..287 = the 32 att dots.
__global__ void __launch_bounds__(256) k_node(const u32* __restrict__ dflag,
                                              const uint2* __restrict__ pedge, const void* __restrict__ x,
                                              const u16* __restrict__ xsd,
                                              const u32* __restrict__ obuf,
                                              const void* __restrict__ bias,
                                              const void* __restrict__ g1, const void* __restrict__ b1,
                                              void* __restrict__ hout, u16* __restrict__ hb, int N) {
    bool f32 = dflag[0] != 0u;
    const int wid = threadIdx.x >> 6;
    const int lane = threadIdx.x & 63;
    const int node = blockIdx.x * 4 + wid;
    if (node >= N) return;

    __shared__ u32 s_src[4][64];
    __shared__ float s_w[4][64];
    __shared__ float s_pe[4][64][8];

    const int ch0 = lane * 4;
    const int hh = lane >> 3;
    const size_t nbase = (size_t)node * 288;

    ushort8v dd0v = *(const ushort8v*)&xsd[nbase + 256 + 16];
    ushort8v dd1v = *(const ushort8v*)&xsd[nbase + 256 + 24];

    // self-loop: type 0, weight 1
    float a_self = bf2f(xsd[nbase + 256 + hh]) + bf2f(xsd[nbase + 256 + 16 + hh]);
    float p_self = __expf(a_self >= 0.f ? a_self : 0.2f * a_self);
    float den = p_self;
    ushort4 sv = *(const ushort4*)&xsd[nbase + ch0];
    float num0 = p_self * bf2f(sv.x), num1 = p_self * bf2f(sv.y);
    float num2 = p_self * bf2f(sv.z), num3 = p_self * bf2f(sv.w);

    const u32 kbeg = obuf[node], kend = obuf[node + 1];
    for (u32 c0 = kbeg; c0 < kend; c0 += 64) {
        int cnt = (int)(kend - c0) < 64 ? (int)(kend - c0) : 64;
        __builtin_amdgcn_wave_barrier();   // compiler fence: prior chunk reads done
        if (lane < cnt) {
            uint2 pe = pedge[c0 + lane];
            u32 src = pe.x & 0x7fffffffu;
            int t = (int)(pe.x >> 31);
            s_src[wid][lane] = src;
            s_w[wid][lane] = __uint_as_float(pe.y);
            ushort8v ds8 = *(const ushort8v*)&xsd[(size_t)src * 288 + 256 + t * 8];
            ushort8v ddv = t ? dd1v : dd0v;
            #pragma unroll
            for (int h = 0; h < 8; h++) {
                float aa = bf2f(ds8[h]) + bf2f(ddv[h]);
                s_pe[wid][lane][h] = __expf(aa >= 0.f ? aa : 0.2f * aa);
            }
        }
        __builtin_amdgcn_wave_barrier();   // compiler fence: stage visible before reads
        int k = 0;
        for (; k + 8 <= cnt; k += 8) {
            u32 ss[8]; float pp[8], ww[8]; ushort4 gv[8];
            #pragma unroll
            for (int j = 0; j < 8; j++) {
                ss[j] = s_src[wid][k + j];
                pp[j] = s_pe[wid][k + j][hh];
                ww[j] = s_w[wid][k + j];
            }
            #pragma unroll
            for (int j = 0; j < 8; j++)
                gv[j] = *(const ushort4*)&xsd[(size_t)ss[j] * 288 + ch0];
            #pragma unroll
            for (int j = 0; j < 8; j++) {
                float q = pp[j] * ww[j];
                num0 += q * bf2f(gv[j].x); num1 += q * bf2f(gv[j].y);
                num2 += q * bf2f(gv[j].z); num3 += q * bf2f(gv[j].w);
                den += pp[j];
            }
        }
        for (; k + 4 <= cnt; k += 4) {
            u32 ss[4]; float pp[4], ww[4]; ushort4 gv[4];
            #pragma unroll
            for (int j = 0; j < 4; j++) {
                ss[j] = s_src[wid][k + j];
                pp[j] = s_pe[wid][k + j][hh];
                ww[j] = s_w[wid][k + j];
            }
            #pragma unroll
            for (int j = 0; j < 4; j++)
                gv[j] = *(const ushort4*)&xsd[(size_t)ss[j] * 288 + ch0];
            #pragma unroll
            for (int j = 0; j < 4; j++) {
                float q = pp[j] * ww[j];
                num0 += q * bf2f(gv[j].x); num1 += q * bf2f(gv[j].y);
                num2 += q * bf2f(gv[j].z); num3 += q * bf2f(gv[j].w);
                den += pp[j];
            }
        }
        for (; k < cnt; k++) {
            u32 s = s_src[wid][k];
            float p = s_pe[wid][k][hh];
            float pw = p * s_w[wid][k];
            ushort4 xv = *(const ushort4*)&xsd[(size_t)s * 288 + ch0];
            num0 += pw * bf2f(xv.x); num1 += pw * bf2f(xv.y);
            num2 += pw * bf2f(xv.z); num3 += pw * bf2f(xv.w);
            den += p;
        }
    }

    float rden = 1.0f / den;
    float xr0, xr1, xr2, xr3;
    if (f32) {
        float4 t = *(const float4*)((const float*)x + (size_t)node * 256 + ch0);
        xr0 = t.x; xr1 = t.y; xr2 = t.z; xr3 = t.w;
    } else {
        ushort4 t = *(const ushort4*)((const u16*)x + (size_t)node * 256 + ch0);
        xr0 = bf2f(t.x); xr1 = bf2f(t.y); xr2 = bf2f(t.z); xr3 = bf2f(t.w);
    }
    float v0 = num0 * rden + gld(bias, ch0 + 0, f32) + xr0;
    float v1 = num1 * rden + gld(bias, ch0 + 1, f32) + xr1;
    float v2 = num2 * rden + gld(bias, ch0 + 2, f32) + xr2;
    float v3 = num3 * rden + gld(bias, ch0 + 3, f32) + xr3;

    // fused LN1 (wave-local)
    float mu = wave_sum(v0 + v1 + v2 + v3) * (1.f / 256.f);
    float d0 = v0 - mu, d1 = v1 - mu, d2 = v2 - mu, d3 = v3 - mu;
    float var = wave_sum(d0 * d0 + d1 * d1 + d2 * d2 + d3 * d3) * (1.f / 256.f);
    float rs = rsqrtf(var + 1e-5f);
    float o0 = d0 * rs * gld(g1, ch0 + 0, f32) + gld(b1, ch0 + 0, f32);
    float o1 = d1 * rs * gld(g1, ch0 + 1, f32) + gld(b1, ch0 + 1, f32);
    float o2 = d2 * rs * gld(g1, ch0 + 2, f32) + gld(b1, ch0 + 2, f32);
    float o3 = d3 * rs * gld(g1, ch0 + 3, f32) + gld(b1, ch0 + 3, f32);

    size_t base = (size_t)node * 256 + ch0;
    if (f32) {
        float4 ov; ov.x = o0; ov.y = o1; ov.z = o2; ov.w = o3;
        *(float4*)&((float*)hout)[base] = ov;
    } else {
        ushort4 ov; ov.x = f2bf(o0); ov.y = f2bf(o1); ov.z = f2bf(o2); ov.w = f2bf(o3);
        *(ushort4*)&((u16*)hout)[base] = ov;
    }
    ushort4 hv; hv.x = f2bf(o0); hv.y = f2bf(o1); hv.z = f2bf(o2); hv.w = f2bf(o3);
    *(ushort4*)&hb[base] = hv;
}

extern "C" void kernel_launch(void* const* d_in, const int* in_sizes, int n_in,
                              void* d_out, int out_size, void* d_ws, size_t ws_size,
                              hipStream_t stream) {
    const int N = in_sizes[0] / 256;     // 50000
    const int E = in_sizes[1] / 2;       // 800000
    const int NB = (N + 255) / 256;      // 196

    const void* x    = d_in[0];
    const int*  ei   = (const int*)d_in[1];
    const int*  et   = (const int*)d_in[2];
    const void* ew   = d_in[3];
    const void* Wsrc = d_in[4];
    const void* Wdst = d_in[5];
    const void* attS = d_in[6];
    const void* attD = d_in[7];
    const void* bias = d_in[8];
    const void* g1   = d_in[9];
    const void* b1   = d_in[10];
    const void* g2   = d_in[11];
    const void* b2   = d_in[12];
    const void* W1   = d_in[13];
    const void* fb1  = d_in[14];
    const void* W2   = d_in[15];
    const void* fb2  = d_in[16];

    // Workspace layout (round 4+ proved ws_size >= ~213 MB: full one-chunk FFN ran)
    char* ws = (char*)d_ws;
    u32* flag   = (u32*)(ws + 0);             // 256 B
    u32* bsum   = (u32*)(ws + 256);           // 1 KB
    u32* obuf   = (u32*)(ws + 1536);          // (N+1)*4 ~ 200 KB
    u32* cursor = (u32*)(ws + 201984);        // N*4 = 200 KB
    u16* xb     = (u16*)(ws + 3602176);       // [N,256] bf16 = 25.6 MB (x pre-cvt)
    u16* hb     = (u16*)(ws + 3602176);       // [N,256] bf16 post-LN1 (xb dead by then)
    u16* xsd    = (u16*)(ws + 29202176);      // [N,288] bf16 = 28.8 MB (xs | 32 dots)
    u16* Bcat   = (u16*)(ws + 58002176);      // [288,256] bf16: Wsb rows 0-255, Mmat 256-287
    u16* W1b    = (u16*)(ws + 58149632);      // [1024,256] bf16 = 512 KB
    u16* W2b    = (u16*)(ws + 58673920);      // [256,1024] bf16 = 512 KB
    uint2* pedge = (uint2*)(ws + 59198208);   // [E] packed {src|t<<31, w} = 6.4 MB (dead before FFN)
    char* ffnbuf = ws + 59198208;             // FFN act buffer aliases pedge (temporally disjoint)
    void* hbuf  = d_out;                      // h -> out staged in d_out (dtype = flag)

    k_probe<<<1, 256, 0, stream>>>((const u16*)x, flag);

    // bf16 pre-conversion of all GEMM operands (identity if inputs already bf16)
    k_cvt<<<(N * 32 + 255) / 256, 256, 0, stream>>>(flag, x, xb, N * 32);
    k_cvt<<<32, 256, 0, stream>>>(flag, Wsrc, Bcat, 8192);
    k_cvt<<<128, 256, 0, stream>>>(flag, W1, W1b, 32768);
    k_cvt<<<128, 256, 0, stream>>>(flag, W2, W2b, 32768);
    k_mkatt<<<32, 256, 0, stream>>>(flag, Wsrc, Wdst, attS, attD, Bcat + 256 * 256, 256);

    const int gyN = (N + 127) / 128;          // 391

    // xsd[N,288] = xb @ [Wsb; Mmat]^T  (x_src features + all 32 att dots, one pass)
    mgemm4<0><<<dim3(3, gyN), 256, 0, stream>>>(flag, xb, Bcat, xsd, nullptr, N, 288, 256, 288, 0);

    // CSR build (packed payload)
    k_zero<<<NB, 256, 0, stream>>>(obuf, N);
    k_count<<<(E + 255) / 256, 256, 0, stream>>>(ei, obuf, E);
    k_scanA<<<NB, 256, 0, stream>>>(obuf, bsum, N);
    k_scanB<<<1, 256, 0, stream>>>(bsum, NB);
    k_scanC<<<NB, 256, 0, stream>>>(obuf, cursor, bsum, N, E);
    k_scatter<<<(E + 255) / 256, 256, 0, stream>>>(flag, ei, et, ew, cursor, pedge, E);

    // aggregation + fused LN1 (one wave per node) -> h in d_out + hb bf16
    k_node<<<(N + 3) / 4, 256, 0, stream>>>(flag, pedge, x, xsd, obuf,
                                            bias, g1, b1, hbuf, hb, N);

    // FFN: W1 (gelu epilogue) -> act; W2+LN2 fused writes final output in place.
    long long avail = (long long)ws_size - 59198208 - 256;
    int rc = (int)(avail / 2048);
    rc &= ~127;
    if (rc > 50048) rc = 50048;
    if (rc < 128) rc = 128;
    u16* act = (u16*)ffnbuf;

    for (int r0 = 0; r0 < N; r0 += rc) {
        int rows = N - r0; if (rows > rc) rows = rc;
        int gy = (rows + 127) / 128;
        mgemm4<1><<<dim3(8, gy), 256, 0, stream>>>(flag, hb, W1b, act, fb1, rows, 1024, 256, 1024, r0);
        int g5 = (rows + 63) / 64;
        mgemm5<<<g5, 256, 0, stream>>>(flag, act, W2b, hbuf, fb2, g2, b2, rows, r0);
    }
}